// Round 8
// baseline (447.923 us; speedup 1.0000x reference)
//
#include <hip/hip_runtime.h>

using bf16 = __bf16;
typedef bf16 bf16x4 __attribute__((ext_vector_type(4)));
typedef bf16 bf16x8 __attribute__((ext_vector_type(8)));
typedef float f32x4 __attribute__((ext_vector_type(4)));
typedef float f32x8 __attribute__((ext_vector_type(8)));

#define MFMA16(a, b, c) __builtin_amdgcn_mfma_f32_16x16x32_bf16(a, b, c, 0, 0, 0)

constexpr int Bb = 4, Tt = 2048, Dd = 1024, Hh = 16, Hd = 64;
constexpr int Mrows = Bb * Tt;                 // 8192
constexpr float CEXP = 0.18033688011112042f;   // (1/sqrt(64)) * log2(e), folded into Wq/bq

// async global->LDS, 16B per lane; LDS dst = wave-uniform base + lane*16 [m97/m104]
__device__ __forceinline__ void gload_lds16(const bf16* g, bf16* lds_base) {
  __builtin_amdgcn_global_load_lds((const __attribute__((address_space(1))) void*)g,
                                   (__attribute__((address_space(3))) void*)lds_base,
                                   16, 0, 0);
}

// ---------------------------------------------------------------- cast x -> bf16
__global__ void cast_f32_bf16_kernel(const float* __restrict__ in, bf16* __restrict__ out) {
  size_t i = ((size_t)blockIdx.x * 256 + threadIdx.x) * 8;
  f32x8 v = *(const f32x8*)(in + i);
  *(bf16x8*)(out + i) = __builtin_convertvector(v, bf16x8);
}

// ---- fused transpose+cast of all four weight matrices: W[k][n] f32 -> Wt[n][k] bf16
__global__ void transpose_cast_w4_kernel(const float* __restrict__ Wq, const float* __restrict__ Wk,
                                         const float* __restrict__ Wv, const float* __restrict__ Wo,
                                         bf16* __restrict__ Wt, bf16* __restrict__ Wot) {
  __shared__ alignas(16) float tile[64][68];
  const int tid = threadIdx.x;
  const int n0 = blockIdx.x * 64, k0 = blockIdx.y * 64, z = blockIdx.z;
  const float* W = (z == 0) ? Wq : (z == 1) ? Wk : (z == 2) ? Wv : Wo;
  bf16* dst = (z == 3) ? Wot : (Wt + (size_t)z * Dd * Dd);
  const float scale = (z == 0) ? CEXP : 1.0f;
#pragma unroll
  for (int it = 0; it < 4; ++it) {
    int chunk = tid + it * 256;
    int kr = chunk >> 4, c4 = chunk & 15;
    f32x4 v = *(const f32x4*)(W + (size_t)(k0 + kr) * Dd + n0 + c4 * 4);
    *(f32x4*)&tile[kr][c4 * 4] = v * scale;
  }
  __syncthreads();
#pragma unroll
  for (int it = 0; it < 2; ++it) {
    int chunk = tid + it * 256;
    int n = chunk & 63, k8 = chunk >> 6;
    bf16x8 o;
#pragma unroll
    for (int j = 0; j < 8; ++j) o[j] = (bf16)tile[k8 * 8 + j][n];
    *(bf16x8*)(dst + (size_t)(n0 + n) * Dd + k0 + k8 * 8) = o;
  }
}

// ---------------------------------------------------------------- pack qkv bias
__global__ void pack_bias_kernel(const float* __restrict__ bq, const float* __restrict__ bk,
                                 const float* __restrict__ bv, float* __restrict__ outb) {
  int i = blockIdx.x * 256 + threadIdx.x;
  float v = (i < 1024) ? bq[i] * CEXP : (i < 2048 ? bk[i - 1024] : bv[i - 2048]);
  outb[i] = v;
}

// --------- QKV GEMM v2: 128x256 tile / 512 threads / 8 waves (2M x 4N), BK=32.
// 3-slot LDS ring (72 KiB), counted vmcnt(3), one raw s_barrier per tile.
constexpr int QBM = 128, QBN = 256, QBK = 32, QNT = Dd / QBK;  // 32 K-tiles

#define VMW(n) asm volatile("s_waitcnt vmcnt(" #n ")" ::: "memory")

__global__ __launch_bounds__(512, 2)
void gemm_qkv_kernel(const bf16* __restrict__ A, const bf16* __restrict__ Bt,
                     const float* __restrict__ bias, bf16* __restrict__ QK,
                     bf16* __restrict__ Vt) {
  constexpr int KD = Dd;
  __shared__ alignas(16) bf16 As[3][QBM * QBK];   // 3 x 8 KiB
  __shared__ alignas(16) bf16 Bs[3][QBN * QBK];   // 3 x 16 KiB  (72 KiB total)
  const int tid = threadIdx.x;
  const int lane = tid & 63, wave = tid >> 6;
  const int col = lane & 15, quad = lane >> 4;
  const int wr = wave >> 2, wc = wave & 3;        // wave tile: 64 x 64
  const size_t m0 = (size_t)blockIdx.x * QBM, n0 = (size_t)blockIdx.y * QBN;

  // staging source pre-swizzle (rule #21): lane l writes LDS vrow (g*8 + l>>3),
  // phys pos (l&7); fetch logical chunk u = (l&7)^(l>>3):
  const int u = (lane & 7) ^ (lane >> 3);
  const int srow = 2 * (lane >> 3) + (u >> 2);    // row within 16-row group
  const int scol = (u & 3) * 8;                   // element col within 32
  const bf16* Abase = A + (m0 + srow) * (size_t)KD + scol;
  const bf16* Bbase = Bt + (n0 + srow) * (size_t)KD + scol;

  // swizzled fragment read base: row R -> vrow R>>1, pos ((R&1)*4 | quad) ^ (vrow&7)
  const int pswz = (((col & 1) << 2) | quad) ^ (col >> 1);
  const int afb = wr * 2048 + (col >> 1) * 64 + pswz * 8;  // + i*512
  const int bfb = wc * 2048 + (col >> 1) * 64 + pswz * 8;  // + j*512

  f32x4 acc[4][4];
#pragma unroll
  for (int i = 0; i < 4; ++i)
#pragma unroll
    for (int j = 0; j < 4; ++j)
#pragma unroll
      for (int r = 0; r < 4; ++r) acc[i][j][r] = 0.f;

  // per wave per tile: 1 A gload (16 rows) + 2 B gloads (32 rows)
#define QSTAGE(t, sl) do { \
    gload_lds16(Abase + (size_t)(t) * QBK + (size_t)(wave * 16) * KD, &As[sl][wave * 512]); \
    gload_lds16(Bbase + (size_t)(t) * QBK + (size_t)(2 * wave) * 16 * KD, &Bs[sl][(2 * wave) * 512]); \
    gload_lds16(Bbase + (size_t)(t) * QBK + (size_t)(2 * wave + 1) * 16 * KD, &Bs[sl][(2 * wave + 1) * 512]); \
  } while (0)

#define QKV_TILE(cur, DOSTAGE, VM) do { \
    bf16x8 af[4], bfv[4]; \
    _Pragma("unroll") for (int j = 0; j < 4; ++j) bfv[j] = *(const bf16x8*)&Bs[cur][bfb + j * 512]; \
    _Pragma("unroll") for (int i = 0; i < 4; ++i) af[i] = *(const bf16x8*)&As[cur][afb + i * 512]; \
    DOSTAGE; \
    asm volatile("s_waitcnt lgkmcnt(0)" ::: "memory"); \
    __builtin_amdgcn_s_setprio(1); \
    _Pragma("unroll") for (int i = 0; i < 4; ++i) \
      _Pragma("unroll") for (int j = 0; j < 4; ++j) acc[i][j] = MFMA16(af[i], bfv[j], acc[i][j]); \
    __builtin_amdgcn_s_setprio(0); \
    VM; \
    __builtin_amdgcn_s_barrier(); \
  } while (0)

  // prologue: stage tiles 0,1 (6 loads/wave outstanding); wait oldest 3 = tile 0
  QSTAGE(0, 0);
  QSTAGE(1, 1);
  VMW(3);
  __builtin_amdgcn_s_barrier();

#pragma unroll 1
  for (int t = 0; t < QNT - 2; t += 3) {          // tiles 0..29 (30 % 3 == 0)
    QKV_TILE(0, QSTAGE(t + 2, 2), VMW(3));
    QKV_TILE(1, QSTAGE(t + 3, 0), VMW(3));
    QKV_TILE(2, QSTAGE(t + 4, 1), VMW(3));
  }
  QKV_TILE(0, (void)0, VMW(0));                   // tile 30: only tile 31 in flight
  QKV_TILE(1, (void)0, (void)0);                  // tile 31

  if (n0 < 2048) {      // Q/K block -> compact [8192][2048] buffer
#pragma unroll
    for (int i = 0; i < 4; ++i)
#pragma unroll
      for (int j = 0; j < 4; ++j) {
        size_t row = m0 + wr * 64 + i * 16 + quad * 4;
        size_t c = n0 + wc * 64 + j * 16 + col;
        float bv = bias[c];
#pragma unroll
        for (int r = 0; r < 4; ++r) QK[(row + r) * 2048 + c] = (bf16)(acc[i][j][r] + bv);
      }
  } else {              // V block -> Vt[b][h][d][t], packed along t
#pragma unroll
    for (int i = 0; i < 4; ++i)
#pragma unroll
      for (int j = 0; j < 4; ++j) {
        size_t row = m0 + wr * 64 + i * 16 + quad * 4;
        int c = (int)(n0 + wc * 64 + j * 16 + col);
        float bv = bias[c];
        int dall = c - 2048, hh = dall >> 6, dd = dall & 63;
        int bi = (int)(row >> 11), trow = (int)(row & 2047);
        bf16x4 pk;
#pragma unroll
        for (int r = 0; r < 4; ++r) pk[r] = (bf16)(acc[i][j][r] + bv);
        *(bf16x4*)&Vt[((size_t)(bi * Hh + hh) * Hd + dd) * Tt + trow] = pk;
      }
  }
#undef QKV_TILE
#undef QSTAGE
}

// ------------------------- generic GEMM (out-projection): C = A @ Bt^T + bias
__global__ __launch_bounds__(256)
void gemm_bf16_kernel(const bf16* __restrict__ A, const bf16* __restrict__ Bt,
                      const float* __restrict__ bias, float* __restrict__ C,
                      int M, int N, int K) {
  __shared__ alignas(16) bf16 As[128 * 64];
  __shared__ alignas(16) bf16 Bs[128 * 64];
  const int tid = threadIdx.x;
  const int lane = tid & 63, wave = tid >> 6;
  const int col = lane & 15, quad = lane >> 4;
  const int wr = (wave >> 1) * 64, wc = (wave & 1) * 64;
  const size_t m0 = (size_t)blockIdx.x * 128, n0 = (size_t)blockIdx.y * 128;
  const int srow = lane >> 3, schunk = (lane & 7) * 8;

  f32x4 acc[4][4];
#pragma unroll
  for (int i = 0; i < 4; ++i)
#pragma unroll
    for (int j = 0; j < 4; ++j)
#pragma unroll
      for (int r = 0; r < 4; ++r) acc[i][j][r] = 0.f;

  for (int k0 = 0; k0 < K; k0 += 64) {
#pragma unroll
    for (int it = 0; it < 4; ++it) {
      int rbase = it * 32 + wave * 8;
      gload_lds16(A + (m0 + rbase + srow) * (size_t)K + k0 + schunk, &As[rbase * 64]);
      gload_lds16(Bt + (n0 + rbase + srow) * (size_t)K + k0 + schunk, &Bs[rbase * 64]);
    }
    __syncthreads();
#pragma unroll
    for (int kk = 0; kk < 2; ++kk) {
      bf16x8 af[4], bfr[4];
#pragma unroll
      for (int i = 0; i < 4; ++i) af[i] = *(const bf16x8*)&As[(wr + i * 16 + col) * 64 + kk * 32 + quad * 8];
#pragma unroll
      for (int j = 0; j < 4; ++j) bfr[j] = *(const bf16x8*)&Bs[(wc + j * 16 + col) * 64 + kk * 32 + quad * 8];
#pragma unroll
      for (int i = 0; i < 4; ++i)
#pragma unroll
        for (int j = 0; j < 4; ++j) acc[i][j] = MFMA16(af[i], bfr[j], acc[i][j]);
    }
    __syncthreads();
  }
#pragma unroll
  for (int i = 0; i < 4; ++i)
#pragma unroll
    for (int j = 0; j < 4; ++j) {
      size_t row = m0 + wr + i * 16 + quad * 4;
      size_t c = n0 + wc + j * 16 + col;
      float bv = bias[c];
#pragma unroll
      for (int r = 0; r < 4; ++r) C[(row + r) * (size_t)N + c] = acc[i][j][r] + bv;
    }
}

// ----------------------------------------------- flash attention v5
// R7 base: 1024 blocks, (256,2), ones-MFMA denominator, per-kt QK^T / per-n PV.
// NEW (lesson m169 / Common-mistake #7): V is NO LONGER LDS-STAGED. V per (b,h) is
// 256KB, reused by 16 XCD-pinned blocks (8 heads x 512KB = one XCD L2) -> read V
// fragments DIRECTLY from global (L2) into registers at the top of each iteration;
// the QK^T+softmax phase (~500cy) hides L2 latency (~200-400cy). Vt[d][t] layout
// makes each fragment an 8B-contiguous run: key = kb + kk*32 + half*16 + quad*4 at
// row d = n*16+col (verified == the old LDS sigma-map). Only K keeps the 3-slot
// gload_lds ring (2 loads/iter, counted vmcnt(2)). V loads issue BEFORE K-stage so
// the compiler's implicit pre-PV wait (vmcnt<=2) never drains the K prefetch.
// Removes: 2/4 gloads, 16 LDS b64 reads, Vs conflicts; LDS 48->24KB. +32 VGPR (free:
// occupancy pinned at 2 waves/SIMD regardless, R2-R7).
__global__ __launch_bounds__(256, 2)
void flash_attn_kernel(const bf16* __restrict__ qk, const bf16* __restrict__ vt,
                       const unsigned char* __restrict__ mask, bf16* __restrict__ ao) {
  __shared__ alignas(16) bf16 Ks[3][64 * 64];      // [key][slot^], xor-swizzled 16B slots

  const int tid = threadIdx.x;
  const int wave = tid >> 6, lane = tid & 63;
  const int col = lane & 15, quad = lane >> 4;
  const int id = blockIdx.x;
  const int hb = id & 63, qi = id >> 6;            // same-head blocks stride 64 -> same XCD
  const int h = hb & 15, b = hb >> 4;
  const int qbase0 = qi * 128 + wave * 32;

  const bf16* Qp = qk + (size_t)(b * Tt) * 2048 + h * Hd;
  const bf16* Kp = Qp + 1024;
  const bf16* Vp = vt + ((size_t)(b * Hh + h) * Hd) * Tt;
  const unsigned char* mp = mask + b * Tt;

  unsigned long long anym;
  {
    const unsigned long long* mq = (const unsigned long long*)mp;
    unsigned long long acc = 0;
#pragma unroll
    for (int j = 0; j < 4; ++j) acc |= mq[lane * 4 + j];
    anym = __ballot(acc != 0ull);
  }

  // Q fragments (pre-scaled by CEXP): free index = query
  bf16x8 qf[2][2];
#pragma unroll
  for (int t = 0; t < 2; ++t)
#pragma unroll
    for (int kk = 0; kk < 2; ++kk)
      qf[t][kk] = *(const bf16x8*)(Qp + (size_t)(qbase0 + t * 16 + col) * 2048 + kk * 32 + quad * 8);

  // K gload_lds staging (rule #21 pre-swizzle): wave w stages 1KB chunks {2w, 2w+1}.
  const int u = (lane & 7) ^ (lane >> 3);
  const int g0 = 2 * wave, g1 = 2 * wave + 1;
  const bf16* Ksrc0 = Kp + (size_t)(g0 * 8 + (lane >> 3)) * 2048 + u * 8;
  const bf16* Ksrc1 = Kp + (size_t)(g1 * 8 + (lane >> 3)) * 2048 + u * 8;
  // direct-global V base: row d = col (+n*16), key chunk quad*4
  const bf16* Vrow = Vp + (size_t)col * Tt + quad * 4;

#define KSTAGE(t, sl) do { \
    gload_lds16(Ksrc0 + (size_t)(t) * 64 * 2048, &Ks[sl][g0 * 512]); \
    gload_lds16(Ksrc1 + (size_t)(t) * 64 * 2048, &Ks[sl][g1 * 512]); \
  } while (0)

  f32x4 oacc[2][4];
  f32x4 lones[2];
#pragma unroll
  for (int t = 0; t < 2; ++t) {
#pragma unroll
    for (int r = 0; r < 4; ++r) lones[t][r] = 0.f;
#pragma unroll
    for (int n = 0; n < 4; ++n)
#pragma unroll
      for (int r = 0; r < 4; ++r) oacc[t][n][r] = 0.f;
  }
  const f32x4 zero4 = {0.f, 0.f, 0.f, 0.f};
  bf16x8 onev;
#pragma unroll
  for (int j = 0; j < 8; ++j) onev[j] = (bf16)1.0f;

  const int fslot0 = ((0 * 4 + quad) ^ (col & 7)) * 8;   // b128 frag slots (kf)
  const int fslot1 = ((1 * 4 + quad) ^ (col & 7)) * 8;

// one KV-tile: {issue 16 V b64 loads (L2-direct, consumed in PV); issue K stage
// II+2; per-kt QK^T both q-tiles; mask; exp2 -> pf; per-n PV from vv; ones-MFMA;
// counted vmcnt(2); barrier}
#define FITER(cur, II, DOSTAGE, VM) do { \
    const int kb = (II) * 64; \
    bf16x4 vv[4][2][2]; \
    _Pragma("unroll") for (int n = 0; n < 4; ++n) \
      _Pragma("unroll") for (int kk = 0; kk < 2; ++kk) \
        _Pragma("unroll") for (int hf = 0; hf < 2; ++hf) \
          vv[n][kk][hf] = *(const bf16x4*)(Vrow + (size_t)(n * 16) * Tt + kb + kk * 32 + hf * 16); \
    DOSTAGE; \
    f32x4 s[2][4]; \
    _Pragma("unroll") for (int kt = 0; kt < 4; ++kt) { \
      bf16x8 kf0 = *(const bf16x8*)&Ks[cur][(kt * 16 + col) * 64 + fslot0]; \
      bf16x8 kf1 = *(const bf16x8*)&Ks[cur][(kt * 16 + col) * 64 + fslot1]; \
      s[0][kt] = MFMA16(kf0, qf[0][0], zero4); \
      s[1][kt] = MFMA16(kf0, qf[1][0], zero4); \
      s[0][kt] = MFMA16(kf1, qf[0][1], s[0][kt]); \
      s[1][kt] = MFMA16(kf1, qf[1][1], s[1][kt]); \
    } \
    if ((anym >> (2 * (II))) & 3ull) { \
      _Pragma("unroll") for (int kt = 0; kt < 4; ++kt) \
        _Pragma("unroll") for (int r = 0; r < 4; ++r) \
          if (mp[kb + kt * 16 + quad * 4 + r] != 0) { s[0][kt][r] = -1e9f; s[1][kt][r] = -1e9f; } \
    } \
    bf16x8 pf[2][2]; \
    _Pragma("unroll") for (int t = 0; t < 2; ++t) { \
      f32x4 e0, e1, e2, e3; \
      _Pragma("unroll") for (int r = 0; r < 4; ++r) { \
        e0[r] = __builtin_amdgcn_exp2f(s[t][0][r]); \
        e1[r] = __builtin_amdgcn_exp2f(s[t][1][r]); \
        e2[r] = __builtin_amdgcn_exp2f(s[t][2][r]); \
        e3[r] = __builtin_amdgcn_exp2f(s[t][3][r]); \
      } \
      bf16x4 c0 = __builtin_convertvector(e0, bf16x4); \
      bf16x4 c1 = __builtin_convertvector(e1, bf16x4); \
      bf16x4 c2 = __builtin_convertvector(e2, bf16x4); \
      bf16x4 c3 = __builtin_convertvector(e3, bf16x4); \
      pf[t][0] = __builtin_shufflevector(c0, c1, 0, 1, 2, 3, 4, 5, 6, 7); \
      pf[t][1] = __builtin_shufflevector(c2, c3, 0, 1, 2, 3, 4, 5, 6, 7); \
    } \
    _Pragma("unroll") for (int n = 0; n < 4; ++n) { \
      bf16x8 v0 = __builtin_shufflevector(vv[n][0][0], vv[n][0][1], 0, 1, 2, 3, 4, 5, 6, 7); \
      bf16x8 v1 = __builtin_shufflevector(vv[n][1][0], vv[n][1][1], 0, 1, 2, 3, 4, 5, 6, 7); \
      _Pragma("unroll") for (int t = 0; t < 2; ++t) { \
        oacc[t][n] = MFMA16(pf[t][0], v0, oacc[t][n]); \
        oacc[t][n] = MFMA16(pf[t][1], v1, oacc[t][n]); \
      } \
    } \
    _Pragma("unroll") for (int t = 0; t < 2; ++t) { \
      lones[t] = MFMA16(pf[t][0], onev, lones[t]); \
      lones[t] = MFMA16(pf[t][1], onev, lones[t]); \
    } \
    VM; \
    __builtin_amdgcn_s_barrier(); \
  } while (0)

  // prologue: stage K tiles 0,1 (4 loads outstanding); wait oldest 2 = tile 0
  KSTAGE(0, 0);
  KSTAGE(1, 1);
  VMW(2);
  __builtin_amdgcn_s_barrier();

#pragma unroll 1
  for (int ii = 0; ii < 30; ii += 3) {            // tiles 0..29
    FITER(0, ii + 0, KSTAGE(ii + 2, 2), VMW(2));
    FITER(1, ii + 1, KSTAGE(ii + 3, 0), VMW(2));
    FITER(2, ii + 2, KSTAGE(ii + 4, 1), VMW(2));
  }
  FITER(0, 30, (void)0, VMW(0));                  // tile 30: tile 31's K must land
  FITER(1, 31, (void)0, (void)0);                 // tile 31

#undef FITER
#undef KSTAGE

  // epilogue: no cross-lane transpose needed; lones rows == oacc rows
#pragma unroll
  for (int t = 0; t < 2; ++t) {
    f32x4 rl;
#pragma unroll
    for (int r = 0; r < 4; ++r) rl[r] = __builtin_amdgcn_rcpf(lones[t][r]);
#pragma unroll
    for (int n = 0; n < 4; ++n)
#pragma unroll
      for (int r = 0; r < 4; ++r) {
        size_t q = (size_t)b * Tt + qbase0 + t * 16 + quad * 4 + r;
        ao[q * Dd + h * Hd + n * 16 + col] = (bf16)(oacc[t][n][r] * rl[r]);
      }
  }
}

// --------------------------------------------------------------------- launcher
extern "C" void kernel_launch(void* const* d_in, const int* in_sizes, int n_in,
                              void* d_out, int out_size, void* d_ws, size_t ws_size,
                              hipStream_t stream) {
  const float* x = (const float*)d_in[0];
  const unsigned char* mask = (const unsigned char*)d_in[1];
  const float* Wq = (const float*)d_in[2];
  const float* bq = (const float*)d_in[3];
  const float* Wk = (const float*)d_in[4];
  const float* bk = (const float*)d_in[5];
  const float* Wv = (const float*)d_in[6];
  const float* bv = (const float*)d_in[7];
  const float* Wo = (const float*)d_in[8];
  const float* bo = (const float*)d_in[9];
  float* out = (float*)d_out;

  char* ws = (char*)d_ws;
  size_t off = 0;
  auto alloc = [&](size_t bytes) {
    char* p = ws + off;
    off += (bytes + 255) & ~(size_t)255;
    return p;
  };
  bf16* xb  = (bf16*)alloc((size_t)Mrows * Dd * 2);        // 16.8MB (reused as AO)
  bf16* Wt  = (bf16*)alloc((size_t)3 * Dd * Dd * 2);       // 6.3MB  packed [3072][1024]
  bf16* Wot = (bf16*)alloc((size_t)Dd * Dd * 2);           // 2.1MB
  bf16* QK  = (bf16*)alloc((size_t)Mrows * 2048 * 2);      // 33.6MB [8192][2048]
  bf16* Vt  = (bf16*)alloc((size_t)Bb * Hh * Hd * Tt * 2); // 16.8MB
  float* bqkv = (float*)alloc((size_t)3 * Dd * 4);

  cast_f32_bf16_kernel<<<Mrows * Dd / (256 * 8), 256, 0, stream>>>(x, xb);
  transpose_cast_w4_kernel<<<dim3(16, 16, 4), 256, 0, stream>>>(Wq, Wk, Wv, Wo, Wt, Wot);
  pack_bias_kernel<<<12, 256, 0, stream>>>(bq, bk, bv, bqkv);

  gemm_qkv_kernel<<<dim3(Mrows / QBM, 3 * Dd / QBN), 512, 0, stream>>>(
      xb, Wt, bqkv, QK, Vt);

  bf16* AO = xb;  // xb dead after QKV GEMM
  flash_attn_kernel<<<dim3(1024), 256, 0, stream>>>(QK, Vt, mask, AO);
  gemm_bf16_kernel<<<dim3(Mrows / 128, Dd / 128), 256, 0, stream>>>(
      AO, Wot, bo, out, Mrows, Dd, Dd);
}

// Round 9
// 280.988 us; speedup vs baseline: 1.5941x; 1.5941x over previous
//
#include <hip/hip_runtime.h>

using bf16 = __bf16;
typedef bf16 bf16x4 __attribute__((ext_vector_type(4)));
typedef bf16 bf16x8 __attribute__((ext_vector_type(8)));
typedef float f32x4 __attribute__((ext_vector_type(4)));
typedef float f32x8 __attribute__((ext_vector_type(8)));

#define MFMA16(a, b, c) __builtin_amdgcn_mfma_f32_16x16x32_bf16(a, b, c, 0, 0, 0)

constexpr int Bb = 4, Tt = 2048, Dd = 1024, Hh = 16, Hd = 64;
constexpr int Mrows = Bb * Tt;                 // 8192
constexpr float CEXP = 0.18033688011112042f;   // (1/sqrt(64)) * log2(e), folded into Wq/bq

// async global->LDS, 16B per lane; LDS dst = wave-uniform base + lane*16 [m97/m104]
__device__ __forceinline__ void gload_lds16(const bf16* g, bf16* lds_base) {
  __builtin_amdgcn_global_load_lds((const __attribute__((address_space(1))) void*)g,
                                   (__attribute__((address_space(3))) void*)lds_base,
                                   16, 0, 0);
}

// ---------------------------------------------------------------- cast x -> bf16
__global__ void cast_f32_bf16_kernel(const float* __restrict__ in, bf16* __restrict__ out) {
  size_t i = ((size_t)blockIdx.x * 256 + threadIdx.x) * 8;
  f32x8 v = *(const f32x8*)(in + i);
  *(bf16x8*)(out + i) = __builtin_convertvector(v, bf16x8);
}

// ---- fused transpose+cast of all four weight matrices: W[k][n] f32 -> Wt[n][k] bf16
__global__ void transpose_cast_w4_kernel(const float* __restrict__ Wq, const float* __restrict__ Wk,
                                         const float* __restrict__ Wv, const float* __restrict__ Wo,
                                         bf16* __restrict__ Wt, bf16* __restrict__ Wot) {
  __shared__ alignas(16) float tile[64][68];
  const int tid = threadIdx.x;
  const int n0 = blockIdx.x * 64, k0 = blockIdx.y * 64, z = blockIdx.z;
  const float* W = (z == 0) ? Wq : (z == 1) ? Wk : (z == 2) ? Wv : Wo;
  bf16* dst = (z == 3) ? Wot : (Wt + (size_t)z * Dd * Dd);
  const float scale = (z == 0) ? CEXP : 1.0f;
#pragma unroll
  for (int it = 0; it < 4; ++it) {
    int chunk = tid + it * 256;
    int kr = chunk >> 4, c4 = chunk & 15;
    f32x4 v = *(const f32x4*)(W + (size_t)(k0 + kr) * Dd + n0 + c4 * 4);
    *(f32x4*)&tile[kr][c4 * 4] = v * scale;
  }
  __syncthreads();
#pragma unroll
  for (int it = 0; it < 2; ++it) {
    int chunk = tid + it * 256;
    int n = chunk & 63, k8 = chunk >> 6;
    bf16x8 o;
#pragma unroll
    for (int j = 0; j < 8; ++j) o[j] = (bf16)tile[k8 * 8 + j][n];
    *(bf16x8*)(dst + (size_t)(n0 + n) * Dd + k0 + k8 * 8) = o;
  }
}

// ---------------------------------------------------------------- pack qkv bias
__global__ void pack_bias_kernel(const float* __restrict__ bq, const float* __restrict__ bk,
                                 const float* __restrict__ bv, float* __restrict__ outb) {
  int i = blockIdx.x * 256 + threadIdx.x;
  float v = (i < 1024) ? bq[i] * CEXP : (i < 2048 ? bk[i - 1024] : bv[i - 2048]);
  outb[i] = v;
}

// --------- QKV GEMM v2: 128x256 tile / 512 threads / 8 waves (2M x 4N), BK=32.
// 3-slot LDS ring (72 KiB), counted vmcnt(3), one raw s_barrier per tile.
constexpr int QBM = 128, QBN = 256, QBK = 32, QNT = Dd / QBK;  // 32 K-tiles

#define VMW(n) asm volatile("s_waitcnt vmcnt(" #n ")" ::: "memory")

__global__ __launch_bounds__(512, 2)
void gemm_qkv_kernel(const bf16* __restrict__ A, const bf16* __restrict__ Bt,
                     const float* __restrict__ bias, bf16* __restrict__ QK,
                     bf16* __restrict__ Vt) {
  constexpr int KD = Dd;
  __shared__ alignas(16) bf16 As[3][QBM * QBK];   // 3 x 8 KiB
  __shared__ alignas(16) bf16 Bs[3][QBN * QBK];   // 3 x 16 KiB  (72 KiB total)
  const int tid = threadIdx.x;
  const int lane = tid & 63, wave = tid >> 6;
  const int col = lane & 15, quad = lane >> 4;
  const int wr = wave >> 2, wc = wave & 3;        // wave tile: 64 x 64
  const size_t m0 = (size_t)blockIdx.x * QBM, n0 = (size_t)blockIdx.y * QBN;

  // staging source pre-swizzle (rule #21): lane l writes LDS vrow (g*8 + l>>3),
  // phys pos (l&7); fetch logical chunk u = (l&7)^(l>>3):
  const int u = (lane & 7) ^ (lane >> 3);
  const int srow = 2 * (lane >> 3) + (u >> 2);    // row within 16-row group
  const int scol = (u & 3) * 8;                   // element col within 32
  const bf16* Abase = A + (m0 + srow) * (size_t)KD + scol;
  const bf16* Bbase = Bt + (n0 + srow) * (size_t)KD + scol;

  // swizzled fragment read base: row R -> vrow R>>1, pos ((R&1)*4 | quad) ^ (vrow&7)
  const int pswz = (((col & 1) << 2) | quad) ^ (col >> 1);
  const int afb = wr * 2048 + (col >> 1) * 64 + pswz * 8;  // + i*512
  const int bfb = wc * 2048 + (col >> 1) * 64 + pswz * 8;  // + j*512

  f32x4 acc[4][4];
#pragma unroll
  for (int i = 0; i < 4; ++i)
#pragma unroll
    for (int j = 0; j < 4; ++j)
#pragma unroll
      for (int r = 0; r < 4; ++r) acc[i][j][r] = 0.f;

  // per wave per tile: 1 A gload (16 rows) + 2 B gloads (32 rows)
#define QSTAGE(t, sl) do { \
    gload_lds16(Abase + (size_t)(t) * QBK + (size_t)(wave * 16) * KD, &As[sl][wave * 512]); \
    gload_lds16(Bbase + (size_t)(t) * QBK + (size_t)(2 * wave) * 16 * KD, &Bs[sl][(2 * wave) * 512]); \
    gload_lds16(Bbase + (size_t)(t) * QBK + (size_t)(2 * wave + 1) * 16 * KD, &Bs[sl][(2 * wave + 1) * 512]); \
  } while (0)

#define QKV_TILE(cur, DOSTAGE, VM) do { \
    bf16x8 af[4], bfv[4]; \
    _Pragma("unroll") for (int j = 0; j < 4; ++j) bfv[j] = *(const bf16x8*)&Bs[cur][bfb + j * 512]; \
    _Pragma("unroll") for (int i = 0; i < 4; ++i) af[i] = *(const bf16x8*)&As[cur][afb + i * 512]; \
    DOSTAGE; \
    asm volatile("s_waitcnt lgkmcnt(0)" ::: "memory"); \
    __builtin_amdgcn_s_setprio(1); \
    _Pragma("unroll") for (int i = 0; i < 4; ++i) \
      _Pragma("unroll") for (int j = 0; j < 4; ++j) acc[i][j] = MFMA16(af[i], bfv[j], acc[i][j]); \
    __builtin_amdgcn_s_setprio(0); \
    VM; \
    __builtin_amdgcn_s_barrier(); \
  } while (0)

  // prologue: stage tiles 0,1 (6 loads/wave outstanding); wait oldest 3 = tile 0
  QSTAGE(0, 0);
  QSTAGE(1, 1);
  VMW(3);
  __builtin_amdgcn_s_barrier();

#pragma unroll 1
  for (int t = 0; t < QNT - 2; t += 3) {          // tiles 0..29 (30 % 3 == 0)
    QKV_TILE(0, QSTAGE(t + 2, 2), VMW(3));
    QKV_TILE(1, QSTAGE(t + 3, 0), VMW(3));
    QKV_TILE(2, QSTAGE(t + 4, 1), VMW(3));
  }
  QKV_TILE(0, (void)0, VMW(0));                   // tile 30: only tile 31 in flight
  QKV_TILE(1, (void)0, (void)0);                  // tile 31

  if (n0 < 2048) {      // Q/K block -> compact [8192][2048] buffer
#pragma unroll
    for (int i = 0; i < 4; ++i)
#pragma unroll
      for (int j = 0; j < 4; ++j) {
        size_t row = m0 + wr * 64 + i * 16 + quad * 4;
        size_t c = n0 + wc * 64 + j * 16 + col;
        float bv = bias[c];
#pragma unroll
        for (int r = 0; r < 4; ++r) QK[(row + r) * 2048 + c] = (bf16)(acc[i][j][r] + bv);
      }
  } else {              // V block -> Vt[b][h][d][t], packed along t
#pragma unroll
    for (int i = 0; i < 4; ++i)
#pragma unroll
      for (int j = 0; j < 4; ++j) {
        size_t row = m0 + wr * 64 + i * 16 + quad * 4;
        int c = (int)(n0 + wc * 64 + j * 16 + col);
        float bv = bias[c];
        int dall = c - 2048, hh = dall >> 6, dd = dall & 63;
        int bi = (int)(row >> 11), trow = (int)(row & 2047);
        bf16x4 pk;
#pragma unroll
        for (int r = 0; r < 4; ++r) pk[r] = (bf16)(acc[i][j][r] + bv);
        *(bf16x4*)&Vt[((size_t)(bi * Hh + hh) * Hd + dd) * Tt + trow] = pk;
      }
  }
#undef QKV_TILE
#undef QSTAGE
}

// ---------- out-projection GEMM: same ring template, f32 output. 128x256 tile,
// grid 64x4 = 256 blocks = EXACTLY one dispatch round (old 128^2: 512 blocks,
// 2 rounds, __syncthreads-drain 2-phase structure = m233 stall).
__global__ __launch_bounds__(512, 2)
void gemm_out_kernel(const bf16* __restrict__ A, const bf16* __restrict__ Bt,
                     const float* __restrict__ bias, float* __restrict__ C) {
  constexpr int KD = Dd, NN = Dd;
  __shared__ alignas(16) bf16 As[3][QBM * QBK];
  __shared__ alignas(16) bf16 Bs[3][QBN * QBK];
  const int tid = threadIdx.x;
  const int lane = tid & 63, wave = tid >> 6;
  const int col = lane & 15, quad = lane >> 4;
  const int wr = wave >> 2, wc = wave & 3;        // wave tile: 64 x 64
  const size_t m0 = (size_t)blockIdx.x * QBM, n0 = (size_t)blockIdx.y * QBN;

  const int u = (lane & 7) ^ (lane >> 3);
  const int srow = 2 * (lane >> 3) + (u >> 2);
  const int scol = (u & 3) * 8;
  const bf16* Abase = A + (m0 + srow) * (size_t)KD + scol;
  const bf16* Bbase = Bt + (n0 + srow) * (size_t)KD + scol;

  const int pswz = (((col & 1) << 2) | quad) ^ (col >> 1);
  const int afb = wr * 2048 + (col >> 1) * 64 + pswz * 8;
  const int bfb = wc * 2048 + (col >> 1) * 64 + pswz * 8;

  f32x4 acc[4][4];
#pragma unroll
  for (int i = 0; i < 4; ++i)
#pragma unroll
    for (int j = 0; j < 4; ++j)
#pragma unroll
      for (int r = 0; r < 4; ++r) acc[i][j][r] = 0.f;

#define OSTAGE(t, sl) do { \
    gload_lds16(Abase + (size_t)(t) * QBK + (size_t)(wave * 16) * KD, &As[sl][wave * 512]); \
    gload_lds16(Bbase + (size_t)(t) * QBK + (size_t)(2 * wave) * 16 * KD, &Bs[sl][(2 * wave) * 512]); \
    gload_lds16(Bbase + (size_t)(t) * QBK + (size_t)(2 * wave + 1) * 16 * KD, &Bs[sl][(2 * wave + 1) * 512]); \
  } while (0)

#define OUT_TILE(cur, DOSTAGE, VM) do { \
    bf16x8 af[4], bfv[4]; \
    _Pragma("unroll") for (int j = 0; j < 4; ++j) bfv[j] = *(const bf16x8*)&Bs[cur][bfb + j * 512]; \
    _Pragma("unroll") for (int i = 0; i < 4; ++i) af[i] = *(const bf16x8*)&As[cur][afb + i * 512]; \
    DOSTAGE; \
    asm volatile("s_waitcnt lgkmcnt(0)" ::: "memory"); \
    __builtin_amdgcn_s_setprio(1); \
    _Pragma("unroll") for (int i = 0; i < 4; ++i) \
      _Pragma("unroll") for (int j = 0; j < 4; ++j) acc[i][j] = MFMA16(af[i], bfv[j], acc[i][j]); \
    __builtin_amdgcn_s_setprio(0); \
    VM; \
    __builtin_amdgcn_s_barrier(); \
  } while (0)

  OSTAGE(0, 0);
  OSTAGE(1, 1);
  VMW(3);
  __builtin_amdgcn_s_barrier();

#pragma unroll 1
  for (int t = 0; t < QNT - 2; t += 3) {          // tiles 0..29
    OUT_TILE(0, OSTAGE(t + 2, 2), VMW(3));
    OUT_TILE(1, OSTAGE(t + 3, 0), VMW(3));
    OUT_TILE(2, OSTAGE(t + 4, 1), VMW(3));
  }
  OUT_TILE(0, (void)0, VMW(0));                   // tile 30
  OUT_TILE(1, (void)0, (void)0);                  // tile 31

#pragma unroll
  for (int i = 0; i < 4; ++i)
#pragma unroll
    for (int j = 0; j < 4; ++j) {
      size_t row = m0 + wr * 64 + i * 16 + quad * 4;
      size_t c = n0 + wc * 64 + j * 16 + col;
      float bv = bias[c];
#pragma unroll
      for (int r = 0; r < 4; ++r) C[(row + r) * (size_t)NN + c] = acc[i][j][r] + bv;
    }
#undef OUT_TILE
#undef OSTAGE
}

// ----------------------------------------------- flash attention v3 (R6, 91.6us —
// best of session; exact revert of the R8 direct-global-V regression: scattered
// 8B V loads = 256 small L2 reqs/wave/iter, MfmaUtil 12%). 1024 blocks, (256,2),
// ones-MFMA denominator, 3-slot K/V LDS ring with counted vmcnt(4), no setprio
// (R5: lockstep waves = m190 null case).
__global__ __launch_bounds__(256, 2)
void flash_attn_kernel(const bf16* __restrict__ qk, const bf16* __restrict__ vt,
                       const unsigned char* __restrict__ mask, bf16* __restrict__ ao) {
  __shared__ alignas(16) bf16 Ks[3][64 * 64];      // [key][slot^], xor-swizzled 16B slots
  __shared__ alignas(16) bf16 Vs[3][64 * 64];      // [d][slot^]

  const int tid = threadIdx.x;
  const int wave = tid >> 6, lane = tid & 63;
  const int col = lane & 15, quad = lane >> 4;
  const int id = blockIdx.x;
  const int hb = id & 63, qi = id >> 6;            // same-head blocks stride 64 -> same XCD
  const int h = hb & 15, b = hb >> 4;
  const int qbase0 = qi * 128 + wave * 32;

  const bf16* Qp = qk + (size_t)(b * Tt) * 2048 + h * Hd;
  const bf16* Kp = Qp + 1024;
  const bf16* Vp = vt + ((size_t)(b * Hh + h) * Hd) * Tt;
  const unsigned char* mp = mask + b * Tt;

  unsigned long long anym;
  {
    const unsigned long long* mq = (const unsigned long long*)mp;
    unsigned long long acc = 0;
#pragma unroll
    for (int j = 0; j < 4; ++j) acc |= mq[lane * 4 + j];
    anym = __ballot(acc != 0ull);
  }

  // Q fragments (pre-scaled by CEXP): free index = query
  bf16x8 qf[2][2];
#pragma unroll
  for (int t = 0; t < 2; ++t)
#pragma unroll
    for (int kk = 0; kk < 2; ++kk)
      qf[t][kk] = *(const bf16x8*)(Qp + (size_t)(qbase0 + t * 16 + col) * 2048 + kk * 32 + quad * 8);

  // gload_lds staging: wave w stages 1KB chunks g in {2w, 2w+1} of K and of V.
  // lane l -> LDS row g*8 + (l>>3), phys pos l&7; fetch logical chunk u = (l&7)^(l>>3).
  const int u = (lane & 7) ^ (lane >> 3);
  const int g0 = 2 * wave, g1 = 2 * wave + 1;
  const bf16* Ksrc0 = Kp + (size_t)(g0 * 8 + (lane >> 3)) * 2048 + u * 8;
  const bf16* Ksrc1 = Kp + (size_t)(g1 * 8 + (lane >> 3)) * 2048 + u * 8;
  const bf16* Vsrc0 = Vp + (size_t)(g0 * 8 + (lane >> 3)) * 2048 + u * 8;
  const bf16* Vsrc1 = Vp + (size_t)(g1 * 8 + (lane >> 3)) * 2048 + u * 8;

#define FSTAGE(t, sl) do { \
    gload_lds16(Ksrc0 + (size_t)(t) * 64 * 2048, &Ks[sl][g0 * 512]); \
    gload_lds16(Ksrc1 + (size_t)(t) * 64 * 2048, &Ks[sl][g1 * 512]); \
    gload_lds16(Vsrc0 + (t) * 64, &Vs[sl][g0 * 512]); \
    gload_lds16(Vsrc1 + (t) * 64, &Vs[sl][g1 * 512]); \
  } while (0)

  f32x4 oacc[2][4];
  f32x4 lones[2];
#pragma unroll
  for (int t = 0; t < 2; ++t) {
#pragma unroll
    for (int r = 0; r < 4; ++r) lones[t][r] = 0.f;
#pragma unroll
    for (int n = 0; n < 4; ++n)
#pragma unroll
      for (int r = 0; r < 4; ++r) oacc[t][n][r] = 0.f;
  }
  const f32x4 zero4 = {0.f, 0.f, 0.f, 0.f};
  bf16x8 onev;
#pragma unroll
  for (int j = 0; j < 8; ++j) onev[j] = (bf16)1.0f;

  const int fslot0 = ((0 * 4 + quad) ^ (col & 7)) * 8;   // b128 frag slots (kf)
  const int fslot1 = ((1 * 4 + quad) ^ (col & 7)) * 8;
  const int voff = (quad & 1) * 4;

// one KV-tile: {issue stage for tile II+2, ds_read kf/vfs from slot cur, QK^T,
// mask, exp2, pack, PV + ones-MFMA, counted vmcnt, barrier}
#define FITER(cur, II, DOSTAGE, VM) do { \
    const int kb = (II) * 64; \
    DOSTAGE; \
    bf16x8 kf[4][2], vfs[4][2]; \
    _Pragma("unroll") for (int kt = 0; kt < 4; ++kt) { \
      kf[kt][0] = *(const bf16x8*)&Ks[cur][(kt * 16 + col) * 64 + fslot0]; \
      kf[kt][1] = *(const bf16x8*)&Ks[cur][(kt * 16 + col) * 64 + fslot1]; \
    } \
    _Pragma("unroll") for (int n = 0; n < 4; ++n) { \
      const int row = (n * 16 + col) * 64; \
      const int rx = col & 7; \
      _Pragma("unroll") for (int kk = 0; kk < 2; ++kk) { \
        bf16x4 lo = *(const bf16x4*)&Vs[cur][row + ((kk * 4 + 0 + (quad >> 1)) ^ rx) * 8 + voff]; \
        bf16x4 hi = *(const bf16x4*)&Vs[cur][row + ((kk * 4 + 2 + (quad >> 1)) ^ rx) * 8 + voff]; \
        vfs[n][kk] = __builtin_shufflevector(lo, hi, 0, 1, 2, 3, 4, 5, 6, 7); \
      } \
    } \
    _Pragma("unroll") for (int t = 0; t < 2; ++t) { \
      f32x4 s[4]; \
      _Pragma("unroll") for (int kt = 0; kt < 4; ++kt) s[kt] = MFMA16(kf[kt][0], qf[t][0], zero4); \
      _Pragma("unroll") for (int kt = 0; kt < 4; ++kt) s[kt] = MFMA16(kf[kt][1], qf[t][1], s[kt]); \
      if ((anym >> (2 * (II))) & 3ull) { \
        _Pragma("unroll") for (int kt = 0; kt < 4; ++kt) \
          _Pragma("unroll") for (int r = 0; r < 4; ++r) \
            if (mp[kb + kt * 16 + quad * 4 + r] != 0) s[kt][r] = -1e9f; \
      } \
      f32x4 e[4]; \
      _Pragma("unroll") for (int kt = 0; kt < 4; ++kt) \
        _Pragma("unroll") for (int r = 0; r < 4; ++r) e[kt][r] = __builtin_amdgcn_exp2f(s[kt][r]); \
      bf16x4 c0 = __builtin_convertvector(e[0], bf16x4); \
      bf16x4 c1 = __builtin_convertvector(e[1], bf16x4); \
      bf16x4 c2 = __builtin_convertvector(e[2], bf16x4); \
      bf16x4 c3 = __builtin_convertvector(e[3], bf16x4); \
      bf16x8 pf0 = __builtin_shufflevector(c0, c1, 0, 1, 2, 3, 4, 5, 6, 7); \
      bf16x8 pf1 = __builtin_shufflevector(c2, c3, 0, 1, 2, 3, 4, 5, 6, 7); \
      _Pragma("unroll") for (int n = 0; n < 4; ++n) { \
        oacc[t][n] = MFMA16(pf0, vfs[n][0], oacc[t][n]); \
        oacc[t][n] = MFMA16(pf1, vfs[n][1], oacc[t][n]); \
      } \
      lones[t] = MFMA16(pf0, onev, lones[t]); \
      lones[t] = MFMA16(pf1, onev, lones[t]); \
    } \
    VM; \
    __builtin_amdgcn_s_barrier(); \
  } while (0)

  // prologue: stage tiles 0,1 (8 loads outstanding); wait oldest 4 = tile 0
  FSTAGE(0, 0);
  FSTAGE(1, 1);
  VMW(4);
  __builtin_amdgcn_s_barrier();

#pragma unroll 1
  for (int ii = 0; ii < 30; ii += 3) {            // tiles 0..29
    FITER(0, ii + 0, FSTAGE(ii + 2, 2), VMW(4));
    FITER(1, ii + 1, FSTAGE(ii + 3, 0), VMW(4));
    FITER(2, ii + 2, FSTAGE(ii + 4, 1), VMW(4));
  }
  FITER(0, 30, (void)0, VMW(0));                  // tile 30: tile 31 must land
  FITER(1, 31, (void)0, (void)0);                 // tile 31

#undef FITER
#undef FSTAGE

  // epilogue: no cross-lane transpose needed; lones rows == oacc rows
#pragma unroll
  for (int t = 0; t < 2; ++t) {
    f32x4 rl;
#pragma unroll
    for (int r = 0; r < 4; ++r) rl[r] = __builtin_amdgcn_rcpf(lones[t][r]);
#pragma unroll
    for (int n = 0; n < 4; ++n)
#pragma unroll
      for (int r = 0; r < 4; ++r) {
        size_t q = (size_t)b * Tt + qbase0 + t * 16 + quad * 4 + r;
        ao[q * Dd + h * Hd + n * 16 + col] = (bf16)(oacc[t][n][r] * rl[r]);
      }
  }
}

// --------------------------------------------------------------------- launcher
extern "C" void kernel_launch(void* const* d_in, const int* in_sizes, int n_in,
                              void* d_out, int out_size, void* d_ws, size_t ws_size,
                              hipStream_t stream) {
  const float* x = (const float*)d_in[0];
  const unsigned char* mask = (const unsigned char*)d_in[1];
  const float* Wq = (const float*)d_in[2];
  const float* bq = (const float*)d_in[3];
  const float* Wk = (const float*)d_in[4];
  const float* bk = (const float*)d_in[5];
  const float* Wv = (const float*)d_in[6];
  const float* bv = (const float*)d_in[7];
  const float* Wo = (const float*)d_in[8];
  const float* bo = (const float*)d_in[9];
  float* out = (float*)d_out;

  char* ws = (char*)d_ws;
  size_t off = 0;
  auto alloc = [&](size_t bytes) {
    char* p = ws + off;
    off += (bytes + 255) & ~(size_t)255;
    return p;
  };
  bf16* xb  = (bf16*)alloc((size_t)Mrows * Dd * 2);        // 16.8MB (reused as AO)
  bf16* Wt  = (bf16*)alloc((size_t)3 * Dd * Dd * 2);       // 6.3MB  packed [3072][1024]
  bf16* Wot = (bf16*)alloc((size_t)Dd * Dd * 2);           // 2.1MB
  bf16* QK  = (bf16*)alloc((size_t)Mrows * 2048 * 2);      // 33.6MB [8192][2048]
  bf16* Vt  = (bf16*)alloc((size_t)Bb * Hh * Hd * Tt * 2); // 16.8MB
  float* bqkv = (float*)alloc((size_t)3 * Dd * 4);

  cast_f32_bf16_kernel<<<Mrows * Dd / (256 * 8), 256, 0, stream>>>(x, xb);
  transpose_cast_w4_kernel<<<dim3(16, 16, 4), 256, 0, stream>>>(Wq, Wk, Wv, Wo, Wt, Wot);
  pack_bias_kernel<<<12, 256, 0, stream>>>(bq, bk, bv, bqkv);

  gemm_qkv_kernel<<<dim3(Mrows / QBM, 3 * Dd / QBN), 512, 0, stream>>>(
      xb, Wt, bqkv, QK, Vt);

  bf16* AO = xb;  // xb dead after QKV GEMM
  flash_attn_kernel<<<dim3(1024), 256, 0, stream>>>(QK, Vt, mask, AO);
  gemm_out_kernel<<<dim3(Mrows / QBM, Dd / QBN), 512, 0, stream>>>(
      AO, Wot, bo, out);
}

// Round 10
// 265.254 us; speedup vs baseline: 1.6887x; 1.0593x over previous
//
#include <hip/hip_runtime.h>

using bf16 = __bf16;
typedef bf16 bf16x4 __attribute__((ext_vector_type(4)));
typedef bf16 bf16x8 __attribute__((ext_vector_type(8)));
typedef float f32x4 __attribute__((ext_vector_type(4)));
typedef float f32x8 __attribute__((ext_vector_type(8)));

#define MFMA16(a, b, c) __builtin_amdgcn_mfma_f32_16x16x32_bf16(a, b, c, 0, 0, 0)

constexpr int Bb = 4, Tt = 2048, Dd = 1024, Hh = 16, Hd = 64;
constexpr int Mrows = Bb * Tt;                 // 8192
constexpr float CEXP = 0.18033688011112042f;   // (1/sqrt(64)) * log2(e), folded into Wq/bq

// async global->LDS, 16B per lane; LDS dst = wave-uniform base + lane*16 [m97/m104]
__device__ __forceinline__ void gload_lds16(const bf16* g, bf16* lds_base) {
  __builtin_amdgcn_global_load_lds((const __attribute__((address_space(1))) void*)g,
                                   (__attribute__((address_space(3))) void*)lds_base,
                                   16, 0, 0);
}

// ---------------------------------------------------------------- cast x -> bf16
__global__ void cast_f32_bf16_kernel(const float* __restrict__ in, bf16* __restrict__ out) {
  size_t i = ((size_t)blockIdx.x * 256 + threadIdx.x) * 8;
  f32x8 v = *(const f32x8*)(in + i);
  *(bf16x8*)(out + i) = __builtin_convertvector(v, bf16x8);
}

// ---- fused transpose+cast of all four weight matrices: W[k][n] f32 -> Wt[n][k] bf16
__global__ void transpose_cast_w4_kernel(const float* __restrict__ Wq, const float* __restrict__ Wk,
                                         const float* __restrict__ Wv, const float* __restrict__ Wo,
                                         bf16* __restrict__ Wt, bf16* __restrict__ Wot) {
  __shared__ alignas(16) float tile[64][68];
  const int tid = threadIdx.x;
  const int n0 = blockIdx.x * 64, k0 = blockIdx.y * 64, z = blockIdx.z;
  const float* W = (z == 0) ? Wq : (z == 1) ? Wk : (z == 2) ? Wv : Wo;
  bf16* dst = (z == 3) ? Wot : (Wt + (size_t)z * Dd * Dd);
  const float scale = (z == 0) ? CEXP : 1.0f;
#pragma unroll
  for (int it = 0; it < 4; ++it) {
    int chunk = tid + it * 256;
    int kr = chunk >> 4, c4 = chunk & 15;
    f32x4 v = *(const f32x4*)(W + (size_t)(k0 + kr) * Dd + n0 + c4 * 4);
    *(f32x4*)&tile[kr][c4 * 4] = v * scale;
  }
  __syncthreads();
#pragma unroll
  for (int it = 0; it < 2; ++it) {
    int chunk = tid + it * 256;
    int n = chunk & 63, k8 = chunk >> 6;
    bf16x8 o;
#pragma unroll
    for (int j = 0; j < 8; ++j) o[j] = (bf16)tile[k8 * 8 + j][n];
    *(bf16x8*)(dst + (size_t)(n0 + n) * Dd + k0 + k8 * 8) = o;
  }
}

// ---------------------------------------------------------------- pack qkv bias
__global__ void pack_bias_kernel(const float* __restrict__ bq, const float* __restrict__ bk,
                                 const float* __restrict__ bv, float* __restrict__ outb) {
  int i = blockIdx.x * 256 + threadIdx.x;
  float v = (i < 1024) ? bq[i] * CEXP : (i < 2048 ? bk[i - 1024] : bv[i - 2048]);
  outb[i] = v;
}

// --------- QKV GEMM v2: 128x256 tile / 512 threads / 8 waves (2M x 4N), BK=32.
// 3-slot LDS ring (72 KiB), counted vmcnt(3), one raw s_barrier per tile.
constexpr int QBM = 128, QBN = 256, QBK = 32, QNT = Dd / QBK;  // 32 K-tiles

#define VMW(n) asm volatile("s_waitcnt vmcnt(" #n ")" ::: "memory")

__global__ __launch_bounds__(512, 2)
void gemm_qkv_kernel(const bf16* __restrict__ A, const bf16* __restrict__ Bt,
                     const float* __restrict__ bias, bf16* __restrict__ QK,
                     bf16* __restrict__ Vt) {
  constexpr int KD = Dd;
  __shared__ alignas(16) bf16 As[3][QBM * QBK];   // 3 x 8 KiB
  __shared__ alignas(16) bf16 Bs[3][QBN * QBK];   // 3 x 16 KiB  (72 KiB total)
  const int tid = threadIdx.x;
  const int lane = tid & 63, wave = tid >> 6;
  const int col = lane & 15, quad = lane >> 4;
  const int wr = wave >> 2, wc = wave & 3;        // wave tile: 64 x 64
  const size_t m0 = (size_t)blockIdx.x * QBM, n0 = (size_t)blockIdx.y * QBN;

  // staging source pre-swizzle (rule #21): lane l writes LDS vrow (g*8 + l>>3),
  // phys pos (l&7); fetch logical chunk u = (l&7)^(l>>3):
  const int u = (lane & 7) ^ (lane >> 3);
  const int srow = 2 * (lane >> 3) + (u >> 2);    // row within 16-row group
  const int scol = (u & 3) * 8;                   // element col within 32
  const bf16* Abase = A + (m0 + srow) * (size_t)KD + scol;
  const bf16* Bbase = Bt + (n0 + srow) * (size_t)KD + scol;

  // swizzled fragment read base: row R -> vrow R>>1, pos ((R&1)*4 | quad) ^ (vrow&7)
  const int pswz = (((col & 1) << 2) | quad) ^ (col >> 1);
  const int afb = wr * 2048 + (col >> 1) * 64 + pswz * 8;  // + i*512
  const int bfb = wc * 2048 + (col >> 1) * 64 + pswz * 8;  // + j*512

  f32x4 acc[4][4];
#pragma unroll
  for (int i = 0; i < 4; ++i)
#pragma unroll
    for (int j = 0; j < 4; ++j)
#pragma unroll
      for (int r = 0; r < 4; ++r) acc[i][j][r] = 0.f;

  // per wave per tile: 1 A gload (16 rows) + 2 B gloads (32 rows)
#define QSTAGE(t, sl) do { \
    gload_lds16(Abase + (size_t)(t) * QBK + (size_t)(wave * 16) * KD, &As[sl][wave * 512]); \
    gload_lds16(Bbase + (size_t)(t) * QBK + (size_t)(2 * wave) * 16 * KD, &Bs[sl][(2 * wave) * 512]); \
    gload_lds16(Bbase + (size_t)(t) * QBK + (size_t)(2 * wave + 1) * 16 * KD, &Bs[sl][(2 * wave + 1) * 512]); \
  } while (0)

#define QKV_TILE(cur, DOSTAGE, VM) do { \
    bf16x8 af[4], bfv[4]; \
    _Pragma("unroll") for (int j = 0; j < 4; ++j) bfv[j] = *(const bf16x8*)&Bs[cur][bfb + j * 512]; \
    _Pragma("unroll") for (int i = 0; i < 4; ++i) af[i] = *(const bf16x8*)&As[cur][afb + i * 512]; \
    DOSTAGE; \
    asm volatile("s_waitcnt lgkmcnt(0)" ::: "memory"); \
    __builtin_amdgcn_s_setprio(1); \
    _Pragma("unroll") for (int i = 0; i < 4; ++i) \
      _Pragma("unroll") for (int j = 0; j < 4; ++j) acc[i][j] = MFMA16(af[i], bfv[j], acc[i][j]); \
    __builtin_amdgcn_s_setprio(0); \
    VM; \
    __builtin_amdgcn_s_barrier(); \
  } while (0)

  // prologue: stage tiles 0,1 (6 loads/wave outstanding); wait oldest 3 = tile 0
  QSTAGE(0, 0);
  QSTAGE(1, 1);
  VMW(3);
  __builtin_amdgcn_s_barrier();

#pragma unroll 1
  for (int t = 0; t < QNT - 2; t += 3) {          // tiles 0..29 (30 % 3 == 0)
    QKV_TILE(0, QSTAGE(t + 2, 2), VMW(3));
    QKV_TILE(1, QSTAGE(t + 3, 0), VMW(3));
    QKV_TILE(2, QSTAGE(t + 4, 1), VMW(3));
  }
  QKV_TILE(0, (void)0, VMW(0));                   // tile 30: only tile 31 in flight
  QKV_TILE(1, (void)0, (void)0);                  // tile 31

  if (n0 < 2048) {      // Q/K block -> compact [8192][2048] buffer
#pragma unroll
    for (int i = 0; i < 4; ++i)
#pragma unroll
      for (int j = 0; j < 4; ++j) {
        size_t row = m0 + wr * 64 + i * 16 + quad * 4;
        size_t c = n0 + wc * 64 + j * 16 + col;
        float bv = bias[c];
#pragma unroll
        for (int r = 0; r < 4; ++r) QK[(row + r) * 2048 + c] = (bf16)(acc[i][j][r] + bv);
      }
  } else {              // V block -> Vt[b][h][d][t], packed along t
#pragma unroll
    for (int i = 0; i < 4; ++i)
#pragma unroll
      for (int j = 0; j < 4; ++j) {
        size_t row = m0 + wr * 64 + i * 16 + quad * 4;
        int c = (int)(n0 + wc * 64 + j * 16 + col);
        float bv = bias[c];
        int dall = c - 2048, hh = dall >> 6, dd = dall & 63;
        int bi = (int)(row >> 11), trow = (int)(row & 2047);
        bf16x4 pk;
#pragma unroll
        for (int r = 0; r < 4; ++r) pk[r] = (bf16)(acc[i][j][r] + bv);
        *(bf16x4*)&Vt[((size_t)(bi * Hh + hh) * Hd + dd) * Tt + trow] = pk;
      }
  }
#undef QKV_TILE
#undef QSTAGE
}

// ---------- out-projection GEMM: ring template, f32 output, grid 64x4 = 256 blocks
__global__ __launch_bounds__(512, 2)
void gemm_out_kernel(const bf16* __restrict__ A, const bf16* __restrict__ Bt,
                     const float* __restrict__ bias, float* __restrict__ C) {
  constexpr int KD = Dd, NN = Dd;
  __shared__ alignas(16) bf16 As[3][QBM * QBK];
  __shared__ alignas(16) bf16 Bs[3][QBN * QBK];
  const int tid = threadIdx.x;
  const int lane = tid & 63, wave = tid >> 6;
  const int col = lane & 15, quad = lane >> 4;
  const int wr = wave >> 2, wc = wave & 3;        // wave tile: 64 x 64
  const size_t m0 = (size_t)blockIdx.x * QBM, n0 = (size_t)blockIdx.y * QBN;

  const int u = (lane & 7) ^ (lane >> 3);
  const int srow = 2 * (lane >> 3) + (u >> 2);
  const int scol = (u & 3) * 8;
  const bf16* Abase = A + (m0 + srow) * (size_t)KD + scol;
  const bf16* Bbase = Bt + (n0 + srow) * (size_t)KD + scol;

  const int pswz = (((col & 1) << 2) | quad) ^ (col >> 1);
  const int afb = wr * 2048 + (col >> 1) * 64 + pswz * 8;
  const int bfb = wc * 2048 + (col >> 1) * 64 + pswz * 8;

  f32x4 acc[4][4];
#pragma unroll
  for (int i = 0; i < 4; ++i)
#pragma unroll
    for (int j = 0; j < 4; ++j)
#pragma unroll
      for (int r = 0; r < 4; ++r) acc[i][j][r] = 0.f;

#define OSTAGE(t, sl) do { \
    gload_lds16(Abase + (size_t)(t) * QBK + (size_t)(wave * 16) * KD, &As[sl][wave * 512]); \
    gload_lds16(Bbase + (size_t)(t) * QBK + (size_t)(2 * wave) * 16 * KD, &Bs[sl][(2 * wave) * 512]); \
    gload_lds16(Bbase + (size_t)(t) * QBK + (size_t)(2 * wave + 1) * 16 * KD, &Bs[sl][(2 * wave + 1) * 512]); \
  } while (0)

#define OUT_TILE(cur, DOSTAGE, VM) do { \
    bf16x8 af[4], bfv[4]; \
    _Pragma("unroll") for (int j = 0; j < 4; ++j) bfv[j] = *(const bf16x8*)&Bs[cur][bfb + j * 512]; \
    _Pragma("unroll") for (int i = 0; i < 4; ++i) af[i] = *(const bf16x8*)&As[cur][afb + i * 512]; \
    DOSTAGE; \
    asm volatile("s_waitcnt lgkmcnt(0)" ::: "memory"); \
    __builtin_amdgcn_s_setprio(1); \
    _Pragma("unroll") for (int i = 0; i < 4; ++i) \
      _Pragma("unroll") for (int j = 0; j < 4; ++j) acc[i][j] = MFMA16(af[i], bfv[j], acc[i][j]); \
    __builtin_amdgcn_s_setprio(0); \
    VM; \
    __builtin_amdgcn_s_barrier(); \
  } while (0)

  OSTAGE(0, 0);
  OSTAGE(1, 1);
  VMW(3);
  __builtin_amdgcn_s_barrier();

#pragma unroll 1
  for (int t = 0; t < QNT - 2; t += 3) {          // tiles 0..29
    OUT_TILE(0, OSTAGE(t + 2, 2), VMW(3));
    OUT_TILE(1, OSTAGE(t + 3, 0), VMW(3));
    OUT_TILE(2, OSTAGE(t + 4, 1), VMW(3));
  }
  OUT_TILE(0, (void)0, VMW(0));                   // tile 30
  OUT_TILE(1, (void)0, (void)0);                  // tile 31

#pragma unroll
  for (int i = 0; i < 4; ++i)
#pragma unroll
    for (int j = 0; j < 4; ++j) {
      size_t row = m0 + wr * 64 + i * 16 + quad * 4;
      size_t c = n0 + wc * 64 + j * 16 + col;
      float bv = bias[c];
#pragma unroll
      for (int r = 0; r < 4; ++r) C[(row + r) * (size_t)NN + c] = acc[i][j][r] + bv;
    }
#undef OUT_TILE
#undef OSTAGE
}

// ----------------------------------------------- flash attention v6
// 4 q-tiles per wave (64 queries; 512 blocks = exactly one resident round at
// 2 blocks/CU), combining all session-proven pieces: ones-MFMA denominator,
// 3-slot K/V ring + counted vmcnt(4) (R6), per-kt QK^T and per-n PV register
// windows (R7). Rationale: R3's 64->32 q/wave halving doubled per-query
// staging/barrier/kf-vfs costs; this restores the amortization while keeping
// the later improvements. Persistent regs: qf32 + oacc64 + lones16 = 112;
// peak transient s[4][4]=64 + kf window 16 ~ 210 < 256 (2 waves/SIMD, no cap).
// Spill tripwire: WRITE_SIZE (16.4MB = clean).
__global__ __launch_bounds__(256, 2)
void flash_attn_kernel(const bf16* __restrict__ qk, const bf16* __restrict__ vt,
                       const unsigned char* __restrict__ mask, bf16* __restrict__ ao) {
  __shared__ alignas(16) bf16 Ks[3][64 * 64];      // [key][slot^], xor-swizzled 16B slots
  __shared__ alignas(16) bf16 Vs[3][64 * 64];      // [d][slot^]

  const int tid = threadIdx.x;
  const int wave = tid >> 6, lane = tid & 63;
  const int col = lane & 15, quad = lane >> 4;
  const int id = blockIdx.x;
  const int hb = id & 63, qi = id >> 6;            // same-head blocks stride 64 -> same XCD
  const int h = hb & 15, b = hb >> 4;
  const int qbase0 = qi * 256 + wave * 64;

  const bf16* Qp = qk + (size_t)(b * Tt) * 2048 + h * Hd;
  const bf16* Kp = Qp + 1024;
  const bf16* Vp = vt + ((size_t)(b * Hh + h) * Hd) * Tt;
  const unsigned char* mp = mask + b * Tt;

  unsigned long long anym;
  {
    const unsigned long long* mq = (const unsigned long long*)mp;
    unsigned long long acc = 0;
#pragma unroll
    for (int j = 0; j < 4; ++j) acc |= mq[lane * 4 + j];
    anym = __ballot(acc != 0ull);
  }

  // Q fragments (pre-scaled by CEXP): free index = query
  bf16x8 qf[4][2];
#pragma unroll
  for (int t = 0; t < 4; ++t)
#pragma unroll
    for (int kk = 0; kk < 2; ++kk)
      qf[t][kk] = *(const bf16x8*)(Qp + (size_t)(qbase0 + t * 16 + col) * 2048 + kk * 32 + quad * 8);

  // gload_lds staging: wave w stages 1KB chunks g in {2w, 2w+1} of K and of V.
  const int u = (lane & 7) ^ (lane >> 3);
  const int g0 = 2 * wave, g1 = 2 * wave + 1;
  const bf16* Ksrc0 = Kp + (size_t)(g0 * 8 + (lane >> 3)) * 2048 + u * 8;
  const bf16* Ksrc1 = Kp + (size_t)(g1 * 8 + (lane >> 3)) * 2048 + u * 8;
  const bf16* Vsrc0 = Vp + (size_t)(g0 * 8 + (lane >> 3)) * 2048 + u * 8;
  const bf16* Vsrc1 = Vp + (size_t)(g1 * 8 + (lane >> 3)) * 2048 + u * 8;

#define FSTAGE(t, sl) do { \
    gload_lds16(Ksrc0 + (size_t)(t) * 64 * 2048, &Ks[sl][g0 * 512]); \
    gload_lds16(Ksrc1 + (size_t)(t) * 64 * 2048, &Ks[sl][g1 * 512]); \
    gload_lds16(Vsrc0 + (t) * 64, &Vs[sl][g0 * 512]); \
    gload_lds16(Vsrc1 + (t) * 64, &Vs[sl][g1 * 512]); \
  } while (0)

  f32x4 oacc[4][4];
  f32x4 lones[4];
#pragma unroll
  for (int t = 0; t < 4; ++t) {
#pragma unroll
    for (int r = 0; r < 4; ++r) lones[t][r] = 0.f;
#pragma unroll
    for (int n = 0; n < 4; ++n)
#pragma unroll
      for (int r = 0; r < 4; ++r) oacc[t][n][r] = 0.f;
  }
  const f32x4 zero4 = {0.f, 0.f, 0.f, 0.f};
  bf16x8 onev;
#pragma unroll
  for (int j = 0; j < 8; ++j) onev[j] = (bf16)1.0f;

  const int fslot0 = ((0 * 4 + quad) ^ (col & 7)) * 8;   // b128 frag slots (kf)
  const int fslot1 = ((1 * 4 + quad) ^ (col & 7)) * 8;
  const int voff = (quad & 1) * 4;

// one KV-tile: {issue stage II+2; per-kt kf window -> QK^T all 4 q-tiles; mask;
// exp2 -> pf[4][2]; per-n vfs window -> PV all 4 tiles; ones-MFMA; counted vmcnt;
// barrier}
#define FITER(cur, II, DOSTAGE, VM) do { \
    const int kb = (II) * 64; \
    DOSTAGE; \
    f32x4 s[4][4]; \
    _Pragma("unroll") for (int kt = 0; kt < 4; ++kt) { \
      bf16x8 kf0 = *(const bf16x8*)&Ks[cur][(kt * 16 + col) * 64 + fslot0]; \
      bf16x8 kf1 = *(const bf16x8*)&Ks[cur][(kt * 16 + col) * 64 + fslot1]; \
      _Pragma("unroll") for (int t = 0; t < 4; ++t) { \
        s[t][kt] = MFMA16(kf0, qf[t][0], zero4); \
        s[t][kt] = MFMA16(kf1, qf[t][1], s[t][kt]); \
      } \
    } \
    if ((anym >> (2 * (II))) & 3ull) { \
      _Pragma("unroll") for (int kt = 0; kt < 4; ++kt) \
        _Pragma("unroll") for (int r = 0; r < 4; ++r) \
          if (mp[kb + kt * 16 + quad * 4 + r] != 0) { \
            _Pragma("unroll") for (int t = 0; t < 4; ++t) s[t][kt][r] = -1e9f; \
          } \
    } \
    bf16x8 pf[4][2]; \
    _Pragma("unroll") for (int t = 0; t < 4; ++t) { \
      f32x4 e0, e1, e2, e3; \
      _Pragma("unroll") for (int r = 0; r < 4; ++r) { \
        e0[r] = __builtin_amdgcn_exp2f(s[t][0][r]); \
        e1[r] = __builtin_amdgcn_exp2f(s[t][1][r]); \
        e2[r] = __builtin_amdgcn_exp2f(s[t][2][r]); \
        e3[r] = __builtin_amdgcn_exp2f(s[t][3][r]); \
      } \
      bf16x4 c0 = __builtin_convertvector(e0, bf16x4); \
      bf16x4 c1 = __builtin_convertvector(e1, bf16x4); \
      bf16x4 c2 = __builtin_convertvector(e2, bf16x4); \
      bf16x4 c3 = __builtin_convertvector(e3, bf16x4); \
      pf[t][0] = __builtin_shufflevector(c0, c1, 0, 1, 2, 3, 4, 5, 6, 7); \
      pf[t][1] = __builtin_shufflevector(c2, c3, 0, 1, 2, 3, 4, 5, 6, 7); \
    } \
    _Pragma("unroll") for (int n = 0; n < 4; ++n) { \
      const int row = (n * 16 + col) * 64; \
      const int rx = col & 7; \
      bf16x8 v0, v1; \
      { bf16x4 lo = *(const bf16x4*)&Vs[cur][row + ((0 + (quad >> 1)) ^ rx) * 8 + voff]; \
        bf16x4 hi = *(const bf16x4*)&Vs[cur][row + ((2 + (quad >> 1)) ^ rx) * 8 + voff]; \
        v0 = __builtin_shufflevector(lo, hi, 0, 1, 2, 3, 4, 5, 6, 7); } \
      { bf16x4 lo = *(const bf16x4*)&Vs[cur][row + ((4 + (quad >> 1)) ^ rx) * 8 + voff]; \
        bf16x4 hi = *(const bf16x4*)&Vs[cur][row + ((6 + (quad >> 1)) ^ rx) * 8 + voff]; \
        v1 = __builtin_shufflevector(lo, hi, 0, 1, 2, 3, 4, 5, 6, 7); } \
      _Pragma("unroll") for (int t = 0; t < 4; ++t) { \
        oacc[t][n] = MFMA16(pf[t][0], v0, oacc[t][n]); \
        oacc[t][n] = MFMA16(pf[t][1], v1, oacc[t][n]); \
      } \
    } \
    _Pragma("unroll") for (int t = 0; t < 4; ++t) { \
      lones[t] = MFMA16(pf[t][0], onev, lones[t]); \
      lones[t] = MFMA16(pf[t][1], onev, lones[t]); \
    } \
    VM; \
    __builtin_amdgcn_s_barrier(); \
  } while (0)

  // prologue: stage tiles 0,1 (8 loads outstanding); wait oldest 4 = tile 0
  FSTAGE(0, 0);
  FSTAGE(1, 1);
  VMW(4);
  __builtin_amdgcn_s_barrier();

#pragma unroll 1
  for (int ii = 0; ii < 30; ii += 3) {            // tiles 0..29
    FITER(0, ii + 0, FSTAGE(ii + 2, 2), VMW(4));
    FITER(1, ii + 1, FSTAGE(ii + 3, 0), VMW(4));
    FITER(2, ii + 2, FSTAGE(ii + 4, 1), VMW(4));
  }
  FITER(0, 30, (void)0, VMW(0));                  // tile 30: tile 31 must land
  FITER(1, 31, (void)0, (void)0);                 // tile 31

#undef FITER
#undef FSTAGE

  // epilogue: no cross-lane transpose needed; lones rows == oacc rows
#pragma unroll
  for (int t = 0; t < 4; ++t) {
    f32x4 rl;
#pragma unroll
    for (int r = 0; r < 4; ++r) rl[r] = __builtin_amdgcn_rcpf(lones[t][r]);
#pragma unroll
    for (int n = 0; n < 4; ++n)
#pragma unroll
      for (int r = 0; r < 4; ++r) {
        size_t q = (size_t)b * Tt + qbase0 + t * 16 + quad * 4 + r;
        ao[q * Dd + h * Hd + n * 16 + col] = (bf16)(oacc[t][n][r] * rl[r]);
      }
  }
}

// --------------------------------------------------------------------- launcher
extern "C" void kernel_launch(void* const* d_in, const int* in_sizes, int n_in,
                              void* d_out, int out_size, void* d_ws, size_t ws_size,
                              hipStream_t stream) {
  const float* x = (const float*)d_in[0];
  const unsigned char* mask = (const unsigned char*)d_in[1];
  const float* Wq = (const float*)d_in[2];
  const float* bq = (const float*)d_in[3];
  const float* Wk = (const float*)d_in[4];
  const float* bk = (const float*)d_in[5];
  const float* Wv = (const float*)d_in[6];
  const float* bv = (const float*)d_in[7];
  const float* Wo = (const float*)d_in[8];
  const float* bo = (const float*)d_in[9];
  float* out = (float*)d_out;

  char* ws = (char*)d_ws;
  size_t off = 0;
  auto alloc = [&](size_t bytes) {
    char* p = ws + off;
    off += (bytes + 255) & ~(size_t)255;
    return p;
  };
  bf16* xb  = (bf16*)alloc((size_t)Mrows * Dd * 2);        // 16.8MB (reused as AO)
  bf16* Wt  = (bf16*)alloc((size_t)3 * Dd * Dd * 2);       // 6.3MB  packed [3072][1024]
  bf16* Wot = (bf16*)alloc((size_t)Dd * Dd * 2);           // 2.1MB
  bf16* QK  = (bf16*)alloc((size_t)Mrows * 2048 * 2);      // 33.6MB [8192][2048]
  bf16* Vt  = (bf16*)alloc((size_t)Bb * Hh * Hd * Tt * 2); // 16.8MB
  float* bqkv = (float*)alloc((size_t)3 * Dd * 4);

  cast_f32_bf16_kernel<<<Mrows * Dd / (256 * 8), 256, 0, stream>>>(x, xb);
  transpose_cast_w4_kernel<<<dim3(16, 16, 4), 256, 0, stream>>>(Wq, Wk, Wv, Wo, Wt, Wot);
  pack_bias_kernel<<<12, 256, 0, stream>>>(bq, bk, bv, bqkv);

  gemm_qkv_kernel<<<dim3(Mrows / QBM, 3 * Dd / QBN), 512, 0, stream>>>(
      xb, Wt, bqkv, QK, Vt);

  bf16* AO = xb;  // xb dead after QKV GEMM
  flash_attn_kernel<<<dim3(512), 256, 0, stream>>>(QK, Vt, mask, AO);
  gemm_out_kernel<<<dim3(Mrows / QBM, Dd / QBN), 512, 0, stream>>>(
      AO, Wot, bo, out);
}

// Round 11
// 264.056 us; speedup vs baseline: 1.6963x; 1.0045x over previous
//
#include <hip/hip_runtime.h>

using bf16 = __bf16;
typedef bf16 bf16x4 __attribute__((ext_vector_type(4)));
typedef bf16 bf16x8 __attribute__((ext_vector_type(8)));
typedef float f32x4 __attribute__((ext_vector_type(4)));
typedef float f32x8 __attribute__((ext_vector_type(8)));

#define MFMA16(a, b, c) __builtin_amdgcn_mfma_f32_16x16x32_bf16(a, b, c, 0, 0, 0)

constexpr int Bb = 4, Tt = 2048, Dd = 1024, Hh = 16, Hd = 64;
constexpr int Mrows = Bb * Tt;                 // 8192
constexpr float CEXP = 0.18033688011112042f;   // (1/sqrt(64)) * log2(e), folded into Wq/bq

// async global->LDS, 16B per lane; LDS dst = wave-uniform base + lane*16 [m97/m104]
__device__ __forceinline__ void gload_lds16(const bf16* g, bf16* lds_base) {
  __builtin_amdgcn_global_load_lds((const __attribute__((address_space(1))) void*)g,
                                   (__attribute__((address_space(3))) void*)lds_base,
                                   16, 0, 0);
}

// ---------------------------------------------------------------- cast x -> bf16
__global__ void cast_f32_bf16_kernel(const float* __restrict__ in, bf16* __restrict__ out) {
  size_t i = ((size_t)blockIdx.x * 256 + threadIdx.x) * 8;
  f32x8 v = *(const f32x8*)(in + i);
  *(bf16x8*)(out + i) = __builtin_convertvector(v, bf16x8);
}

// ---- fused transpose+cast of all four weight matrices: W[k][n] f32 -> Wt[n][k] bf16
__global__ void transpose_cast_w4_kernel(const float* __restrict__ Wq, const float* __restrict__ Wk,
                                         const float* __restrict__ Wv, const float* __restrict__ Wo,
                                         bf16* __restrict__ Wt, bf16* __restrict__ Wot) {
  __shared__ alignas(16) float tile[64][68];
  const int tid = threadIdx.x;
  const int n0 = blockIdx.x * 64, k0 = blockIdx.y * 64, z = blockIdx.z;
  const float* W = (z == 0) ? Wq : (z == 1) ? Wk : (z == 2) ? Wv : Wo;
  bf16* dst = (z == 3) ? Wot : (Wt + (size_t)z * Dd * Dd);
  const float scale = (z == 0) ? CEXP : 1.0f;
#pragma unroll
  for (int it = 0; it < 4; ++it) {
    int chunk = tid + it * 256;
    int kr = chunk >> 4, c4 = chunk & 15;
    f32x4 v = *(const f32x4*)(W + (size_t)(k0 + kr) * Dd + n0 + c4 * 4);
    *(f32x4*)&tile[kr][c4 * 4] = v * scale;
  }
  __syncthreads();
#pragma unroll
  for (int it = 0; it < 2; ++it) {
    int chunk = tid + it * 256;
    int n = chunk & 63, k8 = chunk >> 6;
    bf16x8 o;
#pragma unroll
    for (int j = 0; j < 8; ++j) o[j] = (bf16)tile[k8 * 8 + j][n];
    *(bf16x8*)(dst + (size_t)(n0 + n) * Dd + k0 + k8 * 8) = o;
  }
}

// ---------------------------------------------------------------- pack qkv bias
__global__ void pack_bias_kernel(const float* __restrict__ bq, const float* __restrict__ bk,
                                 const float* __restrict__ bv, float* __restrict__ outb) {
  int i = blockIdx.x * 256 + threadIdx.x;
  float v = (i < 1024) ? bq[i] * CEXP : (i < 2048 ? bk[i - 1024] : bv[i - 2048]);
  outb[i] = v;
}

// --------- QKV GEMM v2: 128x256 tile / 512 threads / 8 waves (2M x 4N), BK=32.
// 3-slot LDS ring (72 KiB), counted vmcnt(3), one raw s_barrier per tile.
constexpr int QBM = 128, QBN = 256, QBK = 32, QNT = Dd / QBK;  // 32 K-tiles

#define VMW(n) asm volatile("s_waitcnt vmcnt(" #n ")" ::: "memory")

__global__ __launch_bounds__(512, 2)
void gemm_qkv_kernel(const bf16* __restrict__ A, const bf16* __restrict__ Bt,
                     const float* __restrict__ bias, bf16* __restrict__ QK,
                     bf16* __restrict__ Vt) {
  constexpr int KD = Dd;
  __shared__ alignas(16) bf16 As[3][QBM * QBK];   // 3 x 8 KiB
  __shared__ alignas(16) bf16 Bs[3][QBN * QBK];   // 3 x 16 KiB  (72 KiB total)
  const int tid = threadIdx.x;
  const int lane = tid & 63, wave = tid >> 6;
  const int col = lane & 15, quad = lane >> 4;
  const int wr = wave >> 2, wc = wave & 3;        // wave tile: 64 x 64
  const size_t m0 = (size_t)blockIdx.x * QBM, n0 = (size_t)blockIdx.y * QBN;

  // staging source pre-swizzle (rule #21): lane l writes LDS vrow (g*8 + l>>3),
  // phys pos (l&7); fetch logical chunk u = (l&7)^(l>>3):
  const int u = (lane & 7) ^ (lane >> 3);
  const int srow = 2 * (lane >> 3) + (u >> 2);    // row within 16-row group
  const int scol = (u & 3) * 8;                   // element col within 32
  const bf16* Abase = A + (m0 + srow) * (size_t)KD + scol;
  const bf16* Bbase = Bt + (n0 + srow) * (size_t)KD + scol;

  // swizzled fragment read base: row R -> vrow R>>1, pos ((R&1)*4 | quad) ^ (vrow&7)
  const int pswz = (((col & 1) << 2) | quad) ^ (col >> 1);
  const int afb = wr * 2048 + (col >> 1) * 64 + pswz * 8;  // + i*512
  const int bfb = wc * 2048 + (col >> 1) * 64 + pswz * 8;  // + j*512

  f32x4 acc[4][4];
#pragma unroll
  for (int i = 0; i < 4; ++i)
#pragma unroll
    for (int j = 0; j < 4; ++j)
#pragma unroll
      for (int r = 0; r < 4; ++r) acc[i][j][r] = 0.f;

  // per wave per tile: 1 A gload (16 rows) + 2 B gloads (32 rows)
#define QSTAGE(t, sl) do { \
    gload_lds16(Abase + (size_t)(t) * QBK + (size_t)(wave * 16) * KD, &As[sl][wave * 512]); \
    gload_lds16(Bbase + (size_t)(t) * QBK + (size_t)(2 * wave) * 16 * KD, &Bs[sl][(2 * wave) * 512]); \
    gload_lds16(Bbase + (size_t)(t) * QBK + (size_t)(2 * wave + 1) * 16 * KD, &Bs[sl][(2 * wave + 1) * 512]); \
  } while (0)

#define QKV_TILE(cur, DOSTAGE, VM) do { \
    bf16x8 af[4], bfv[4]; \
    _Pragma("unroll") for (int j = 0; j < 4; ++j) bfv[j] = *(const bf16x8*)&Bs[cur][bfb + j * 512]; \
    _Pragma("unroll") for (int i = 0; i < 4; ++i) af[i] = *(const bf16x8*)&As[cur][afb + i * 512]; \
    DOSTAGE; \
    asm volatile("s_waitcnt lgkmcnt(0)" ::: "memory"); \
    __builtin_amdgcn_s_setprio(1); \
    _Pragma("unroll") for (int i = 0; i < 4; ++i) \
      _Pragma("unroll") for (int j = 0; j < 4; ++j) acc[i][j] = MFMA16(af[i], bfv[j], acc[i][j]); \
    __builtin_amdgcn_s_setprio(0); \
    VM; \
    __builtin_amdgcn_s_barrier(); \
  } while (0)

  // prologue: stage tiles 0,1 (6 loads/wave outstanding); wait oldest 3 = tile 0
  QSTAGE(0, 0);
  QSTAGE(1, 1);
  VMW(3);
  __builtin_amdgcn_s_barrier();

#pragma unroll 1
  for (int t = 0; t < QNT - 2; t += 3) {          // tiles 0..29 (30 % 3 == 0)
    QKV_TILE(0, QSTAGE(t + 2, 2), VMW(3));
    QKV_TILE(1, QSTAGE(t + 3, 0), VMW(3));
    QKV_TILE(2, QSTAGE(t + 4, 1), VMW(3));
  }
  QKV_TILE(0, (void)0, VMW(0));                   // tile 30: only tile 31 in flight
  QKV_TILE(1, (void)0, (void)0);                  // tile 31

  if (n0 < 2048) {      // Q/K block -> compact [8192][2048] buffer
#pragma unroll
    for (int i = 0; i < 4; ++i)
#pragma unroll
      for (int j = 0; j < 4; ++j) {
        size_t row = m0 + wr * 64 + i * 16 + quad * 4;
        size_t c = n0 + wc * 64 + j * 16 + col;
        float bv = bias[c];
#pragma unroll
        for (int r = 0; r < 4; ++r) QK[(row + r) * 2048 + c] = (bf16)(acc[i][j][r] + bv);
      }
  } else {              // V block -> Vt[b][h][d][t], packed along t
#pragma unroll
    for (int i = 0; i < 4; ++i)
#pragma unroll
      for (int j = 0; j < 4; ++j) {
        size_t row = m0 + wr * 64 + i * 16 + quad * 4;
        int c = (int)(n0 + wc * 64 + j * 16 + col);
        float bv = bias[c];
        int dall = c - 2048, hh = dall >> 6, dd = dall & 63;
        int bi = (int)(row >> 11), trow = (int)(row & 2047);
        bf16x4 pk;
#pragma unroll
        for (int r = 0; r < 4; ++r) pk[r] = (bf16)(acc[i][j][r] + bv);
        *(bf16x4*)&Vt[((size_t)(bi * Hh + hh) * Hd + dd) * Tt + trow] = pk;
      }
  }
#undef QKV_TILE
#undef QSTAGE
}

// ---------- out-projection GEMM: ring template, f32 output, grid 64x4 = 256 blocks
__global__ __launch_bounds__(512, 2)
void gemm_out_kernel(const bf16* __restrict__ A, const bf16* __restrict__ Bt,
                     const float* __restrict__ bias, float* __restrict__ C) {
  constexpr int KD = Dd, NN = Dd;
  __shared__ alignas(16) bf16 As[3][QBM * QBK];
  __shared__ alignas(16) bf16 Bs[3][QBN * QBK];
  const int tid = threadIdx.x;
  const int lane = tid & 63, wave = tid >> 6;
  const int col = lane & 15, quad = lane >> 4;
  const int wr = wave >> 2, wc = wave & 3;        // wave tile: 64 x 64
  const size_t m0 = (size_t)blockIdx.x * QBM, n0 = (size_t)blockIdx.y * QBN;

  const int u = (lane & 7) ^ (lane >> 3);
  const int srow = 2 * (lane >> 3) + (u >> 2);
  const int scol = (u & 3) * 8;
  const bf16* Abase = A + (m0 + srow) * (size_t)KD + scol;
  const bf16* Bbase = Bt + (n0 + srow) * (size_t)KD + scol;

  const int pswz = (((col & 1) << 2) | quad) ^ (col >> 1);
  const int afb = wr * 2048 + (col >> 1) * 64 + pswz * 8;
  const int bfb = wc * 2048 + (col >> 1) * 64 + pswz * 8;

  f32x4 acc[4][4];
#pragma unroll
  for (int i = 0; i < 4; ++i)
#pragma unroll
    for (int j = 0; j < 4; ++j)
#pragma unroll
      for (int r = 0; r < 4; ++r) acc[i][j][r] = 0.f;

#define OSTAGE(t, sl) do { \
    gload_lds16(Abase + (size_t)(t) * QBK + (size_t)(wave * 16) * KD, &As[sl][wave * 512]); \
    gload_lds16(Bbase + (size_t)(t) * QBK + (size_t)(2 * wave) * 16 * KD, &Bs[sl][(2 * wave) * 512]); \
    gload_lds16(Bbase + (size_t)(t) * QBK + (size_t)(2 * wave + 1) * 16 * KD, &Bs[sl][(2 * wave + 1) * 512]); \
  } while (0)

#define OUT_TILE(cur, DOSTAGE, VM) do { \
    bf16x8 af[4], bfv[4]; \
    _Pragma("unroll") for (int j = 0; j < 4; ++j) bfv[j] = *(const bf16x8*)&Bs[cur][bfb + j * 512]; \
    _Pragma("unroll") for (int i = 0; i < 4; ++i) af[i] = *(const bf16x8*)&As[cur][afb + i * 512]; \
    DOSTAGE; \
    asm volatile("s_waitcnt lgkmcnt(0)" ::: "memory"); \
    __builtin_amdgcn_s_setprio(1); \
    _Pragma("unroll") for (int i = 0; i < 4; ++i) \
      _Pragma("unroll") for (int j = 0; j < 4; ++j) acc[i][j] = MFMA16(af[i], bfv[j], acc[i][j]); \
    __builtin_amdgcn_s_setprio(0); \
    VM; \
    __builtin_amdgcn_s_barrier(); \
  } while (0)

  OSTAGE(0, 0);
  OSTAGE(1, 1);
  VMW(3);
  __builtin_amdgcn_s_barrier();

#pragma unroll 1
  for (int t = 0; t < QNT - 2; t += 3) {          // tiles 0..29
    OUT_TILE(0, OSTAGE(t + 2, 2), VMW(3));
    OUT_TILE(1, OSTAGE(t + 3, 0), VMW(3));
    OUT_TILE(2, OSTAGE(t + 4, 1), VMW(3));
  }
  OUT_TILE(0, (void)0, VMW(0));                   // tile 30
  OUT_TILE(1, (void)0, (void)0);                  // tile 31

#pragma unroll
  for (int i = 0; i < 4; ++i)
#pragma unroll
    for (int j = 0; j < 4; ++j) {
      size_t row = m0 + wr * 64 + i * 16 + quad * 4;
      size_t c = n0 + wc * 64 + j * 16 + col;
      float bv = bias[c];
#pragma unroll
      for (int r = 0; r < 4; ++r) C[(row + r) * (size_t)NN + c] = acc[i][j][r] + bv;
    }
#undef OUT_TILE
#undef OSTAGE
}

// ----------------------------------------------- flash attention v7
// R10 (76.2us) + 8-wave consolidation: 512 threads, 512 queries/block, grid 256
// = exactly one dispatch round at 1 block/CU (co-residency unchanged: 8 waves =
// 2 waves/SIMD, same as R10's 2x 4-wave blocks). Per-wave staging halves again:
// each wave stages ONE 1KB K-chunk + ONE V-chunk per tile (2 gloads, was 4);
// ring discipline rederived: prologue 4 outstanding, steady vmcnt(2) ensures
// tile ii+1 landed. All R10 pieces kept: 4 q-tiles/wave, ones-MFMA denominator,
// 3-slot ring, per-kt/per-n register windows, no setprio. XCD pinning preserved
// (same-(b,h) blocks stride 64). Spill tripwire: WRITE_SIZE (16.4MB = clean).
__global__ __launch_bounds__(512, 2)
void flash_attn_kernel(const bf16* __restrict__ qk, const bf16* __restrict__ vt,
                       const unsigned char* __restrict__ mask, bf16* __restrict__ ao) {
  __shared__ alignas(16) bf16 Ks[3][64 * 64];      // [key][slot^], xor-swizzled 16B slots
  __shared__ alignas(16) bf16 Vs[3][64 * 64];      // [d][slot^]

  const int tid = threadIdx.x;
  const int wave = tid >> 6, lane = tid & 63;
  const int col = lane & 15, quad = lane >> 4;
  const int id = blockIdx.x;
  const int hb = id & 63, qi = id >> 6;            // same-head blocks stride 64 -> same XCD
  const int h = hb & 15, b = hb >> 4;
  const int qbase0 = qi * 512 + wave * 64;

  const bf16* Qp = qk + (size_t)(b * Tt) * 2048 + h * Hd;
  const bf16* Kp = Qp + 1024;
  const bf16* Vp = vt + ((size_t)(b * Hh + h) * Hd) * Tt;
  const unsigned char* mp = mask + b * Tt;

  unsigned long long anym;
  {
    const unsigned long long* mq = (const unsigned long long*)mp;
    unsigned long long acc = 0;
#pragma unroll
    for (int j = 0; j < 4; ++j) acc |= mq[lane * 4 + j];
    anym = __ballot(acc != 0ull);
  }

  // Q fragments (pre-scaled by CEXP): free index = query
  bf16x8 qf[4][2];
#pragma unroll
  for (int t = 0; t < 4; ++t)
#pragma unroll
    for (int kk = 0; kk < 2; ++kk)
      qf[t][kk] = *(const bf16x8*)(Qp + (size_t)(qbase0 + t * 16 + col) * 2048 + kk * 32 + quad * 8);

  // gload_lds staging: wave w stages 1KB chunk g = w of K and of V (8 waves cover
  // all 8 chunks). lane l -> LDS row g*8 + (l>>3), phys pos l&7; fetch logical
  // chunk u = (l&7)^(l>>3) (rule #21 inverse pre-swizzle).
  const int u = (lane & 7) ^ (lane >> 3);
  const bf16* Ksrc = Kp + (size_t)(wave * 8 + (lane >> 3)) * 2048 + u * 8;
  const bf16* Vsrc = Vp + (size_t)(wave * 8 + (lane >> 3)) * 2048 + u * 8;

#define FSTAGE(t, sl) do { \
    gload_lds16(Ksrc + (size_t)(t) * 64 * 2048, &Ks[sl][wave * 512]); \
    gload_lds16(Vsrc + (t) * 64, &Vs[sl][wave * 512]); \
  } while (0)

  f32x4 oacc[4][4];
  f32x4 lones[4];
#pragma unroll
  for (int t = 0; t < 4; ++t) {
#pragma unroll
    for (int r = 0; r < 4; ++r) lones[t][r] = 0.f;
#pragma unroll
    for (int n = 0; n < 4; ++n)
#pragma unroll
      for (int r = 0; r < 4; ++r) oacc[t][n][r] = 0.f;
  }
  const f32x4 zero4 = {0.f, 0.f, 0.f, 0.f};
  bf16x8 onev;
#pragma unroll
  for (int j = 0; j < 8; ++j) onev[j] = (bf16)1.0f;

  const int fslot0 = ((0 * 4 + quad) ^ (col & 7)) * 8;   // b128 frag slots (kf)
  const int fslot1 = ((1 * 4 + quad) ^ (col & 7)) * 8;
  const int voff = (quad & 1) * 4;

// one KV-tile: {issue stage II+2; per-kt kf window -> QK^T all 4 q-tiles; mask;
// exp2 -> pf[4][2]; per-n vfs window -> PV all 4 tiles; ones-MFMA; counted vmcnt;
// barrier}
#define FITER(cur, II, DOSTAGE, VM) do { \
    const int kb = (II) * 64; \
    DOSTAGE; \
    f32x4 s[4][4]; \
    _Pragma("unroll") for (int kt = 0; kt < 4; ++kt) { \
      bf16x8 kf0 = *(const bf16x8*)&Ks[cur][(kt * 16 + col) * 64 + fslot0]; \
      bf16x8 kf1 = *(const bf16x8*)&Ks[cur][(kt * 16 + col) * 64 + fslot1]; \
      _Pragma("unroll") for (int t = 0; t < 4; ++t) { \
        s[t][kt] = MFMA16(kf0, qf[t][0], zero4); \
        s[t][kt] = MFMA16(kf1, qf[t][1], s[t][kt]); \
      } \
    } \
    if ((anym >> (2 * (II))) & 3ull) { \
      _Pragma("unroll") for (int kt = 0; kt < 4; ++kt) \
        _Pragma("unroll") for (int r = 0; r < 4; ++r) \
          if (mp[kb + kt * 16 + quad * 4 + r] != 0) { \
            _Pragma("unroll") for (int t = 0; t < 4; ++t) s[t][kt][r] = -1e9f; \
          } \
    } \
    bf16x8 pf[4][2]; \
    _Pragma("unroll") for (int t = 0; t < 4; ++t) { \
      f32x4 e0, e1, e2, e3; \
      _Pragma("unroll") for (int r = 0; r < 4; ++r) { \
        e0[r] = __builtin_amdgcn_exp2f(s[t][0][r]); \
        e1[r] = __builtin_amdgcn_exp2f(s[t][1][r]); \
        e2[r] = __builtin_amdgcn_exp2f(s[t][2][r]); \
        e3[r] = __builtin_amdgcn_exp2f(s[t][3][r]); \
      } \
      bf16x4 c0 = __builtin_convertvector(e0, bf16x4); \
      bf16x4 c1 = __builtin_convertvector(e1, bf16x4); \
      bf16x4 c2 = __builtin_convertvector(e2, bf16x4); \
      bf16x4 c3 = __builtin_convertvector(e3, bf16x4); \
      pf[t][0] = __builtin_shufflevector(c0, c1, 0, 1, 2, 3, 4, 5, 6, 7); \
      pf[t][1] = __builtin_shufflevector(c2, c3, 0, 1, 2, 3, 4, 5, 6, 7); \
    } \
    _Pragma("unroll") for (int n = 0; n < 4; ++n) { \
      const int row = (n * 16 + col) * 64; \
      const int rx = col & 7; \
      bf16x8 v0, v1; \
      { bf16x4 lo = *(const bf16x4*)&Vs[cur][row + ((0 + (quad >> 1)) ^ rx) * 8 + voff]; \
        bf16x4 hi = *(const bf16x4*)&Vs[cur][row + ((2 + (quad >> 1)) ^ rx) * 8 + voff]; \
        v0 = __builtin_shufflevector(lo, hi, 0, 1, 2, 3, 4, 5, 6, 7); } \
      { bf16x4 lo = *(const bf16x4*)&Vs[cur][row + ((4 + (quad >> 1)) ^ rx) * 8 + voff]; \
        bf16x4 hi = *(const bf16x4*)&Vs[cur][row + ((6 + (quad >> 1)) ^ rx) * 8 + voff]; \
        v1 = __builtin_shufflevector(lo, hi, 0, 1, 2, 3, 4, 5, 6, 7); } \
      _Pragma("unroll") for (int t = 0; t < 4; ++t) { \
        oacc[t][n] = MFMA16(pf[t][0], v0, oacc[t][n]); \
        oacc[t][n] = MFMA16(pf[t][1], v1, oacc[t][n]); \
      } \
    } \
    _Pragma("unroll") for (int t = 0; t < 4; ++t) { \
      lones[t] = MFMA16(pf[t][0], onev, lones[t]); \
      lones[t] = MFMA16(pf[t][1], onev, lones[t]); \
    } \
    VM; \
    __builtin_amdgcn_s_barrier(); \
  } while (0)

  // prologue: stage tiles 0,1 (4 loads/wave outstanding); wait oldest 2 = tile 0
  FSTAGE(0, 0);
  FSTAGE(1, 1);
  VMW(2);
  __builtin_amdgcn_s_barrier();

#pragma unroll 1
  for (int ii = 0; ii < 30; ii += 3) {            // tiles 0..29
    FITER(0, ii + 0, FSTAGE(ii + 2, 2), VMW(2));
    FITER(1, ii + 1, FSTAGE(ii + 3, 0), VMW(2));
    FITER(2, ii + 2, FSTAGE(ii + 4, 1), VMW(2));
  }
  FITER(0, 30, (void)0, VMW(0));                  // tile 30: tile 31 must land
  FITER(1, 31, (void)0, (void)0);                 // tile 31

#undef FITER
#undef FSTAGE

  // epilogue: no cross-lane transpose needed; lones rows == oacc rows
#pragma unroll
  for (int t = 0; t < 4; ++t) {
    f32x4 rl;
#pragma unroll
    for (int r = 0; r < 4; ++r) rl[r] = __builtin_amdgcn_rcpf(lones[t][r]);
#pragma unroll
    for (int n = 0; n < 4; ++n)
#pragma unroll
      for (int r = 0; r < 4; ++r) {
        size_t q = (size_t)b * Tt + qbase0 + t * 16 + quad * 4 + r;
        ao[q * Dd + h * Hd + n * 16 + col] = (bf16)(oacc[t][n][r] * rl[r]);
      }
  }
}

// --------------------------------------------------------------------- launcher
extern "C" void kernel_launch(void* const* d_in, const int* in_sizes, int n_in,
                              void* d_out, int out_size, void* d_ws, size_t ws_size,
                              hipStream_t stream) {
  const float* x = (const float*)d_in[0];
  const unsigned char* mask = (const unsigned char*)d_in[1];
  const float* Wq = (const float*)d_in[2];
  const float* bq = (const float*)d_in[3];
  const float* Wk = (const float*)d_in[4];
  const float* bk = (const float*)d_in[5];
  const float* Wv = (const float*)d_in[6];
  const float* bv = (const float*)d_in[7];
  const float* Wo = (const float*)d_in[8];
  const float* bo = (const float*)d_in[9];
  float* out = (float*)d_out;

  char* ws = (char*)d_ws;
  size_t off = 0;
  auto alloc = [&](size_t bytes) {
    char* p = ws + off;
    off += (bytes + 255) & ~(size_t)255;
    return p;
  };
  bf16* xb  = (bf16*)alloc((size_t)Mrows * Dd * 2);        // 16.8MB (reused as AO)
  bf16* Wt  = (bf16*)alloc((size_t)3 * Dd * Dd * 2);       // 6.3MB  packed [3072][1024]
  bf16* Wot = (bf16*)alloc((size_t)Dd * Dd * 2);           // 2.1MB
  bf16* QK  = (bf16*)alloc((size_t)Mrows * 2048 * 2);      // 33.6MB [8192][2048]
  bf16* Vt  = (bf16*)alloc((size_t)Bb * Hh * Hd * Tt * 2); // 16.8MB
  float* bqkv = (float*)alloc((size_t)3 * Dd * 4);

  cast_f32_bf16_kernel<<<Mrows * Dd / (256 * 8), 256, 0, stream>>>(x, xb);
  transpose_cast_w4_kernel<<<dim3(16, 16, 4), 256, 0, stream>>>(Wq, Wk, Wv, Wo, Wt, Wot);
  pack_bias_kernel<<<12, 256, 0, stream>>>(bq, bk, bv, bqkv);

  gemm_qkv_kernel<<<dim3(Mrows / QBM, 3 * Dd / QBN), 512, 0, stream>>>(
      xb, Wt, bqkv, QK, Vt);

  bf16* AO = xb;  // xb dead after QKV GEMM
  flash_attn_kernel<<<dim3(256), 512, 0, stream>>>(QK, Vt, mask, AO);
  gemm_out_kernel<<<dim3(Mrows / QBM, Dd / QBN), 512, 0, stream>>>(
      AO, Wot, bo, out);
}

// Round 12
// 263.743 us; speedup vs baseline: 1.6983x; 1.0012x over previous
//
#include <hip/hip_runtime.h>

using bf16 = __bf16;
typedef bf16 bf16x4 __attribute__((ext_vector_type(4)));
typedef bf16 bf16x8 __attribute__((ext_vector_type(8)));
typedef float f32x4 __attribute__((ext_vector_type(4)));
typedef float f32x8 __attribute__((ext_vector_type(8)));

#define MFMA16(a, b, c) __builtin_amdgcn_mfma_f32_16x16x32_bf16(a, b, c, 0, 0, 0)

constexpr int Bb = 4, Tt = 2048, Dd = 1024, Hh = 16, Hd = 64;
constexpr int Mrows = Bb * Tt;                 // 8192
constexpr float CEXP = 0.18033688011112042f;   // (1/sqrt(64)) * log2(e), folded into Wq/bq

// async global->LDS, 16B per lane; LDS dst = wave-uniform base + lane*16 [m97/m104]
__device__ __forceinline__ void gload_lds16(const bf16* g, bf16* lds_base) {
  __builtin_amdgcn_global_load_lds((const __attribute__((address_space(1))) void*)g,
                                   (__attribute__((address_space(3))) void*)lds_base,
                                   16, 0, 0);
}

// ---------------------------------------------------------------- cast x -> bf16
__global__ void cast_f32_bf16_kernel(const float* __restrict__ in, bf16* __restrict__ out) {
  size_t i = ((size_t)blockIdx.x * 256 + threadIdx.x) * 8;
  f32x8 v = *(const f32x8*)(in + i);
  *(bf16x8*)(out + i) = __builtin_convertvector(v, bf16x8);
}

// ---- fused transpose+cast of all four weight matrices: W[k][n] f32 -> Wt[n][k] bf16
// + fused qkv bias pack (k0==0, z<3 blocks emit their 64-col bias slice; saves the
// separate pack_bias launch).
__global__ void transpose_cast_w4_kernel(const float* __restrict__ Wq, const float* __restrict__ Wk,
                                         const float* __restrict__ Wv, const float* __restrict__ Wo,
                                         const float* __restrict__ bq, const float* __restrict__ bk,
                                         const float* __restrict__ bv,
                                         bf16* __restrict__ Wt, bf16* __restrict__ Wot,
                                         float* __restrict__ bqkv) {
  __shared__ alignas(16) float tile[64][68];
  const int tid = threadIdx.x;
  const int n0 = blockIdx.x * 64, k0 = blockIdx.y * 64, z = blockIdx.z;
  const float* W = (z == 0) ? Wq : (z == 1) ? Wk : (z == 2) ? Wv : Wo;
  bf16* dst = (z == 3) ? Wot : (Wt + (size_t)z * Dd * Dd);
  const float scale = (z == 0) ? CEXP : 1.0f;
  if (k0 == 0 && z < 3 && tid < 64) {
    const float* bsrc = (z == 0) ? bq : (z == 1) ? bk : bv;
    bqkv[z * Dd + n0 + tid] = bsrc[n0 + tid] * scale;
  }
#pragma unroll
  for (int it = 0; it < 4; ++it) {
    int chunk = tid + it * 256;
    int kr = chunk >> 4, c4 = chunk & 15;
    f32x4 v = *(const f32x4*)(W + (size_t)(k0 + kr) * Dd + n0 + c4 * 4);
    *(f32x4*)&tile[kr][c4 * 4] = v * scale;
  }
  __syncthreads();
#pragma unroll
  for (int it = 0; it < 2; ++it) {
    int chunk = tid + it * 256;
    int n = chunk & 63, k8 = chunk >> 6;
    bf16x8 o;
#pragma unroll
    for (int j = 0; j < 8; ++j) o[j] = (bf16)tile[k8 * 8 + j][n];
    *(bf16x8*)(dst + (size_t)(n0 + n) * Dd + k0 + k8 * 8) = o;
  }
}

// --------- QKV GEMM v2: 128x256 tile / 512 threads / 8 waves (2M x 4N), BK=32.
// 3-slot LDS ring (72 KiB), counted vmcnt(3), one raw s_barrier per tile.
constexpr int QBM = 128, QBN = 256, QBK = 32, QNT = Dd / QBK;  // 32 K-tiles

#define VMW(n) asm volatile("s_waitcnt vmcnt(" #n ")" ::: "memory")

__global__ __launch_bounds__(512, 2)
void gemm_qkv_kernel(const bf16* __restrict__ A, const bf16* __restrict__ Bt,
                     const float* __restrict__ bias, bf16* __restrict__ QK,
                     bf16* __restrict__ Vt) {
  constexpr int KD = Dd;
  __shared__ alignas(16) bf16 As[3][QBM * QBK];   // 3 x 8 KiB
  __shared__ alignas(16) bf16 Bs[3][QBN * QBK];   // 3 x 16 KiB  (72 KiB total)
  const int tid = threadIdx.x;
  const int lane = tid & 63, wave = tid >> 6;
  const int col = lane & 15, quad = lane >> 4;
  const int wr = wave >> 2, wc = wave & 3;        // wave tile: 64 x 64
  const size_t m0 = (size_t)blockIdx.x * QBM, n0 = (size_t)blockIdx.y * QBN;

  // staging source pre-swizzle (rule #21): lane l writes LDS vrow (g*8 + l>>3),
  // phys pos (l&7); fetch logical chunk u = (l&7)^(l>>3):
  const int u = (lane & 7) ^ (lane >> 3);
  const int srow = 2 * (lane >> 3) + (u >> 2);    // row within 16-row group
  const int scol = (u & 3) * 8;                   // element col within 32
  const bf16* Abase = A + (m0 + srow) * (size_t)KD + scol;
  const bf16* Bbase = Bt + (n0 + srow) * (size_t)KD + scol;

  // swizzled fragment read base: row R -> vrow R>>1, pos ((R&1)*4 | quad) ^ (vrow&7)
  const int pswz = (((col & 1) << 2) | quad) ^ (col >> 1);
  const int afb = wr * 2048 + (col >> 1) * 64 + pswz * 8;  // + i*512
  const int bfb = wc * 2048 + (col >> 1) * 64 + pswz * 8;  // + j*512

  f32x4 acc[4][4];
#pragma unroll
  for (int i = 0; i < 4; ++i)
#pragma unroll
    for (int j = 0; j < 4; ++j)
#pragma unroll
      for (int r = 0; r < 4; ++r) acc[i][j][r] = 0.f;

  // per wave per tile: 1 A gload (16 rows) + 2 B gloads (32 rows)
#define QSTAGE(t, sl) do { \
    gload_lds16(Abase + (size_t)(t) * QBK + (size_t)(wave * 16) * KD, &As[sl][wave * 512]); \
    gload_lds16(Bbase + (size_t)(t) * QBK + (size_t)(2 * wave) * 16 * KD, &Bs[sl][(2 * wave) * 512]); \
    gload_lds16(Bbase + (size_t)(t) * QBK + (size_t)(2 * wave + 1) * 16 * KD, &Bs[sl][(2 * wave + 1) * 512]); \
  } while (0)

#define QKV_TILE(cur, DOSTAGE, VM) do { \
    bf16x8 af[4], bfv[4]; \
    _Pragma("unroll") for (int j = 0; j < 4; ++j) bfv[j] = *(const bf16x8*)&Bs[cur][bfb + j * 512]; \
    _Pragma("unroll") for (int i = 0; i < 4; ++i) af[i] = *(const bf16x8*)&As[cur][afb + i * 512]; \
    DOSTAGE; \
    asm volatile("s_waitcnt lgkmcnt(0)" ::: "memory"); \
    __builtin_amdgcn_s_setprio(1); \
    _Pragma("unroll") for (int i = 0; i < 4; ++i) \
      _Pragma("unroll") for (int j = 0; j < 4; ++j) acc[i][j] = MFMA16(af[i], bfv[j], acc[i][j]); \
    __builtin_amdgcn_s_setprio(0); \
    VM; \
    __builtin_amdgcn_s_barrier(); \
  } while (0)

  // prologue: stage tiles 0,1 (6 loads/wave outstanding); wait oldest 3 = tile 0
  QSTAGE(0, 0);
  QSTAGE(1, 1);
  VMW(3);
  __builtin_amdgcn_s_barrier();

#pragma unroll 1
  for (int t = 0; t < QNT - 2; t += 3) {          // tiles 0..29 (30 % 3 == 0)
    QKV_TILE(0, QSTAGE(t + 2, 2), VMW(3));
    QKV_TILE(1, QSTAGE(t + 3, 0), VMW(3));
    QKV_TILE(2, QSTAGE(t + 4, 1), VMW(3));
  }
  QKV_TILE(0, (void)0, VMW(0));                   // tile 30: only tile 31 in flight
  QKV_TILE(1, (void)0, (void)0);                  // tile 31

  if (n0 < 2048) {      // Q/K block -> compact [8192][2048] buffer
#pragma unroll
    for (int i = 0; i < 4; ++i)
#pragma unroll
      for (int j = 0; j < 4; ++j) {
        size_t row = m0 + wr * 64 + i * 16 + quad * 4;
        size_t c = n0 + wc * 64 + j * 16 + col;
        float bv = bias[c];
#pragma unroll
        for (int r = 0; r < 4; ++r) QK[(row + r) * 2048 + c] = (bf16)(acc[i][j][r] + bv);
      }
  } else {              // V block -> Vt[b][h][d][t], packed along t
#pragma unroll
    for (int i = 0; i < 4; ++i)
#pragma unroll
      for (int j = 0; j < 4; ++j) {
        size_t row = m0 + wr * 64 + i * 16 + quad * 4;
        int c = (int)(n0 + wc * 64 + j * 16 + col);
        float bv = bias[c];
        int dall = c - 2048, hh = dall >> 6, dd = dall & 63;
        int bi = (int)(row >> 11), trow = (int)(row & 2047);
        bf16x4 pk;
#pragma unroll
        for (int r = 0; r < 4; ++r) pk[r] = (bf16)(acc[i][j][r] + bv);
        *(bf16x4*)&Vt[((size_t)(bi * Hh + hh) * Hd + dd) * Tt + trow] = pk;
      }
  }
#undef QKV_TILE
#undef QSTAGE
}

// ---------- out-projection GEMM: ring template, f32 output, grid 64x4 = 256 blocks
__global__ __launch_bounds__(512, 2)
void gemm_out_kernel(const bf16* __restrict__ A, const bf16* __restrict__ Bt,
                     const float* __restrict__ bias, float* __restrict__ C) {
  constexpr int KD = Dd, NN = Dd;
  __shared__ alignas(16) bf16 As[3][QBM * QBK];
  __shared__ alignas(16) bf16 Bs[3][QBN * QBK];
  const int tid = threadIdx.x;
  const int lane = tid & 63, wave = tid >> 6;
  const int col = lane & 15, quad = lane >> 4;
  const int wr = wave >> 2, wc = wave & 3;        // wave tile: 64 x 64
  const size_t m0 = (size_t)blockIdx.x * QBM, n0 = (size_t)blockIdx.y * QBN;

  const int u = (lane & 7) ^ (lane >> 3);
  const int srow = 2 * (lane >> 3) + (u >> 2);
  const int scol = (u & 3) * 8;
  const bf16* Abase = A + (m0 + srow) * (size_t)KD + scol;
  const bf16* Bbase = Bt + (n0 + srow) * (size_t)KD + scol;

  const int pswz = (((col & 1) << 2) | quad) ^ (col >> 1);
  const int afb = wr * 2048 + (col >> 1) * 64 + pswz * 8;
  const int bfb = wc * 2048 + (col >> 1) * 64 + pswz * 8;

  f32x4 acc[4][4];
#pragma unroll
  for (int i = 0; i < 4; ++i)
#pragma unroll
    for (int j = 0; j < 4; ++j)
#pragma unroll
      for (int r = 0; r < 4; ++r) acc[i][j][r] = 0.f;

#define OSTAGE(t, sl) do { \
    gload_lds16(Abase + (size_t)(t) * QBK + (size_t)(wave * 16) * KD, &As[sl][wave * 512]); \
    gload_lds16(Bbase + (size_t)(t) * QBK + (size_t)(2 * wave) * 16 * KD, &Bs[sl][(2 * wave) * 512]); \
    gload_lds16(Bbase + (size_t)(t) * QBK + (size_t)(2 * wave + 1) * 16 * KD, &Bs[sl][(2 * wave + 1) * 512]); \
  } while (0)

#define OUT_TILE(cur, DOSTAGE, VM) do { \
    bf16x8 af[4], bfv[4]; \
    _Pragma("unroll") for (int j = 0; j < 4; ++j) bfv[j] = *(const bf16x8*)&Bs[cur][bfb + j * 512]; \
    _Pragma("unroll") for (int i = 0; i < 4; ++i) af[i] = *(const bf16x8*)&As[cur][afb + i * 512]; \
    DOSTAGE; \
    asm volatile("s_waitcnt lgkmcnt(0)" ::: "memory"); \
    __builtin_amdgcn_s_setprio(1); \
    _Pragma("unroll") for (int i = 0; i < 4; ++i) \
      _Pragma("unroll") for (int j = 0; j < 4; ++j) acc[i][j] = MFMA16(af[i], bfv[j], acc[i][j]); \
    __builtin_amdgcn_s_setprio(0); \
    VM; \
    __builtin_amdgcn_s_barrier(); \
  } while (0)

  OSTAGE(0, 0);
  OSTAGE(1, 1);
  VMW(3);
  __builtin_amdgcn_s_barrier();

#pragma unroll 1
  for (int t = 0; t < QNT - 2; t += 3) {          // tiles 0..29
    OUT_TILE(0, OSTAGE(t + 2, 2), VMW(3));
    OUT_TILE(1, OSTAGE(t + 3, 0), VMW(3));
    OUT_TILE(2, OSTAGE(t + 4, 1), VMW(3));
  }
  OUT_TILE(0, (void)0, VMW(0));                   // tile 30
  OUT_TILE(1, (void)0, (void)0);                  // tile 31

#pragma unroll
  for (int i = 0; i < 4; ++i)
#pragma unroll
    for (int j = 0; j < 4; ++j) {
      size_t row = m0 + wr * 64 + i * 16 + quad * 4;
      size_t c = n0 + wc * 64 + j * 16 + col;
      float bv = bias[c];
#pragma unroll
      for (int r = 0; r < 4; ++r) C[(row + r) * (size_t)NN + c] = acc[i][j][r] + bv;
    }
#undef OUT_TILE
#undef OSTAGE
}

// ----------------------------------------------- flash attention v6 (R10 EXACT,
// 76.2us measured — session best). 4 q-tiles/wave, 4 waves/block, 512 blocks =
// 2 blocks/CU. Both neighbors regress: 2-tile split (R3: 93) and 8-wave
// consolidation (R11: 86 — wider barrier cone + no inter-block stall cover at
// 1 block/CU). ones-MFMA denominator, 3-slot ring + counted vmcnt(4), per-kt
// QK^T / per-n PV register windows, no setprio.
__global__ __launch_bounds__(256, 2)
void flash_attn_kernel(const bf16* __restrict__ qk, const bf16* __restrict__ vt,
                       const unsigned char* __restrict__ mask, bf16* __restrict__ ao) {
  __shared__ alignas(16) bf16 Ks[3][64 * 64];      // [key][slot^], xor-swizzled 16B slots
  __shared__ alignas(16) bf16 Vs[3][64 * 64];      // [d][slot^]

  const int tid = threadIdx.x;
  const int wave = tid >> 6, lane = tid & 63;
  const int col = lane & 15, quad = lane >> 4;
  const int id = blockIdx.x;
  const int hb = id & 63, qi = id >> 6;            // same-head blocks stride 64 -> same XCD
  const int h = hb & 15, b = hb >> 4;
  const int qbase0 = qi * 256 + wave * 64;

  const bf16* Qp = qk + (size_t)(b * Tt) * 2048 + h * Hd;
  const bf16* Kp = Qp + 1024;
  const bf16* Vp = vt + ((size_t)(b * Hh + h) * Hd) * Tt;
  const unsigned char* mp = mask + b * Tt;

  unsigned long long anym;
  {
    const unsigned long long* mq = (const unsigned long long*)mp;
    unsigned long long acc = 0;
#pragma unroll
    for (int j = 0; j < 4; ++j) acc |= mq[lane * 4 + j];
    anym = __ballot(acc != 0ull);
  }

  // Q fragments (pre-scaled by CEXP): free index = query
  bf16x8 qf[4][2];
#pragma unroll
  for (int t = 0; t < 4; ++t)
#pragma unroll
    for (int kk = 0; kk < 2; ++kk)
      qf[t][kk] = *(const bf16x8*)(Qp + (size_t)(qbase0 + t * 16 + col) * 2048 + kk * 32 + quad * 8);

  // gload_lds staging: wave w stages 1KB chunks g in {2w, 2w+1} of K and of V.
  const int u = (lane & 7) ^ (lane >> 3);
  const int g0 = 2 * wave, g1 = 2 * wave + 1;
  const bf16* Ksrc0 = Kp + (size_t)(g0 * 8 + (lane >> 3)) * 2048 + u * 8;
  const bf16* Ksrc1 = Kp + (size_t)(g1 * 8 + (lane >> 3)) * 2048 + u * 8;
  const bf16* Vsrc0 = Vp + (size_t)(g0 * 8 + (lane >> 3)) * 2048 + u * 8;
  const bf16* Vsrc1 = Vp + (size_t)(g1 * 8 + (lane >> 3)) * 2048 + u * 8;

#define FSTAGE(t, sl) do { \
    gload_lds16(Ksrc0 + (size_t)(t) * 64 * 2048, &Ks[sl][g0 * 512]); \
    gload_lds16(Ksrc1 + (size_t)(t) * 64 * 2048, &Ks[sl][g1 * 512]); \
    gload_lds16(Vsrc0 + (t) * 64, &Vs[sl][g0 * 512]); \
    gload_lds16(Vsrc1 + (t) * 64, &Vs[sl][g1 * 512]); \
  } while (0)

  f32x4 oacc[4][4];
  f32x4 lones[4];
#pragma unroll
  for (int t = 0; t < 4; ++t) {
#pragma unroll
    for (int r = 0; r < 4; ++r) lones[t][r] = 0.f;
#pragma unroll
    for (int n = 0; n < 4; ++n)
#pragma unroll
      for (int r = 0; r < 4; ++r) oacc[t][n][r] = 0.f;
  }
  const f32x4 zero4 = {0.f, 0.f, 0.f, 0.f};
  bf16x8 onev;
#pragma unroll
  for (int j = 0; j < 8; ++j) onev[j] = (bf16)1.0f;

  const int fslot0 = ((0 * 4 + quad) ^ (col & 7)) * 8;   // b128 frag slots (kf)
  const int fslot1 = ((1 * 4 + quad) ^ (col & 7)) * 8;
  const int voff = (quad & 1) * 4;

// one KV-tile: {issue stage II+2; per-kt kf window -> QK^T all 4 q-tiles; mask;
// exp2 -> pf[4][2]; per-n vfs window -> PV all 4 tiles; ones-MFMA; counted vmcnt;
// barrier}
#define FITER(cur, II, DOSTAGE, VM) do { \
    const int kb = (II) * 64; \
    DOSTAGE; \
    f32x4 s[4][4]; \
    _Pragma("unroll") for (int kt = 0; kt < 4; ++kt) { \
      bf16x8 kf0 = *(const bf16x8*)&Ks[cur][(kt * 16 + col) * 64 + fslot0]; \
      bf16x8 kf1 = *(const bf16x8*)&Ks[cur][(kt * 16 + col) * 64 + fslot1]; \
      _Pragma("unroll") for (int t = 0; t < 4; ++t) { \
        s[t][kt] = MFMA16(kf0, qf[t][0], zero4); \
        s[t][kt] = MFMA16(kf1, qf[t][1], s[t][kt]); \
      } \
    } \
    if ((anym >> (2 * (II))) & 3ull) { \
      _Pragma("unroll") for (int kt = 0; kt < 4; ++kt) \
        _Pragma("unroll") for (int r = 0; r < 4; ++r) \
          if (mp[kb + kt * 16 + quad * 4 + r] != 0) { \
            _Pragma("unroll") for (int t = 0; t < 4; ++t) s[t][kt][r] = -1e9f; \
          } \
    } \
    bf16x8 pf[4][2]; \
    _Pragma("unroll") for (int t = 0; t < 4; ++t) { \
      f32x4 e0, e1, e2, e3; \
      _Pragma("unroll") for (int r = 0; r < 4; ++r) { \
        e0[r] = __builtin_amdgcn_exp2f(s[t][0][r]); \
        e1[r] = __builtin_amdgcn_exp2f(s[t][1][r]); \
        e2[r] = __builtin_amdgcn_exp2f(s[t][2][r]); \
        e3[r] = __builtin_amdgcn_exp2f(s[t][3][r]); \
      } \
      bf16x4 c0 = __builtin_convertvector(e0, bf16x4); \
      bf16x4 c1 = __builtin_convertvector(e1, bf16x4); \
      bf16x4 c2 = __builtin_convertvector(e2, bf16x4); \
      bf16x4 c3 = __builtin_convertvector(e3, bf16x4); \
      pf[t][0] = __builtin_shufflevector(c0, c1, 0, 1, 2, 3, 4, 5, 6, 7); \
      pf[t][1] = __builtin_shufflevector(c2, c3, 0, 1, 2, 3, 4, 5, 6, 7); \
    } \
    _Pragma("unroll") for (int n = 0; n < 4; ++n) { \
      const int row = (n * 16 + col) * 64; \
      const int rx = col & 7; \
      bf16x8 v0, v1; \
      { bf16x4 lo = *(const bf16x4*)&Vs[cur][row + ((0 + (quad >> 1)) ^ rx) * 8 + voff]; \
        bf16x4 hi = *(const bf16x4*)&Vs[cur][row + ((2 + (quad >> 1)) ^ rx) * 8 + voff]; \
        v0 = __builtin_shufflevector(lo, hi, 0, 1, 2, 3, 4, 5, 6, 7); } \
      { bf16x4 lo = *(const bf16x4*)&Vs[cur][row + ((4 + (quad >> 1)) ^ rx) * 8 + voff]; \
        bf16x4 hi = *(const bf16x4*)&Vs[cur][row + ((6 + (quad >> 1)) ^ rx) * 8 + voff]; \
        v1 = __builtin_shufflevector(lo, hi, 0, 1, 2, 3, 4, 5, 6, 7); } \
      _Pragma("unroll") for (int t = 0; t < 4; ++t) { \
        oacc[t][n] = MFMA16(pf[t][0], v0, oacc[t][n]); \
        oacc[t][n] = MFMA16(pf[t][1], v1, oacc[t][n]); \
      } \
    } \
    _Pragma("unroll") for (int t = 0; t < 4; ++t) { \
      lones[t] = MFMA16(pf[t][0], onev, lones[t]); \
      lones[t] = MFMA16(pf[t][1], onev, lones[t]); \
    } \
    VM; \
    __builtin_amdgcn_s_barrier(); \
  } while (0)

  // prologue: stage tiles 0,1 (8 loads outstanding); wait oldest 4 = tile 0
  FSTAGE(0, 0);
  FSTAGE(1, 1);
  VMW(4);
  __builtin_amdgcn_s_barrier();

#pragma unroll 1
  for (int ii = 0; ii < 30; ii += 3) {            // tiles 0..29
    FITER(0, ii + 0, FSTAGE(ii + 2, 2), VMW(4));
    FITER(1, ii + 1, FSTAGE(ii + 3, 0), VMW(4));
    FITER(2, ii + 2, FSTAGE(ii + 4, 1), VMW(4));
  }
  FITER(0, 30, (void)0, VMW(0));                  // tile 30: tile 31 must land
  FITER(1, 31, (void)0, (void)0);                 // tile 31

#undef FITER
#undef FSTAGE

  // epilogue: no cross-lane transpose needed; lones rows == oacc rows
#pragma unroll
  for (int t = 0; t < 4; ++t) {
    f32x4 rl;
#pragma unroll
    for (int r = 0; r < 4; ++r) rl[r] = __builtin_amdgcn_rcpf(lones[t][r]);
#pragma unroll
    for (int n = 0; n < 4; ++n)
#pragma unroll
      for (int r = 0; r < 4; ++r) {
        size_t q = (size_t)b * Tt + qbase0 + t * 16 + quad * 4 + r;
        ao[q * Dd + h * Hd + n * 16 + col] = (bf16)(oacc[t][n][r] * rl[r]);
      }
  }
}

// --------------------------------------------------------------------- launcher
extern "C" void kernel_launch(void* const* d_in, const int* in_sizes, int n_in,
                              void* d_out, int out_size, void* d_ws, size_t ws_size,
                              hipStream_t stream) {
  const float* x = (const float*)d_in[0];
  const unsigned char* mask = (const unsigned char*)d_in[1];
  const float* Wq = (const float*)d_in[2];
  const float* bq = (const float*)d_in[3];
  const float* Wk = (const float*)d_in[4];
  const float* bk = (const float*)d_in[5];
  const float* Wv = (const float*)d_in[6];
  const float* bv = (const float*)d_in[7];
  const float* Wo = (const float*)d_in[8];
  const float* bo = (const float*)d_in[9];
  float* out = (float*)d_out;

  char* ws = (char*)d_ws;
  size_t off = 0;
  auto alloc = [&](size_t bytes) {
    char* p = ws + off;
    off += (bytes + 255) & ~(size_t)255;
    return p;
  };
  bf16* xb  = (bf16*)alloc((size_t)Mrows * Dd * 2);        // 16.8MB (reused as AO)
  bf16* Wt  = (bf16*)alloc((size_t)3 * Dd * Dd * 2);       // 6.3MB  packed [3072][1024]
  bf16* Wot = (bf16*)alloc((size_t)Dd * Dd * 2);           // 2.1MB
  bf16* QK  = (bf16*)alloc((size_t)Mrows * 2048 * 2);      // 33.6MB [8192][2048]
  bf16* Vt  = (bf16*)alloc((size_t)Bb * Hh * Hd * Tt * 2); // 16.8MB
  float* bqkv = (float*)alloc((size_t)3 * Dd * 4);

  cast_f32_bf16_kernel<<<Mrows * Dd / (256 * 8), 256, 0, stream>>>(x, xb);
  transpose_cast_w4_kernel<<<dim3(16, 16, 4), 256, 0, stream>>>(
      Wq, Wk, Wv, Wo, bq, bk, bv, Wt, Wot, bqkv);

  gemm_qkv_kernel<<<dim3(Mrows / QBM, 3 * Dd / QBN), 512, 0, stream>>>(
      xb, Wt, bqkv, QK, Vt);

  bf16* AO = xb;  // xb dead after QKV GEMM
  flash_attn_kernel<<<dim3(512), 256, 0, stream>>>(QK, Vt, mask, AO);
  gemm_out_kernel<<<dim3(Mrows / QBM, Dd / QBN), 512, 0, stream>>>(
      AO, Wot, bo, out);
}

// Round 13
// 263.054 us; speedup vs baseline: 1.7028x; 1.0026x over previous
//
#include <hip/hip_runtime.h>

using bf16 = __bf16;
typedef bf16 bf16x4 __attribute__((ext_vector_type(4)));
typedef bf16 bf16x8 __attribute__((ext_vector_type(8)));
typedef float f32x4 __attribute__((ext_vector_type(4)));
typedef float f32x8 __attribute__((ext_vector_type(8)));

#define MFMA16(a, b, c) __builtin_amdgcn_mfma_f32_16x16x32_bf16(a, b, c, 0, 0, 0)

constexpr int Bb = 4, Tt = 2048, Dd = 1024, Hh = 16, Hd = 64;
constexpr int Mrows = Bb * Tt;                 // 8192
constexpr float CEXP = 0.18033688011112042f;   // (1/sqrt(64)) * log2(e), folded into Wq/bq

// async global->LDS, 16B per lane; LDS dst = wave-uniform base + lane*16 [m97/m104]
__device__ __forceinline__ void gload_lds16(const bf16* g, bf16* lds_base) {
  __builtin_amdgcn_global_load_lds((const __attribute__((address_space(1))) void*)g,
                                   (__attribute__((address_space(3))) void*)lds_base,
                                   16, 0, 0);
}

// ---------------------------------------------------------------- cast x -> bf16
__global__ void cast_f32_bf16_kernel(const float* __restrict__ in, bf16* __restrict__ out) {
  size_t i = ((size_t)blockIdx.x * 256 + threadIdx.x) * 8;
  f32x8 v = *(const f32x8*)(in + i);
  *(bf16x8*)(out + i) = __builtin_convertvector(v, bf16x8);
}

// ---- fused transpose+cast of all four weight matrices: W[k][n] f32 -> Wt[n][k] bf16
// + fused qkv bias pack (k0==0, z<3 blocks emit their 64-col bias slice).
__global__ void transpose_cast_w4_kernel(const float* __restrict__ Wq, const float* __restrict__ Wk,
                                         const float* __restrict__ Wv, const float* __restrict__ Wo,
                                         const float* __restrict__ bq, const float* __restrict__ bk,
                                         const float* __restrict__ bv,
                                         bf16* __restrict__ Wt, bf16* __restrict__ Wot,
                                         float* __restrict__ bqkv) {
  __shared__ alignas(16) float tile[64][68];
  const int tid = threadIdx.x;
  const int n0 = blockIdx.x * 64, k0 = blockIdx.y * 64, z = blockIdx.z;
  const float* W = (z == 0) ? Wq : (z == 1) ? Wk : (z == 2) ? Wv : Wo;
  bf16* dst = (z == 3) ? Wot : (Wt + (size_t)z * Dd * Dd);
  const float scale = (z == 0) ? CEXP : 1.0f;
  if (k0 == 0 && z < 3 && tid < 64) {
    const float* bsrc = (z == 0) ? bq : (z == 1) ? bk : bv;
    bqkv[z * Dd + n0 + tid] = bsrc[n0 + tid] * scale;
  }
#pragma unroll
  for (int it = 0; it < 4; ++it) {
    int chunk = tid + it * 256;
    int kr = chunk >> 4, c4 = chunk & 15;
    f32x4 v = *(const f32x4*)(W + (size_t)(k0 + kr) * Dd + n0 + c4 * 4);
    *(f32x4*)&tile[kr][c4 * 4] = v * scale;
  }
  __syncthreads();
#pragma unroll
  for (int it = 0; it < 2; ++it) {
    int chunk = tid + it * 256;
    int n = chunk & 63, k8 = chunk >> 6;
    bf16x8 o;
#pragma unroll
    for (int j = 0; j < 8; ++j) o[j] = (bf16)tile[k8 * 8 + j][n];
    *(bf16x8*)(dst + (size_t)(n0 + n) * Dd + k0 + k8 * 8) = o;
  }
}

// --------- QKV GEMM v3: 128x256 tile / 256 threads / 4 waves (2M x 2N), BK=32.
// Wave-tile 64x128 -> 32 MFMA per wave per barrier interval (was 16 at 8 waves),
// barrier cone halved, MFMA:ds_read 32:12 (was 16:8). 3-slot ring (72 KiB),
// counted vmcnt(6) (2 tiles x 6 loads/wave in flight), one s_barrier per tile.
// Co-residency unchanged: 2 blocks/CU (LDS-bound), 2 waves/SIMD. acc 128 regs +
// af 16 + bfv 32 ~ 200 < 256 at (256,2) -> no cap, no forced split (R2/R4).
constexpr int QBM = 128, QBN = 256, QBK = 32, QNT = Dd / QBK;  // 32 K-tiles

#define VMW(n) asm volatile("s_waitcnt vmcnt(" #n ")" ::: "memory")

__global__ __launch_bounds__(256, 2)
void gemm_qkv_kernel(const bf16* __restrict__ A, const bf16* __restrict__ Bt,
                     const float* __restrict__ bias, bf16* __restrict__ QK,
                     bf16* __restrict__ Vt) {
  constexpr int KD = Dd;
  __shared__ alignas(16) bf16 As[3][QBM * QBK];   // 3 x 8 KiB
  __shared__ alignas(16) bf16 Bs[3][QBN * QBK];   // 3 x 16 KiB  (72 KiB total)
  const int tid = threadIdx.x;
  const int lane = tid & 63, wave = tid >> 6;
  const int col = lane & 15, quad = lane >> 4;
  const int wr = wave >> 1, wc = wave & 1;        // wave tile: 64 x 128
  const size_t m0 = (size_t)blockIdx.x * QBM, n0 = (size_t)blockIdx.y * QBN;

  // staging source pre-swizzle (rule #21): lane l writes LDS vrow (c*8 + l>>3),
  // phys pos (l&7); fetch logical chunk u = (l&7)^(l>>3):
  const int u = (lane & 7) ^ (lane >> 3);
  const int srow = 2 * (lane >> 3) + (u >> 2);    // row within 16-row chunk
  const int scol = (u & 3) * 8;                   // element col within 32
  const bf16* Abase = A + (m0 + srow) * (size_t)KD + scol;
  const bf16* Bbase = Bt + (n0 + srow) * (size_t)KD + scol;

  // swizzled fragment read base: row R -> vrow R>>1, pos ((R&1)*4 | quad) ^ (vrow&7);
  // frag rows step by 16 -> (vrow&7) == col>>1 always.
  const int pswz = (((col & 1) << 2) | quad) ^ (col >> 1);
  const int afb = wr * 2048 + (col >> 1) * 64 + pswz * 8;  // + i*512, i<4
  const int bfb = wc * 4096 + (col >> 1) * 64 + pswz * 8;  // + j*512, j<8

  f32x4 acc[4][8];
#pragma unroll
  for (int i = 0; i < 4; ++i)
#pragma unroll
    for (int j = 0; j < 8; ++j)
#pragma unroll
      for (int r = 0; r < 4; ++r) acc[i][j][r] = 0.f;

  // per wave per tile: 2 A-chunks + 4 B-chunks (6 gloads; 4 waves cover 8+16)
#define QSTAGE(t, sl) do { \
    gload_lds16(Abase + (size_t)(t) * QBK + (size_t)(2 * wave + 0) * 16 * KD, &As[sl][(2 * wave + 0) * 512]); \
    gload_lds16(Abase + (size_t)(t) * QBK + (size_t)(2 * wave + 1) * 16 * KD, &As[sl][(2 * wave + 1) * 512]); \
    gload_lds16(Bbase + (size_t)(t) * QBK + (size_t)(4 * wave + 0) * 16 * KD, &Bs[sl][(4 * wave + 0) * 512]); \
    gload_lds16(Bbase + (size_t)(t) * QBK + (size_t)(4 * wave + 1) * 16 * KD, &Bs[sl][(4 * wave + 1) * 512]); \
    gload_lds16(Bbase + (size_t)(t) * QBK + (size_t)(4 * wave + 2) * 16 * KD, &Bs[sl][(4 * wave + 2) * 512]); \
    gload_lds16(Bbase + (size_t)(t) * QBK + (size_t)(4 * wave + 3) * 16 * KD, &Bs[sl][(4 * wave + 3) * 512]); \
  } while (0)

#define QKV_TILE(cur, DOSTAGE, VM) do { \
    bf16x8 af[4], bfv[8]; \
    _Pragma("unroll") for (int j = 0; j < 8; ++j) bfv[j] = *(const bf16x8*)&Bs[cur][bfb + j * 512]; \
    _Pragma("unroll") for (int i = 0; i < 4; ++i) af[i] = *(const bf16x8*)&As[cur][afb + i * 512]; \
    DOSTAGE; \
    asm volatile("s_waitcnt lgkmcnt(0)" ::: "memory"); \
    __builtin_amdgcn_s_setprio(1); \
    _Pragma("unroll") for (int i = 0; i < 4; ++i) \
      _Pragma("unroll") for (int j = 0; j < 8; ++j) acc[i][j] = MFMA16(af[i], bfv[j], acc[i][j]); \
    __builtin_amdgcn_s_setprio(0); \
    VM; \
    __builtin_amdgcn_s_barrier(); \
  } while (0)

  // prologue: stage tiles 0,1 (12 loads/wave outstanding); wait oldest 6 = tile 0
  QSTAGE(0, 0);
  QSTAGE(1, 1);
  VMW(6);
  __builtin_amdgcn_s_barrier();

#pragma unroll 1
  for (int t = 0; t < QNT - 2; t += 3) {          // tiles 0..29 (30 % 3 == 0)
    QKV_TILE(0, QSTAGE(t + 2, 2), VMW(6));
    QKV_TILE(1, QSTAGE(t + 3, 0), VMW(6));
    QKV_TILE(2, QSTAGE(t + 4, 1), VMW(6));
  }
  QKV_TILE(0, (void)0, VMW(0));                   // tile 30: only tile 31 in flight
  QKV_TILE(1, (void)0, (void)0);                  // tile 31

  if (n0 < 2048) {      // Q/K block -> compact [8192][2048] buffer
#pragma unroll
    for (int i = 0; i < 4; ++i)
#pragma unroll
      for (int j = 0; j < 8; ++j) {
        size_t row = m0 + wr * 64 + i * 16 + quad * 4;
        size_t c = n0 + wc * 128 + j * 16 + col;
        float bv = bias[c];
#pragma unroll
        for (int r = 0; r < 4; ++r) QK[(row + r) * 2048 + c] = (bf16)(acc[i][j][r] + bv);
      }
  } else {              // V block -> Vt[b][h][d][t], packed along t
#pragma unroll
    for (int i = 0; i < 4; ++i)
#pragma unroll
      for (int j = 0; j < 8; ++j) {
        size_t row = m0 + wr * 64 + i * 16 + quad * 4;
        int c = (int)(n0 + wc * 128 + j * 16 + col);
        float bv = bias[c];
        int dall = c - 2048, hh = dall >> 6, dd = dall & 63;
        int bi = (int)(row >> 11), trow = (int)(row & 2047);
        bf16x4 pk;
#pragma unroll
        for (int r = 0; r < 4; ++r) pk[r] = (bf16)(acc[i][j][r] + bv);
        *(bf16x4*)&Vt[((size_t)(bi * Hh + hh) * Hd + dd) * Tt + trow] = pk;
      }
  }
#undef QKV_TILE
#undef QSTAGE
}

// ---------- out-projection GEMM: same v3 template (4 waves, 64x128/wave),
// f32 output, grid 64x4 = 256 blocks (one round at 2 blocks/CU).
__global__ __launch_bounds__(256, 2)
void gemm_out_kernel(const bf16* __restrict__ A, const bf16* __restrict__ Bt,
                     const float* __restrict__ bias, float* __restrict__ C) {
  constexpr int KD = Dd, NN = Dd;
  __shared__ alignas(16) bf16 As[3][QBM * QBK];
  __shared__ alignas(16) bf16 Bs[3][QBN * QBK];
  const int tid = threadIdx.x;
  const int lane = tid & 63, wave = tid >> 6;
  const int col = lane & 15, quad = lane >> 4;
  const int wr = wave >> 1, wc = wave & 1;        // wave tile: 64 x 128
  const size_t m0 = (size_t)blockIdx.x * QBM, n0 = (size_t)blockIdx.y * QBN;

  const int u = (lane & 7) ^ (lane >> 3);
  const int srow = 2 * (lane >> 3) + (u >> 2);
  const int scol = (u & 3) * 8;
  const bf16* Abase = A + (m0 + srow) * (size_t)KD + scol;
  const bf16* Bbase = Bt + (n0 + srow) * (size_t)KD + scol;

  const int pswz = (((col & 1) << 2) | quad) ^ (col >> 1);
  const int afb = wr * 2048 + (col >> 1) * 64 + pswz * 8;
  const int bfb = wc * 4096 + (col >> 1) * 64 + pswz * 8;

  f32x4 acc[4][8];
#pragma unroll
  for (int i = 0; i < 4; ++i)
#pragma unroll
    for (int j = 0; j < 8; ++j)
#pragma unroll
      for (int r = 0; r < 4; ++r) acc[i][j][r] = 0.f;

#define OSTAGE(t, sl) do { \
    gload_lds16(Abase + (size_t)(t) * QBK + (size_t)(2 * wave + 0) * 16 * KD, &As[sl][(2 * wave + 0) * 512]); \
    gload_lds16(Abase + (size_t)(t) * QBK + (size_t)(2 * wave + 1) * 16 * KD, &As[sl][(2 * wave + 1) * 512]); \
    gload_lds16(Bbase + (size_t)(t) * QBK + (size_t)(4 * wave + 0) * 16 * KD, &Bs[sl][(4 * wave + 0) * 512]); \
    gload_lds16(Bbase + (size_t)(t) * QBK + (size_t)(4 * wave + 1) * 16 * KD, &Bs[sl][(4 * wave + 1) * 512]); \
    gload_lds16(Bbase + (size_t)(t) * QBK + (size_t)(4 * wave + 2) * 16 * KD, &Bs[sl][(4 * wave + 2) * 512]); \
    gload_lds16(Bbase + (size_t)(t) * QBK + (size_t)(4 * wave + 3) * 16 * KD, &Bs[sl][(4 * wave + 3) * 512]); \
  } while (0)

#define OUT_TILE(cur, DOSTAGE, VM) do { \
    bf16x8 af[4], bfv[8]; \
    _Pragma("unroll") for (int j = 0; j < 8; ++j) bfv[j] = *(const bf16x8*)&Bs[cur][bfb + j * 512]; \
    _Pragma("unroll") for (int i = 0; i < 4; ++i) af[i] = *(const bf16x8*)&As[cur][afb + i * 512]; \
    DOSTAGE; \
    asm volatile("s_waitcnt lgkmcnt(0)" ::: "memory"); \
    __builtin_amdgcn_s_setprio(1); \
    _Pragma("unroll") for (int i = 0; i < 4; ++i) \
      _Pragma("unroll") for (int j = 0; j < 8; ++j) acc[i][j] = MFMA16(af[i], bfv[j], acc[i][j]); \
    __builtin_amdgcn_s_setprio(0); \
    VM; \
    __builtin_amdgcn_s_barrier(); \
  } while (0)

  OSTAGE(0, 0);
  OSTAGE(1, 1);
  VMW(6);
  __builtin_amdgcn_s_barrier();

#pragma unroll 1
  for (int t = 0; t < QNT - 2; t += 3) {          // tiles 0..29
    OUT_TILE(0, OSTAGE(t + 2, 2), VMW(6));
    OUT_TILE(1, OSTAGE(t + 3, 0), VMW(6));
    OUT_TILE(2, OSTAGE(t + 4, 1), VMW(6));
  }
  OUT_TILE(0, (void)0, VMW(0));                   // tile 30
  OUT_TILE(1, (void)0, (void)0);                  // tile 31

#pragma unroll
  for (int i = 0; i < 4; ++i)
#pragma unroll
    for (int j = 0; j < 8; ++j) {
      size_t row = m0 + wr * 64 + i * 16 + quad * 4;
      size_t c = n0 + wc * 128 + j * 16 + col;
      float bv = bias[c];
#pragma unroll
      for (int r = 0; r < 4; ++r) C[(row + r) * (size_t)NN + c] = acc[i][j][r] + bv;
    }
#undef OUT_TILE
#undef OSTAGE
}

// ----------------------------------------------- flash attention v6 (R10 EXACT,
// 76.2-76.8us measured — session best; both neighbors regress: R3 2-tile split
// 93, R11 8-wave consolidation 86). 4 q-tiles/wave, 4 waves/block, 512 blocks =
// 2 blocks/CU. ones-MFMA denominator, 3-slot ring + counted vmcnt(4), per-kt
// QK^T / per-n PV register windows, no setprio.
__global__ __launch_bounds__(256, 2)
void flash_attn_kernel(const bf16* __restrict__ qk, const bf16* __restrict__ vt,
                       const unsigned char* __restrict__ mask, bf16* __restrict__ ao) {
  __shared__ alignas(16) bf16 Ks[3][64 * 64];      // [key][slot^], xor-swizzled 16B slots
  __shared__ alignas(16) bf16 Vs[3][64 * 64];      // [d][slot^]

  const int tid = threadIdx.x;
  const int wave = tid >> 6, lane = tid & 63;
  const int col = lane & 15, quad = lane >> 4;
  const int id = blockIdx.x;
  const int hb = id & 63, qi = id >> 6;            // same-head blocks stride 64 -> same XCD
  const int h = hb & 15, b = hb >> 4;
  const int qbase0 = qi * 256 + wave * 64;

  const bf16* Qp = qk + (size_t)(b * Tt) * 2048 + h * Hd;
  const bf16* Kp = Qp + 1024;
  const bf16* Vp = vt + ((size_t)(b * Hh + h) * Hd) * Tt;
  const unsigned char* mp = mask + b * Tt;

  unsigned long long anym;
  {
    const unsigned long long* mq = (const unsigned long long*)mp;
    unsigned long long acc = 0;
#pragma unroll
    for (int j = 0; j < 4; ++j) acc |= mq[lane * 4 + j];
    anym = __ballot(acc != 0ull);
  }

  // Q fragments (pre-scaled by CEXP): free index = query
  bf16x8 qf[4][2];
#pragma unroll
  for (int t = 0; t < 4; ++t)
#pragma unroll
    for (int kk = 0; kk < 2; ++kk)
      qf[t][kk] = *(const bf16x8*)(Qp + (size_t)(qbase0 + t * 16 + col) * 2048 + kk * 32 + quad * 8);

  // gload_lds staging: wave w stages 1KB chunks g in {2w, 2w+1} of K and of V.
  const int u = (lane & 7) ^ (lane >> 3);
  const int g0 = 2 * wave, g1 = 2 * wave + 1;
  const bf16* Ksrc0 = Kp + (size_t)(g0 * 8 + (lane >> 3)) * 2048 + u * 8;
  const bf16* Ksrc1 = Kp + (size_t)(g1 * 8 + (lane >> 3)) * 2048 + u * 8;
  const bf16* Vsrc0 = Vp + (size_t)(g0 * 8 + (lane >> 3)) * 2048 + u * 8;
  const bf16* Vsrc1 = Vp + (size_t)(g1 * 8 + (lane >> 3)) * 2048 + u * 8;

#define FSTAGE(t, sl) do { \
    gload_lds16(Ksrc0 + (size_t)(t) * 64 * 2048, &Ks[sl][g0 * 512]); \
    gload_lds16(Ksrc1 + (size_t)(t) * 64 * 2048, &Ks[sl][g1 * 512]); \
    gload_lds16(Vsrc0 + (t) * 64, &Vs[sl][g0 * 512]); \
    gload_lds16(Vsrc1 + (t) * 64, &Vs[sl][g1 * 512]); \
  } while (0)

  f32x4 oacc[4][4];
  f32x4 lones[4];
#pragma unroll
  for (int t = 0; t < 4; ++t) {
#pragma unroll
    for (int r = 0; r < 4; ++r) lones[t][r] = 0.f;
#pragma unroll
    for (int n = 0; n < 4; ++n)
#pragma unroll
      for (int r = 0; r < 4; ++r) oacc[t][n][r] = 0.f;
  }
  const f32x4 zero4 = {0.f, 0.f, 0.f, 0.f};
  bf16x8 onev;
#pragma unroll
  for (int j = 0; j < 8; ++j) onev[j] = (bf16)1.0f;

  const int fslot0 = ((0 * 4 + quad) ^ (col & 7)) * 8;   // b128 frag slots (kf)
  const int fslot1 = ((1 * 4 + quad) ^ (col & 7)) * 8;
  const int voff = (quad & 1) * 4;

#define FITER(cur, II, DOSTAGE, VM) do { \
    const int kb = (II) * 64; \
    DOSTAGE; \
    f32x4 s[4][4]; \
    _Pragma("unroll") for (int kt = 0; kt < 4; ++kt) { \
      bf16x8 kf0 = *(const bf16x8*)&Ks[cur][(kt * 16 + col) * 64 + fslot0]; \
      bf16x8 kf1 = *(const bf16x8*)&Ks[cur][(kt * 16 + col) * 64 + fslot1]; \
      _Pragma("unroll") for (int t = 0; t < 4; ++t) { \
        s[t][kt] = MFMA16(kf0, qf[t][0], zero4); \
        s[t][kt] = MFMA16(kf1, qf[t][1], s[t][kt]); \
      } \
    } \
    if ((anym >> (2 * (II))) & 3ull) { \
      _Pragma("unroll") for (int kt = 0; kt < 4; ++kt) \
        _Pragma("unroll") for (int r = 0; r < 4; ++r) \
          if (mp[kb + kt * 16 + quad * 4 + r] != 0) { \
            _Pragma("unroll") for (int t = 0; t < 4; ++t) s[t][kt][r] = -1e9f; \
          } \
    } \
    bf16x8 pf[4][2]; \
    _Pragma("unroll") for (int t = 0; t < 4; ++t) { \
      f32x4 e0, e1, e2, e3; \
      _Pragma("unroll") for (int r = 0; r < 4; ++r) { \
        e0[r] = __builtin_amdgcn_exp2f(s[t][0][r]); \
        e1[r] = __builtin_amdgcn_exp2f(s[t][1][r]); \
        e2[r] = __builtin_amdgcn_exp2f(s[t][2][r]); \
        e3[r] = __builtin_amdgcn_exp2f(s[t][3][r]); \
      } \
      bf16x4 c0 = __builtin_convertvector(e0, bf16x4); \
      bf16x4 c1 = __builtin_convertvector(e1, bf16x4); \
      bf16x4 c2 = __builtin_convertvector(e2, bf16x4); \
      bf16x4 c3 = __builtin_convertvector(e3, bf16x4); \
      pf[t][0] = __builtin_shufflevector(c0, c1, 0, 1, 2, 3, 4, 5, 6, 7); \
      pf[t][1] = __builtin_shufflevector(c2, c3, 0, 1, 2, 3, 4, 5, 6, 7); \
    } \
    _Pragma("unroll") for (int n = 0; n < 4; ++n) { \
      const int row = (n * 16 + col) * 64; \
      const int rx = col & 7; \
      bf16x8 v0, v1; \
      { bf16x4 lo = *(const bf16x4*)&Vs[cur][row + ((0 + (quad >> 1)) ^ rx) * 8 + voff]; \
        bf16x4 hi = *(const bf16x4*)&Vs[cur][row + ((2 + (quad >> 1)) ^ rx) * 8 + voff]; \
        v0 = __builtin_shufflevector(lo, hi, 0, 1, 2, 3, 4, 5, 6, 7); } \
      { bf16x4 lo = *(const bf16x4*)&Vs[cur][row + ((4 + (quad >> 1)) ^ rx) * 8 + voff]; \
        bf16x4 hi = *(const bf16x4*)&Vs[cur][row + ((6 + (quad >> 1)) ^ rx) * 8 + voff]; \
        v1 = __builtin_shufflevector(lo, hi, 0, 1, 2, 3, 4, 5, 6, 7); } \
      _Pragma("unroll") for (int t = 0; t < 4; ++t) { \
        oacc[t][n] = MFMA16(pf[t][0], v0, oacc[t][n]); \
        oacc[t][n] = MFMA16(pf[t][1], v1, oacc[t][n]); \
      } \
    } \
    _Pragma("unroll") for (int t = 0; t < 4; ++t) { \
      lones[t] = MFMA16(pf[t][0], onev, lones[t]); \
      lones[t] = MFMA16(pf[t][1], onev, lones[t]); \
    } \
    VM; \
    __builtin_amdgcn_s_barrier(); \
  } while (0)

  // prologue: stage tiles 0,1 (8 loads outstanding); wait oldest 4 = tile 0
  FSTAGE(0, 0);
  FSTAGE(1, 1);
  VMW(4);
  __builtin_amdgcn_s_barrier();

#pragma unroll 1
  for (int ii = 0; ii < 30; ii += 3) {            // tiles 0..29
    FITER(0, ii + 0, FSTAGE(ii + 2, 2), VMW(4));
    FITER(1, ii + 1, FSTAGE(ii + 3, 0), VMW(4));
    FITER(2, ii + 2, FSTAGE(ii + 4, 1), VMW(4));
  }
  FITER(0, 30, (void)0, VMW(0));                  // tile 30: tile 31 must land
  FITER(1, 31, (void)0, (void)0);                 // tile 31

#undef FITER
#undef FSTAGE

  // epilogue: no cross-lane transpose needed; lones rows == oacc rows
#pragma unroll
  for (int t = 0; t < 4; ++t) {
    f32x4 rl;
#pragma unroll
    for (int r = 0; r < 4; ++r) rl[r] = __builtin_amdgcn_rcpf(lones[t][r]);
#pragma unroll
    for (int n = 0; n < 4; ++n)
#pragma unroll
      for (int r = 0; r < 4; ++r) {
        size_t q = (size_t)b * Tt + qbase0 + t * 16 + quad * 4 + r;
        ao[q * Dd + h * Hd + n * 16 + col] = (bf16)(oacc[t][n][r] * rl[r]);
      }
  }
}

// --------------------------------------------------------------------- launcher
extern "C" void kernel_launch(void* const* d_in, const int* in_sizes, int n_in,
                              void* d_out, int out_size, void* d_ws, size_t ws_size,
                              hipStream_t stream) {
  const float* x = (const float*)d_in[0];
  const unsigned char* mask = (const unsigned char*)d_in[1];
  const float* Wq = (const float*)d_in[2];
  const float* bq = (const float*)d_in[3];
  const float* Wk = (const float*)d_in[4];
  const float* bk = (const float*)d_in[5];
  const float* Wv = (const float*)d_in[6];
  const float* bv = (const float*)d_in[7];
  const float* Wo = (const float*)d_in[8];
  const float* bo = (const float*)d_in[9];
  float* out = (float*)d_out;

  char* ws = (char*)d_ws;
  size_t off = 0;
  auto alloc = [&](size_t bytes) {
    char* p = ws + off;
    off += (bytes + 255) & ~(size_t)255;
    return p;
  };
  bf16* xb  = (bf16*)alloc((size_t)Mrows * Dd * 2);        // 16.8MB (reused as AO)
  bf16* Wt  = (bf16*)alloc((size_t)3 * Dd * Dd * 2);       // 6.3MB  packed [3072][1024]
  bf16* Wot = (bf16*)alloc((size_t)Dd * Dd * 2);           // 2.1MB
  bf16* QK  = (bf16*)alloc((size_t)Mrows * 2048 * 2);      // 33.6MB [8192][2048]
  bf16* Vt  = (bf16*)alloc((size_t)Bb * Hh * Hd * Tt * 2); // 16.8MB
  float* bqkv = (float*)alloc((size_t)3 * Dd * 4);

  cast_f32_bf16_kernel<<<Mrows * Dd / (256 * 8), 256, 0, stream>>>(x, xb);
  transpose_cast_w4_kernel<<<dim3(16, 16, 4), 256, 0, stream>>>(
      Wq, Wk, Wv, Wo, bq, bk, bv, Wt, Wot, bqkv);

  gemm_qkv_kernel<<<dim3(Mrows / QBM, 3 * Dd / QBN), 256, 0, stream>>>(
      xb, Wt, bqkv, QK, Vt);

  bf16* AO = xb;  // xb dead after QKV GEMM
  flash_attn_kernel<<<dim3(512), 256, 0, stream>>>(QK, Vt, mask, AO);
  gemm_out_kernel<<<dim3(Mrows / QBM, Dd / QBN), 256, 0, stream>>>(
      AO, Wot, bo, out);
}

// Round 14
// 259.449 us; speedup vs baseline: 1.7264x; 1.0139x over previous
//
#include <hip/hip_runtime.h>

using bf16 = __bf16;
typedef bf16 bf16x4 __attribute__((ext_vector_type(4)));
typedef bf16 bf16x8 __attribute__((ext_vector_type(8)));
typedef float f32x4 __attribute__((ext_vector_type(4)));
typedef float f32x8 __attribute__((ext_vector_type(8)));

#define MFMA16(a, b, c) __builtin_amdgcn_mfma_f32_16x16x32_bf16(a, b, c, 0, 0, 0)

constexpr int Bb = 4, Tt = 2048, Dd = 1024, Hh = 16, Hd = 64;
constexpr int Mrows = Bb * Tt;                 // 8192
constexpr float CEXP = 0.18033688011112042f;   // (1/sqrt(64)) * log2(e), folded into Wq/bq

// async global->LDS, 16B per lane; LDS dst = wave-uniform base + lane*16 [m97/m104]
__device__ __forceinline__ void gload_lds16(const bf16* g, bf16* lds_base) {
  __builtin_amdgcn_global_load_lds((const __attribute__((address_space(1))) void*)g,
                                   (__attribute__((address_space(3))) void*)lds_base,
                                   16, 0, 0);
}

// ---------------------------------------------------------------- cast x -> bf16
__global__ void cast_f32_bf16_kernel(const float* __restrict__ in, bf16* __restrict__ out) {
  size_t i = ((size_t)blockIdx.x * 256 + threadIdx.x) * 8;
  f32x8 v = *(const f32x8*)(in + i);
  *(bf16x8*)(out + i) = __builtin_convertvector(v, bf16x8);
}

// ---- fused transpose+cast of all four weight matrices: W[k][n] f32 -> Wt[n][k] bf16
// + fused qkv bias pack (k0==0, z<3 blocks emit their 64-col bias slice).
__global__ void transpose_cast_w4_kernel(const float* __restrict__ Wq, const float* __restrict__ Wk,
                                         const float* __restrict__ Wv, const float* __restrict__ Wo,
                                         const float* __restrict__ bq, const float* __restrict__ bk,
                                         const float* __restrict__ bv,
                                         bf16* __restrict__ Wt, bf16* __restrict__ Wot,
                                         float* __restrict__ bqkv) {
  __shared__ alignas(16) float tile[64][68];
  const int tid = threadIdx.x;
  const int n0 = blockIdx.x * 64, k0 = blockIdx.y * 64, z = blockIdx.z;
  const float* W = (z == 0) ? Wq : (z == 1) ? Wk : (z == 2) ? Wv : Wo;
  bf16* dst = (z == 3) ? Wot : (Wt + (size_t)z * Dd * Dd);
  const float scale = (z == 0) ? CEXP : 1.0f;
  if (k0 == 0 && z < 3 && tid < 64) {
    const float* bsrc = (z == 0) ? bq : (z == 1) ? bk : bv;
    bqkv[z * Dd + n0 + tid] = bsrc[n0 + tid] * scale;
  }
#pragma unroll
  for (int it = 0; it < 4; ++it) {
    int chunk = tid + it * 256;
    int kr = chunk >> 4, c4 = chunk & 15;
    f32x4 v = *(const f32x4*)(W + (size_t)(k0 + kr) * Dd + n0 + c4 * 4);
    *(f32x4*)&tile[kr][c4 * 4] = v * scale;
  }
  __syncthreads();
#pragma unroll
  for (int it = 0; it < 2; ++it) {
    int chunk = tid + it * 256;
    int n = chunk & 63, k8 = chunk >> 6;
    bf16x8 o;
#pragma unroll
    for (int j = 0; j < 8; ++j) o[j] = (bf16)tile[k8 * 8 + j][n];
    *(bf16x8*)(dst + (size_t)(n0 + n) * Dd + k0 + k8 * 8) = o;
  }
}

// --------- QKV GEMM v3b: 128x256 tile / 256 threads / 4 waves (2M x 2N), BK=32.
// 3-slot ring (72 KiB), counted vmcnt(6), one s_barrier per tile. v3b change:
// REMOVED the explicit lgkmcnt(0) drain before the MFMA cluster — ds_reads are
// plain C loads, so the compiler inserts fine-grained lgkmcnt(N) interleaved with
// the MFMAs (m97: near-optimal); the explicit drain serialized ~150cy of LDS
// latency per tile. Cross-wave safety: slot cur was staged + vmcnt-verified two
// barriers ago, so even one-barrier read hoisting is race-free.
constexpr int QBM = 128, QBN = 256, QBK = 32, QNT = Dd / QBK;  // 32 K-tiles

#define VMW(n) asm volatile("s_waitcnt vmcnt(" #n ")" ::: "memory")

__global__ __launch_bounds__(256, 2)
void gemm_qkv_kernel(const bf16* __restrict__ A, const bf16* __restrict__ Bt,
                     const float* __restrict__ bias, bf16* __restrict__ QK,
                     bf16* __restrict__ Vt) {
  constexpr int KD = Dd;
  __shared__ alignas(16) bf16 As[3][QBM * QBK];   // 3 x 8 KiB
  __shared__ alignas(16) bf16 Bs[3][QBN * QBK];   // 3 x 16 KiB  (72 KiB total)
  const int tid = threadIdx.x;
  const int lane = tid & 63, wave = tid >> 6;
  const int col = lane & 15, quad = lane >> 4;
  const int wr = wave >> 1, wc = wave & 1;        // wave tile: 64 x 128
  const size_t m0 = (size_t)blockIdx.x * QBM, n0 = (size_t)blockIdx.y * QBN;

  // staging source pre-swizzle (rule #21): lane l writes LDS vrow (c*8 + l>>3),
  // phys pos (l&7); fetch logical chunk u = (l&7)^(l>>3):
  const int u = (lane & 7) ^ (lane >> 3);
  const int srow = 2 * (lane >> 3) + (u >> 2);    // row within 16-row chunk
  const int scol = (u & 3) * 8;                   // element col within 32
  const bf16* Abase = A + (m0 + srow) * (size_t)KD + scol;
  const bf16* Bbase = Bt + (n0 + srow) * (size_t)KD + scol;

  // swizzled fragment read base: row R -> vrow R>>1, pos ((R&1)*4 | quad) ^ (vrow&7)
  const int pswz = (((col & 1) << 2) | quad) ^ (col >> 1);
  const int afb = wr * 2048 + (col >> 1) * 64 + pswz * 8;  // + i*512, i<4
  const int bfb = wc * 4096 + (col >> 1) * 64 + pswz * 8;  // + j*512, j<8

  f32x4 acc[4][8];
#pragma unroll
  for (int i = 0; i < 4; ++i)
#pragma unroll
    for (int j = 0; j < 8; ++j)
#pragma unroll
      for (int r = 0; r < 4; ++r) acc[i][j][r] = 0.f;

  // per wave per tile: 2 A-chunks + 4 B-chunks (6 gloads; 4 waves cover 8+16)
#define QSTAGE(t, sl) do { \
    gload_lds16(Abase + (size_t)(t) * QBK + (size_t)(2 * wave + 0) * 16 * KD, &As[sl][(2 * wave + 0) * 512]); \
    gload_lds16(Abase + (size_t)(t) * QBK + (size_t)(2 * wave + 1) * 16 * KD, &As[sl][(2 * wave + 1) * 512]); \
    gload_lds16(Bbase + (size_t)(t) * QBK + (size_t)(4 * wave + 0) * 16 * KD, &Bs[sl][(4 * wave + 0) * 512]); \
    gload_lds16(Bbase + (size_t)(t) * QBK + (size_t)(4 * wave + 1) * 16 * KD, &Bs[sl][(4 * wave + 1) * 512]); \
    gload_lds16(Bbase + (size_t)(t) * QBK + (size_t)(4 * wave + 2) * 16 * KD, &Bs[sl][(4 * wave + 2) * 512]); \
    gload_lds16(Bbase + (size_t)(t) * QBK + (size_t)(4 * wave + 3) * 16 * KD, &Bs[sl][(4 * wave + 3) * 512]); \
  } while (0)

#define QKV_TILE(cur, DOSTAGE, VM) do { \
    bf16x8 af[4], bfv[8]; \
    _Pragma("unroll") for (int j = 0; j < 8; ++j) bfv[j] = *(const bf16x8*)&Bs[cur][bfb + j * 512]; \
    _Pragma("unroll") for (int i = 0; i < 4; ++i) af[i] = *(const bf16x8*)&As[cur][afb + i * 512]; \
    DOSTAGE; \
    __builtin_amdgcn_s_setprio(1); \
    _Pragma("unroll") for (int i = 0; i < 4; ++i) \
      _Pragma("unroll") for (int j = 0; j < 8; ++j) acc[i][j] = MFMA16(af[i], bfv[j], acc[i][j]); \
    __builtin_amdgcn_s_setprio(0); \
    VM; \
    __builtin_amdgcn_s_barrier(); \
  } while (0)

  // prologue: stage tiles 0,1 (12 loads/wave outstanding); wait oldest 6 = tile 0
  QSTAGE(0, 0);
  QSTAGE(1, 1);
  VMW(6);
  __builtin_amdgcn_s_barrier();

#pragma unroll 1
  for (int t = 0; t < QNT - 2; t += 3) {          // tiles 0..29 (30 % 3 == 0)
    QKV_TILE(0, QSTAGE(t + 2, 2), VMW(6));
    QKV_TILE(1, QSTAGE(t + 3, 0), VMW(6));
    QKV_TILE(2, QSTAGE(t + 4, 1), VMW(6));
  }
  QKV_TILE(0, (void)0, VMW(0));                   // tile 30: only tile 31 in flight
  QKV_TILE(1, (void)0, (void)0);                  // tile 31

  if (n0 < 2048) {      // Q/K block -> compact [8192][2048] buffer
#pragma unroll
    for (int i = 0; i < 4; ++i)
#pragma unroll
      for (int j = 0; j < 8; ++j) {
        size_t row = m0 + wr * 64 + i * 16 + quad * 4;
        size_t c = n0 + wc * 128 + j * 16 + col;
        float bv = bias[c];
#pragma unroll
        for (int r = 0; r < 4; ++r) QK[(row + r) * 2048 + c] = (bf16)(acc[i][j][r] + bv);
      }
  } else {              // V block -> Vt[b][h][d][t], packed along t
#pragma unroll
    for (int i = 0; i < 4; ++i)
#pragma unroll
      for (int j = 0; j < 8; ++j) {
        size_t row = m0 + wr * 64 + i * 16 + quad * 4;
        int c = (int)(n0 + wc * 128 + j * 16 + col);
        float bv = bias[c];
        int dall = c - 2048, hh = dall >> 6, dd = dall & 63;
        int bi = (int)(row >> 11), trow = (int)(row & 2047);
        bf16x4 pk;
#pragma unroll
        for (int r = 0; r < 4; ++r) pk[r] = (bf16)(acc[i][j][r] + bv);
        *(bf16x4*)&Vt[((size_t)(bi * Hh + hh) * Hd + dd) * Tt + trow] = pk;
      }
  }
#undef QKV_TILE
#undef QSTAGE
}

// ---------- out-projection GEMM: same v3b template (no explicit lgkm drain),
// f32 output, grid 64x4 = 256 blocks (one round at 2 blocks/CU).
__global__ __launch_bounds__(256, 2)
void gemm_out_kernel(const bf16* __restrict__ A, const bf16* __restrict__ Bt,
                     const float* __restrict__ bias, float* __restrict__ C) {
  constexpr int KD = Dd, NN = Dd;
  __shared__ alignas(16) bf16 As[3][QBM * QBK];
  __shared__ alignas(16) bf16 Bs[3][QBN * QBK];
  const int tid = threadIdx.x;
  const int lane = tid & 63, wave = tid >> 6;
  const int col = lane & 15, quad = lane >> 4;
  const int wr = wave >> 1, wc = wave & 1;        // wave tile: 64 x 128
  const size_t m0 = (size_t)blockIdx.x * QBM, n0 = (size_t)blockIdx.y * QBN;

  const int u = (lane & 7) ^ (lane >> 3);
  const int srow = 2 * (lane >> 3) + (u >> 2);
  const int scol = (u & 3) * 8;
  const bf16* Abase = A + (m0 + srow) * (size_t)KD + scol;
  const bf16* Bbase = Bt + (n0 + srow) * (size_t)KD + scol;

  const int pswz = (((col & 1) << 2) | quad) ^ (col >> 1);
  const int afb = wr * 2048 + (col >> 1) * 64 + pswz * 8;
  const int bfb = wc * 4096 + (col >> 1) * 64 + pswz * 8;

  f32x4 acc[4][8];
#pragma unroll
  for (int i = 0; i < 4; ++i)
#pragma unroll
    for (int j = 0; j < 8; ++j)
#pragma unroll
      for (int r = 0; r < 4; ++r) acc[i][j][r] = 0.f;

#define OSTAGE(t, sl) do { \
    gload_lds16(Abase + (size_t)(t) * QBK + (size_t)(2 * wave + 0) * 16 * KD, &As[sl][(2 * wave + 0) * 512]); \
    gload_lds16(Abase + (size_t)(t) * QBK + (size_t)(2 * wave + 1) * 16 * KD, &As[sl][(2 * wave + 1) * 512]); \
    gload_lds16(Bbase + (size_t)(t) * QBK + (size_t)(4 * wave + 0) * 16 * KD, &Bs[sl][(4 * wave + 0) * 512]); \
    gload_lds16(Bbase + (size_t)(t) * QBK + (size_t)(4 * wave + 1) * 16 * KD, &Bs[sl][(4 * wave + 1) * 512]); \
    gload_lds16(Bbase + (size_t)(t) * QBK + (size_t)(4 * wave + 2) * 16 * KD, &Bs[sl][(4 * wave + 2) * 512]); \
    gload_lds16(Bbase + (size_t)(t) * QBK + (size_t)(4 * wave + 3) * 16 * KD, &Bs[sl][(4 * wave + 3) * 512]); \
  } while (0)

#define OUT_TILE(cur, DOSTAGE, VM) do { \
    bf16x8 af[4], bfv[8]; \
    _Pragma("unroll") for (int j = 0; j < 8; ++j) bfv[j] = *(const bf16x8*)&Bs[cur][bfb + j * 512]; \
    _Pragma("unroll") for (int i = 0; i < 4; ++i) af[i] = *(const bf16x8*)&As[cur][afb + i * 512]; \
    DOSTAGE; \
    __builtin_amdgcn_s_setprio(1); \
    _Pragma("unroll") for (int i = 0; i < 4; ++i) \
      _Pragma("unroll") for (int j = 0; j < 8; ++j) acc[i][j] = MFMA16(af[i], bfv[j], acc[i][j]); \
    __builtin_amdgcn_s_setprio(0); \
    VM; \
    __builtin_amdgcn_s_barrier(); \
  } while (0)

  OSTAGE(0, 0);
  OSTAGE(1, 1);
  VMW(6);
  __builtin_amdgcn_s_barrier();

#pragma unroll 1
  for (int t = 0; t < QNT - 2; t += 3) {          // tiles 0..29
    OUT_TILE(0, OSTAGE(t + 2, 2), VMW(6));
    OUT_TILE(1, OSTAGE(t + 3, 0), VMW(6));
    OUT_TILE(2, OSTAGE(t + 4, 1), VMW(6));
  }
  OUT_TILE(0, (void)0, VMW(0));                   // tile 30
  OUT_TILE(1, (void)0, (void)0);                  // tile 31

#pragma unroll
  for (int i = 0; i < 4; ++i)
#pragma unroll
    for (int j = 0; j < 8; ++j) {
      size_t row = m0 + wr * 64 + i * 16 + quad * 4;
      size_t c = n0 + wc * 128 + j * 16 + col;
      float bv = bias[c];
#pragma unroll
      for (int r = 0; r < 4; ++r) C[(row + r) * (size_t)NN + c] = acc[i][j][r] + bv;
    }
#undef OUT_TILE
#undef OSTAGE
}

// ----------------------------------------------- flash attention v6 (R10 EXACT,
// 76.2-76.8us measured — session best; both neighbors regress: R3 2-tile split
// 93, R11 8-wave consolidation 86). 4 q-tiles/wave, 4 waves/block, 512 blocks =
// 2 blocks/CU. ones-MFMA denominator, 3-slot ring + counted vmcnt(4), per-kt
// QK^T / per-n PV register windows, no setprio.
__global__ __launch_bounds__(256, 2)
void flash_attn_kernel(const bf16* __restrict__ qk, const bf16* __restrict__ vt,
                       const unsigned char* __restrict__ mask, bf16* __restrict__ ao) {
  __shared__ alignas(16) bf16 Ks[3][64 * 64];      // [key][slot^], xor-swizzled 16B slots
  __shared__ alignas(16) bf16 Vs[3][64 * 64];      // [d][slot^]

  const int tid = threadIdx.x;
  const int wave = tid >> 6, lane = tid & 63;
  const int col = lane & 15, quad = lane >> 4;
  const int id = blockIdx.x;
  const int hb = id & 63, qi = id >> 6;            // same-head blocks stride 64 -> same XCD
  const int h = hb & 15, b = hb >> 4;
  const int qbase0 = qi * 256 + wave * 64;

  const bf16* Qp = qk + (size_t)(b * Tt) * 2048 + h * Hd;
  const bf16* Kp = Qp + 1024;
  const bf16* Vp = vt + ((size_t)(b * Hh + h) * Hd) * Tt;
  const unsigned char* mp = mask + b * Tt;

  unsigned long long anym;
  {
    const unsigned long long* mq = (const unsigned long long*)mp;
    unsigned long long acc = 0;
#pragma unroll
    for (int j = 0; j < 4; ++j) acc |= mq[lane * 4 + j];
    anym = __ballot(acc != 0ull);
  }

  // Q fragments (pre-scaled by CEXP): free index = query
  bf16x8 qf[4][2];
#pragma unroll
  for (int t = 0; t < 4; ++t)
#pragma unroll
    for (int kk = 0; kk < 2; ++kk)
      qf[t][kk] = *(const bf16x8*)(Qp + (size_t)(qbase0 + t * 16 + col) * 2048 + kk * 32 + quad * 8);

  // gload_lds staging: wave w stages 1KB chunks g in {2w, 2w+1} of K and of V.
  const int u = (lane & 7) ^ (lane >> 3);
  const int g0 = 2 * wave, g1 = 2 * wave + 1;
  const bf16* Ksrc0 = Kp + (size_t)(g0 * 8 + (lane >> 3)) * 2048 + u * 8;
  const bf16* Ksrc1 = Kp + (size_t)(g1 * 8 + (lane >> 3)) * 2048 + u * 8;
  const bf16* Vsrc0 = Vp + (size_t)(g0 * 8 + (lane >> 3)) * 2048 + u * 8;
  const bf16* Vsrc1 = Vp + (size_t)(g1 * 8 + (lane >> 3)) * 2048 + u * 8;

#define FSTAGE(t, sl) do { \
    gload_lds16(Ksrc0 + (size_t)(t) * 64 * 2048, &Ks[sl][g0 * 512]); \
    gload_lds16(Ksrc1 + (size_t)(t) * 64 * 2048, &Ks[sl][g1 * 512]); \
    gload_lds16(Vsrc0 + (t) * 64, &Vs[sl][g0 * 512]); \
    gload_lds16(Vsrc1 + (t) * 64, &Vs[sl][g1 * 512]); \
  } while (0)

  f32x4 oacc[4][4];
  f32x4 lones[4];
#pragma unroll
  for (int t = 0; t < 4; ++t) {
#pragma unroll
    for (int r = 0; r < 4; ++r) lones[t][r] = 0.f;
#pragma unroll
    for (int n = 0; n < 4; ++n)
#pragma unroll
      for (int r = 0; r < 4; ++r) oacc[t][n][r] = 0.f;
  }
  const f32x4 zero4 = {0.f, 0.f, 0.f, 0.f};
  bf16x8 onev;
#pragma unroll
  for (int j = 0; j < 8; ++j) onev[j] = (bf16)1.0f;

  const int fslot0 = ((0 * 4 + quad) ^ (col & 7)) * 8;   // b128 frag slots (kf)
  const int fslot1 = ((1 * 4 + quad) ^ (col & 7)) * 8;
  const int voff = (quad & 1) * 4;

#define FITER(cur, II, DOSTAGE, VM) do { \
    const int kb = (II) * 64; \
    DOSTAGE; \
    f32x4 s[4][4]; \
    _Pragma("unroll") for (int kt = 0; kt < 4; ++kt) { \
      bf16x8 kf0 = *(const bf16x8*)&Ks[cur][(kt * 16 + col) * 64 + fslot0]; \
      bf16x8 kf1 = *(const bf16x8*)&Ks[cur][(kt * 16 + col) * 64 + fslot1]; \
      _Pragma("unroll") for (int t = 0; t < 4; ++t) { \
        s[t][kt] = MFMA16(kf0, qf[t][0], zero4); \
        s[t][kt] = MFMA16(kf1, qf[t][1], s[t][kt]); \
      } \
    } \
    if ((anym >> (2 * (II))) & 3ull) { \
      _Pragma("unroll") for (int kt = 0; kt < 4; ++kt) \
        _Pragma("unroll") for (int r = 0; r < 4; ++r) \
          if (mp[kb + kt * 16 + quad * 4 + r] != 0) { \
            _Pragma("unroll") for (int t = 0; t < 4; ++t) s[t][kt][r] = -1e9f; \
          } \
    } \
    bf16x8 pf[4][2]; \
    _Pragma("unroll") for (int t = 0; t < 4; ++t) { \
      f32x4 e0, e1, e2, e3; \
      _Pragma("unroll") for (int r = 0; r < 4; ++r) { \
        e0[r] = __builtin_amdgcn_exp2f(s[t][0][r]); \
        e1[r] = __builtin_amdgcn_exp2f(s[t][1][r]); \
        e2[r] = __builtin_amdgcn_exp2f(s[t][2][r]); \
        e3[r] = __builtin_amdgcn_exp2f(s[t][3][r]); \
      } \
      bf16x4 c0 = __builtin_convertvector(e0, bf16x4); \
      bf16x4 c1 = __builtin_convertvector(e1, bf16x4); \
      bf16x4 c2 = __builtin_convertvector(e2, bf16x4); \
      bf16x4 c3 = __builtin_convertvector(e3, bf16x4); \
      pf[t][0] = __builtin_shufflevector(c0, c1, 0, 1, 2, 3, 4, 5, 6, 7); \
      pf[t][1] = __builtin_shufflevector(c2, c3, 0, 1, 2, 3, 4, 5, 6, 7); \
    } \
    _Pragma("unroll") for (int n = 0; n < 4; ++n) { \
      const int row = (n * 16 + col) * 64; \
      const int rx = col & 7; \
      bf16x8 v0, v1; \
      { bf16x4 lo = *(const bf16x4*)&Vs[cur][row + ((0 + (quad >> 1)) ^ rx) * 8 + voff]; \
        bf16x4 hi = *(const bf16x4*)&Vs[cur][row + ((2 + (quad >> 1)) ^ rx) * 8 + voff]; \
        v0 = __builtin_shufflevector(lo, hi, 0, 1, 2, 3, 4, 5, 6, 7); } \
      { bf16x4 lo = *(const bf16x4*)&Vs[cur][row + ((4 + (quad >> 1)) ^ rx) * 8 + voff]; \
        bf16x4 hi = *(const bf16x4*)&Vs[cur][row + ((6 + (quad >> 1)) ^ rx) * 8 + voff]; \
        v1 = __builtin_shufflevector(lo, hi, 0, 1, 2, 3, 4, 5, 6, 7); } \
      _Pragma("unroll") for (int t = 0; t < 4; ++t) { \
        oacc[t][n] = MFMA16(pf[t][0], v0, oacc[t][n]); \
        oacc[t][n] = MFMA16(pf[t][1], v1, oacc[t][n]); \
      } \
    } \
    _Pragma("unroll") for (int t = 0; t < 4; ++t) { \
      lones[t] = MFMA16(pf[t][0], onev, lones[t]); \
      lones[t] = MFMA16(pf[t][1], onev, lones[t]); \
    } \
    VM; \
    __builtin_amdgcn_s_barrier(); \
  } while (0)

  // prologue: stage tiles 0,1 (8 loads outstanding); wait oldest 4 = tile 0
  FSTAGE(0, 0);
  FSTAGE(1, 1);
  VMW(4);
  __builtin_amdgcn_s_barrier();

#pragma unroll 1
  for (int ii = 0; ii < 30; ii += 3) {            // tiles 0..29
    FITER(0, ii + 0, FSTAGE(ii + 2, 2), VMW(4));
    FITER(1, ii + 1, FSTAGE(ii + 3, 0), VMW(4));
    FITER(2, ii + 2, FSTAGE(ii + 4, 1), VMW(4));
  }
  FITER(0, 30, (void)0, VMW(0));                  // tile 30: tile 31 must land
  FITER(1, 31, (void)0, (void)0);                 // tile 31

#undef FITER
#undef FSTAGE

  // epilogue: no cross-lane transpose needed; lones rows == oacc rows
#pragma unroll
  for (int t = 0; t < 4; ++t) {
    f32x4 rl;
#pragma unroll
    for (int r = 0; r < 4; ++r) rl[r] = __builtin_amdgcn_rcpf(lones[t][r]);
#pragma unroll
    for (int n = 0; n < 4; ++n)
#pragma unroll
      for (int r = 0; r < 4; ++r) {
        size_t q = (size_t)b * Tt + qbase0 + t * 16 + quad * 4 + r;
        ao[q * Dd + h * Hd + n * 16 + col] = (bf16)(oacc[t][n][r] * rl[r]);
      }
  }
}

// --------------------------------------------------------------------- launcher
extern "C" void kernel_launch(void* const* d_in, const int* in_sizes, int n_in,
                              void* d_out, int out_size, void* d_ws, size_t ws_size,
                              hipStream_t stream) {
  const float* x = (const float*)d_in[0];
  const unsigned char* mask = (const unsigned char*)d_in[1];
  const float* Wq = (const float*)d_in[2];
  const float* bq = (const float*)d_in[3];
  const float* Wk = (const float*)d_in[4];
  const float* bk = (const float*)d_in[5];
  const float* Wv = (const float*)d_in[6];
  const float* bv = (const float*)d_in[7];
  const float* Wo = (const float*)d_in[8];
  const float* bo = (const float*)d_in[9];
  float* out = (float*)d_out;

  char* ws = (char*)d_ws;
  size_t off = 0;
  auto alloc = [&](size_t bytes) {
    char* p = ws + off;
    off += (bytes + 255) & ~(size_t)255;
    return p;
  };
  bf16* xb  = (bf16*)alloc((size_t)Mrows * Dd * 2);        // 16.8MB (reused as AO)
  bf16* Wt  = (bf16*)alloc((size_t)3 * Dd * Dd * 2);       // 6.3MB  packed [3072][1024]
  bf16* Wot = (bf16*)alloc((size_t)Dd * Dd * 2);           // 2.1MB
  bf16* QK  = (bf16*)alloc((size_t)Mrows * 2048 * 2);      // 33.6MB [8192][2048]
  bf16* Vt  = (bf16*)alloc((size_t)Bb * Hh * Hd * Tt * 2); // 16.8MB
  float* bqkv = (float*)alloc((size_t)3 * Dd * 4);

  cast_f32_bf16_kernel<<<Mrows * Dd / (256 * 8), 256, 0, stream>>>(x, xb);
  transpose_cast_w4_kernel<<<dim3(16, 16, 4), 256, 0, stream>>>(
      Wq, Wk, Wv, Wo, bq, bk, bv, Wt, Wot, bqkv);

  gemm_qkv_kernel<<<dim3(Mrows / QBM, 3 * Dd / QBN), 256, 0, stream>>>(
      xb, Wt, bqkv, QK, Vt);

  bf16* AO = xb;  // xb dead after QKV GEMM
  flash_attn_kernel<<<dim3(512), 256, 0, stream>>>(QK, Vt, mask, AO);
  gemm_out_kernel<<<dim3(Mrows / QBM, Dd / QBN), 256, 0, stream>>>(
      AO, Wot, bo, out);
}

// Round 15
// 255.302 us; speedup vs baseline: 1.7545x; 1.0162x over previous
//
#include <hip/hip_runtime.h>

using bf16 = __bf16;
typedef bf16 bf16x4 __attribute__((ext_vector_type(4)));
typedef bf16 bf16x8 __attribute__((ext_vector_type(8)));
typedef float f32x4 __attribute__((ext_vector_type(4)));
typedef float f32x8 __attribute__((ext_vector_type(8)));

#define MFMA16(a, b, c) __builtin_amdgcn_mfma_f32_16x16x32_bf16(a, b, c, 0, 0, 0)

constexpr int Bb = 4, Tt = 2048, Dd = 1024, Hh = 16, Hd = 64;
constexpr int Mrows = Bb * Tt;                 // 8192
constexpr float CEXP = 0.18033688011112042f;   // (1/sqrt(64)) * log2(e), folded into Wq/bq

// async global->LDS, 16B per lane; LDS dst = wave-uniform base + lane*16 [m97/m104]
__device__ __forceinline__ void gload_lds16(const bf16* g, bf16* lds_base) {
  __builtin_amdgcn_global_load_lds((const __attribute__((address_space(1))) void*)g,
                                   (__attribute__((address_space(3))) void*)lds_base,
                                   16, 0, 0);
}

// ---- fused prep: cast x->bf16 (blocks 0..4095) + transpose/cast of the four
// weight matrices W[k][n] f32 -> Wt[n][k] bf16 + qkv bias pack (blocks 4096..5119).
// cast and transpose are independent; one dispatch overlaps them and removes a
// launch boundary (they previously serialized on the stream).
__global__ void prep_kernel(const float* __restrict__ x, bf16* __restrict__ xb,
                            const float* __restrict__ Wq, const float* __restrict__ Wk,
                            const float* __restrict__ Wv, const float* __restrict__ Wo,
                            const float* __restrict__ bq, const float* __restrict__ bk,
                            const float* __restrict__ bv,
                            bf16* __restrict__ Wt, bf16* __restrict__ Wot,
                            float* __restrict__ bqkv) {
  __shared__ alignas(16) float tile[64][68];
  const int tid = threadIdx.x;
  const int bid = blockIdx.x;
  if (bid < 4096) {       // ---- cast path: 4096 blocks x 256 thr x 8 elems
    size_t i = ((size_t)bid * 256 + tid) * 8;
    f32x8 v = *(const f32x8*)(x + i);
    *(bf16x8*)(xb + i) = __builtin_convertvector(v, bf16x8);
    return;
  }
  const int t = bid - 4096;                       // 1024 transpose blocks
  const int n0 = (t & 15) * 64, k0 = ((t >> 4) & 15) * 64, z = t >> 8;
  const float* W = (z == 0) ? Wq : (z == 1) ? Wk : (z == 2) ? Wv : Wo;
  bf16* dst = (z == 3) ? Wot : (Wt + (size_t)z * Dd * Dd);
  const float scale = (z == 0) ? CEXP : 1.0f;
  if (k0 == 0 && z < 3 && tid < 64) {
    const float* bsrc = (z == 0) ? bq : (z == 1) ? bk : bv;
    bqkv[z * Dd + n0 + tid] = bsrc[n0 + tid] * scale;
  }
#pragma unroll
  for (int it = 0; it < 4; ++it) {
    int chunk = tid + it * 256;
    int kr = chunk >> 4, c4 = chunk & 15;
    f32x4 v = *(const f32x4*)(W + (size_t)(k0 + kr) * Dd + n0 + c4 * 4);
    *(f32x4*)&tile[kr][c4 * 4] = v * scale;
  }
  __syncthreads();
#pragma unroll
  for (int it = 0; it < 2; ++it) {
    int chunk = tid + it * 256;
    int n = chunk & 63, k8 = chunk >> 6;
    bf16x8 o;
#pragma unroll
    for (int j = 0; j < 8; ++j) o[j] = (bf16)tile[k8 * 8 + j][n];
    *(bf16x8*)(dst + (size_t)(n0 + n) * Dd + k0 + k8 * 8) = o;
  }
}

// --------- QKV GEMM v3b: 128x256 tile / 256 threads / 4 waves (2M x 2N), BK=32.
// 3-slot ring (72 KiB), counted vmcnt(6), one s_barrier per tile. No explicit
// lgkmcnt drain before MFMAs (R14: compiler's fine-grained lgkmcnt is better;
// removal was worth ~3.6us across both GEMMs).
constexpr int QBM = 128, QBN = 256, QBK = 32, QNT = Dd / QBK;  // 32 K-tiles

#define VMW(n) asm volatile("s_waitcnt vmcnt(" #n ")" ::: "memory")

__global__ __launch_bounds__(256, 2)
void gemm_qkv_kernel(const bf16* __restrict__ A, const bf16* __restrict__ Bt,
                     const float* __restrict__ bias, bf16* __restrict__ QK,
                     bf16* __restrict__ Vt) {
  constexpr int KD = Dd;
  __shared__ alignas(16) bf16 As[3][QBM * QBK];   // 3 x 8 KiB
  __shared__ alignas(16) bf16 Bs[3][QBN * QBK];   // 3 x 16 KiB  (72 KiB total)
  const int tid = threadIdx.x;
  const int lane = tid & 63, wave = tid >> 6;
  const int col = lane & 15, quad = lane >> 4;
  const int wr = wave >> 1, wc = wave & 1;        // wave tile: 64 x 128
  const size_t m0 = (size_t)blockIdx.x * QBM, n0 = (size_t)blockIdx.y * QBN;

  // staging source pre-swizzle (rule #21): lane l writes LDS vrow (c*8 + l>>3),
  // phys pos (l&7); fetch logical chunk u = (l&7)^(l>>3):
  const int u = (lane & 7) ^ (lane >> 3);
  const int srow = 2 * (lane >> 3) + (u >> 2);    // row within 16-row chunk
  const int scol = (u & 3) * 8;                   // element col within 32
  const bf16* Abase = A + (m0 + srow) * (size_t)KD + scol;
  const bf16* Bbase = Bt + (n0 + srow) * (size_t)KD + scol;

  // swizzled fragment read base: row R -> vrow R>>1, pos ((R&1)*4 | quad) ^ (vrow&7)
  const int pswz = (((col & 1) << 2) | quad) ^ (col >> 1);
  const int afb = wr * 2048 + (col >> 1) * 64 + pswz * 8;  // + i*512, i<4
  const int bfb = wc * 4096 + (col >> 1) * 64 + pswz * 8;  // + j*512, j<8

  f32x4 acc[4][8];
#pragma unroll
  for (int i = 0; i < 4; ++i)
#pragma unroll
    for (int j = 0; j < 8; ++j)
#pragma unroll
      for (int r = 0; r < 4; ++r) acc[i][j][r] = 0.f;

  // per wave per tile: 2 A-chunks + 4 B-chunks (6 gloads; 4 waves cover 8+16)
#define QSTAGE(t, sl) do { \
    gload_lds16(Abase + (size_t)(t) * QBK + (size_t)(2 * wave + 0) * 16 * KD, &As[sl][(2 * wave + 0) * 512]); \
    gload_lds16(Abase + (size_t)(t) * QBK + (size_t)(2 * wave + 1) * 16 * KD, &As[sl][(2 * wave + 1) * 512]); \
    gload_lds16(Bbase + (size_t)(t) * QBK + (size_t)(4 * wave + 0) * 16 * KD, &Bs[sl][(4 * wave + 0) * 512]); \
    gload_lds16(Bbase + (size_t)(t) * QBK + (size_t)(4 * wave + 1) * 16 * KD, &Bs[sl][(4 * wave + 1) * 512]); \
    gload_lds16(Bbase + (size_t)(t) * QBK + (size_t)(4 * wave + 2) * 16 * KD, &Bs[sl][(4 * wave + 2) * 512]); \
    gload_lds16(Bbase + (size_t)(t) * QBK + (size_t)(4 * wave + 3) * 16 * KD, &Bs[sl][(4 * wave + 3) * 512]); \
  } while (0)

#define QKV_TILE(cur, DOSTAGE, VM) do { \
    bf16x8 af[4], bfv[8]; \
    _Pragma("unroll") for (int j = 0; j < 8; ++j) bfv[j] = *(const bf16x8*)&Bs[cur][bfb + j * 512]; \
    _Pragma("unroll") for (int i = 0; i < 4; ++i) af[i] = *(const bf16x8*)&As[cur][afb + i * 512]; \
    DOSTAGE; \
    __builtin_amdgcn_s_setprio(1); \
    _Pragma("unroll") for (int i = 0; i < 4; ++i) \
      _Pragma("unroll") for (int j = 0; j < 8; ++j) acc[i][j] = MFMA16(af[i], bfv[j], acc[i][j]); \
    __builtin_amdgcn_s_setprio(0); \
    VM; \
    __builtin_amdgcn_s_barrier(); \
  } while (0)

  // prologue: stage tiles 0,1 (12 loads/wave outstanding); wait oldest 6 = tile 0
  QSTAGE(0, 0);
  QSTAGE(1, 1);
  VMW(6);
  __builtin_amdgcn_s_barrier();

#pragma unroll 1
  for (int t = 0; t < QNT - 2; t += 3) {          // tiles 0..29 (30 % 3 == 0)
    QKV_TILE(0, QSTAGE(t + 2, 2), VMW(6));
    QKV_TILE(1, QSTAGE(t + 3, 0), VMW(6));
    QKV_TILE(2, QSTAGE(t + 4, 1), VMW(6));
  }
  QKV_TILE(0, (void)0, VMW(0));                   // tile 30: only tile 31 in flight
  QKV_TILE(1, (void)0, (void)0);                  // tile 31

  if (n0 < 2048) {      // Q/K block -> compact [8192][2048] buffer
#pragma unroll
    for (int i = 0; i < 4; ++i)
#pragma unroll
      for (int j = 0; j < 8; ++j) {
        size_t row = m0 + wr * 64 + i * 16 + quad * 4;
        size_t c = n0 + wc * 128 + j * 16 + col;
        float bv = bias[c];
#pragma unroll
        for (int r = 0; r < 4; ++r) QK[(row + r) * 2048 + c] = (bf16)(acc[i][j][r] + bv);
      }
  } else {              // V block -> Vt[b][h][d][t], packed along t
#pragma unroll
    for (int i = 0; i < 4; ++i)
#pragma unroll
      for (int j = 0; j < 8; ++j) {
        size_t row = m0 + wr * 64 + i * 16 + quad * 4;
        int c = (int)(n0 + wc * 128 + j * 16 + col);
        float bv = bias[c];
        int dall = c - 2048, hh = dall >> 6, dd = dall & 63;
        int bi = (int)(row >> 11), trow = (int)(row & 2047);
        bf16x4 pk;
#pragma unroll
        for (int r = 0; r < 4; ++r) pk[r] = (bf16)(acc[i][j][r] + bv);
        *(bf16x4*)&Vt[((size_t)(bi * Hh + hh) * Hd + dd) * Tt + trow] = pk;
      }
  }
#undef QKV_TILE
#undef QSTAGE
}

// ---------- out-projection GEMM: same v3b template (no explicit lgkm drain),
// f32 output, grid 64x4 = 256 blocks (one round at 2 blocks/CU).
__global__ __launch_bounds__(256, 2)
void gemm_out_kernel(const bf16* __restrict__ A, const bf16* __restrict__ Bt,
                     const float* __restrict__ bias, float* __restrict__ C) {
  constexpr int KD = Dd, NN = Dd;
  __shared__ alignas(16) bf16 As[3][QBM * QBK];
  __shared__ alignas(16) bf16 Bs[3][QBN * QBK];
  const int tid = threadIdx.x;
  const int lane = tid & 63, wave = tid >> 6;
  const int col = lane & 15, quad = lane >> 4;
  const int wr = wave >> 1, wc = wave & 1;        // wave tile: 64 x 128
  const size_t m0 = (size_t)blockIdx.x * QBM, n0 = (size_t)blockIdx.y * QBN;

  const int u = (lane & 7) ^ (lane >> 3);
  const int srow = 2 * (lane >> 3) + (u >> 2);
  const int scol = (u & 3) * 8;
  const bf16* Abase = A + (m0 + srow) * (size_t)KD + scol;
  const bf16* Bbase = Bt + (n0 + srow) * (size_t)KD + scol;

  const int pswz = (((col & 1) << 2) | quad) ^ (col >> 1);
  const int afb = wr * 2048 + (col >> 1) * 64 + pswz * 8;
  const int bfb = wc * 4096 + (col >> 1) * 64 + pswz * 8;

  f32x4 acc[4][8];
#pragma unroll
  for (int i = 0; i < 4; ++i)
#pragma unroll
    for (int j = 0; j < 8; ++j)
#pragma unroll
      for (int r = 0; r < 4; ++r) acc[i][j][r] = 0.f;

#define OSTAGE(t, sl) do { \
    gload_lds16(Abase + (size_t)(t) * QBK + (size_t)(2 * wave + 0) * 16 * KD, &As[sl][(2 * wave + 0) * 512]); \
    gload_lds16(Abase + (size_t)(t) * QBK + (size_t)(2 * wave + 1) * 16 * KD, &As[sl][(2 * wave + 1) * 512]); \
    gload_lds16(Bbase + (size_t)(t) * QBK + (size_t)(4 * wave + 0) * 16 * KD, &Bs[sl][(4 * wave + 0) * 512]); \
    gload_lds16(Bbase + (size_t)(t) * QBK + (size_t)(4 * wave + 1) * 16 * KD, &Bs[sl][(4 * wave + 1) * 512]); \
    gload_lds16(Bbase + (size_t)(t) * QBK + (size_t)(4 * wave + 2) * 16 * KD, &Bs[sl][(4 * wave + 2) * 512]); \
    gload_lds16(Bbase + (size_t)(t) * QBK + (size_t)(4 * wave + 3) * 16 * KD, &Bs[sl][(4 * wave + 3) * 512]); \
  } while (0)

#define OUT_TILE(cur, DOSTAGE, VM) do { \
    bf16x8 af[4], bfv[8]; \
    _Pragma("unroll") for (int j = 0; j < 8; ++j) bfv[j] = *(const bf16x8*)&Bs[cur][bfb + j * 512]; \
    _Pragma("unroll") for (int i = 0; i < 4; ++i) af[i] = *(const bf16x8*)&As[cur][afb + i * 512]; \
    DOSTAGE; \
    __builtin_amdgcn_s_setprio(1); \
    _Pragma("unroll") for (int i = 0; i < 4; ++i) \
      _Pragma("unroll") for (int j = 0; j < 8; ++j) acc[i][j] = MFMA16(af[i], bfv[j], acc[i][j]); \
    __builtin_amdgcn_s_setprio(0); \
    VM; \
    __builtin_amdgcn_s_barrier(); \
  } while (0)

  OSTAGE(0, 0);
  OSTAGE(1, 1);
  VMW(6);
  __builtin_amdgcn_s_barrier();

#pragma unroll 1
  for (int t = 0; t < QNT - 2; t += 3) {          // tiles 0..29
    OUT_TILE(0, OSTAGE(t + 2, 2), VMW(6));
    OUT_TILE(1, OSTAGE(t + 3, 0), VMW(6));
    OUT_TILE(2, OSTAGE(t + 4, 1), VMW(6));
  }
  OUT_TILE(0, (void)0, VMW(0));                   // tile 30
  OUT_TILE(1, (void)0, (void)0);                  // tile 31

#pragma unroll
  for (int i = 0; i < 4; ++i)
#pragma unroll
    for (int j = 0; j < 8; ++j) {
      size_t row = m0 + wr * 64 + i * 16 + quad * 4;
      size_t c = n0 + wc * 128 + j * 16 + col;
      float bv = bias[c];
#pragma unroll
      for (int r = 0; r < 4; ++r) C[(row + r) * (size_t)NN + c] = acc[i][j][r] + bv;
    }
#undef OUT_TILE
#undef OSTAGE
}

// ----------------------------------------------- flash attention v6 (R10 EXACT,
// 76.2-76.8us measured — session best; both neighbors regress: R3 2-tile split
// 93, R11 8-wave consolidation 86). 4 q-tiles/wave, 4 waves/block, 512 blocks =
// 2 blocks/CU. ones-MFMA denominator, 3-slot ring + counted vmcnt(4), per-kt
// QK^T / per-n PV register windows, no setprio.
__global__ __launch_bounds__(256, 2)
void flash_attn_kernel(const bf16* __restrict__ qk, const bf16* __restrict__ vt,
                       const unsigned char* __restrict__ mask, bf16* __restrict__ ao) {
  __shared__ alignas(16) bf16 Ks[3][64 * 64];      // [key][slot^], xor-swizzled 16B slots
  __shared__ alignas(16) bf16 Vs[3][64 * 64];      // [d][slot^]

  const int tid = threadIdx.x;
  const int wave = tid >> 6, lane = tid & 63;
  const int col = lane & 15, quad = lane >> 4;
  const int id = blockIdx.x;
  const int hb = id & 63, qi = id >> 6;            // same-head blocks stride 64 -> same XCD
  const int h = hb & 15, b = hb >> 4;
  const int qbase0 = qi * 256 + wave * 64;

  const bf16* Qp = qk + (size_t)(b * Tt) * 2048 + h * Hd;
  const bf16* Kp = Qp + 1024;
  const bf16* Vp = vt + ((size_t)(b * Hh + h) * Hd) * Tt;
  const unsigned char* mp = mask + b * Tt;

  unsigned long long anym;
  {
    const unsigned long long* mq = (const unsigned long long*)mp;
    unsigned long long acc = 0;
#pragma unroll
    for (int j = 0; j < 4; ++j) acc |= mq[lane * 4 + j];
    anym = __ballot(acc != 0ull);
  }

  // Q fragments (pre-scaled by CEXP): free index = query
  bf16x8 qf[4][2];
#pragma unroll
  for (int t = 0; t < 4; ++t)
#pragma unroll
    for (int kk = 0; kk < 2; ++kk)
      qf[t][kk] = *(const bf16x8*)(Qp + (size_t)(qbase0 + t * 16 + col) * 2048 + kk * 32 + quad * 8);

  // gload_lds staging: wave w stages 1KB chunks g in {2w, 2w+1} of K and of V.
  const int u = (lane & 7) ^ (lane >> 3);
  const int g0 = 2 * wave, g1 = 2 * wave + 1;
  const bf16* Ksrc0 = Kp + (size_t)(g0 * 8 + (lane >> 3)) * 2048 + u * 8;
  const bf16* Ksrc1 = Kp + (size_t)(g1 * 8 + (lane >> 3)) * 2048 + u * 8;
  const bf16* Vsrc0 = Vp + (size_t)(g0 * 8 + (lane >> 3)) * 2048 + u * 8;
  const bf16* Vsrc1 = Vp + (size_t)(g1 * 8 + (lane >> 3)) * 2048 + u * 8;

#define FSTAGE(t, sl) do { \
    gload_lds16(Ksrc0 + (size_t)(t) * 64 * 2048, &Ks[sl][g0 * 512]); \
    gload_lds16(Ksrc1 + (size_t)(t) * 64 * 2048, &Ks[sl][g1 * 512]); \
    gload_lds16(Vsrc0 + (t) * 64, &Vs[sl][g0 * 512]); \
    gload_lds16(Vsrc1 + (t) * 64, &Vs[sl][g1 * 512]); \
  } while (0)

  f32x4 oacc[4][4];
  f32x4 lones[4];
#pragma unroll
  for (int t = 0; t < 4; ++t) {
#pragma unroll
    for (int r = 0; r < 4; ++r) lones[t][r] = 0.f;
#pragma unroll
    for (int n = 0; n < 4; ++n)
#pragma unroll
      for (int r = 0; r < 4; ++r) oacc[t][n][r] = 0.f;
  }
  const f32x4 zero4 = {0.f, 0.f, 0.f, 0.f};
  bf16x8 onev;
#pragma unroll
  for (int j = 0; j < 8; ++j) onev[j] = (bf16)1.0f;

  const int fslot0 = ((0 * 4 + quad) ^ (col & 7)) * 8;   // b128 frag slots (kf)
  const int fslot1 = ((1 * 4 + quad) ^ (col & 7)) * 8;
  const int voff = (quad & 1) * 4;

#define FITER(cur, II, DOSTAGE, VM) do { \
    const int kb = (II) * 64; \
    DOSTAGE; \
    f32x4 s[4][4]; \
    _Pragma("unroll") for (int kt = 0; kt < 4; ++kt) { \
      bf16x8 kf0 = *(const bf16x8*)&Ks[cur][(kt * 16 + col) * 64 + fslot0]; \
      bf16x8 kf1 = *(const bf16x8*)&Ks[cur][(kt * 16 + col) * 64 + fslot1]; \
      _Pragma("unroll") for (int t = 0; t < 4; ++t) { \
        s[t][kt] = MFMA16(kf0, qf[t][0], zero4); \
        s[t][kt] = MFMA16(kf1, qf[t][1], s[t][kt]); \
      } \
    } \
    if ((anym >> (2 * (II))) & 3ull) { \
      _Pragma("unroll") for (int kt = 0; kt < 4; ++kt) \
        _Pragma("unroll") for (int r = 0; r < 4; ++r) \
          if (mp[kb + kt * 16 + quad * 4 + r] != 0) { \
            _Pragma("unroll") for (int t = 0; t < 4; ++t) s[t][kt][r] = -1e9f; \
          } \
    } \
    bf16x8 pf[4][2]; \
    _Pragma("unroll") for (int t = 0; t < 4; ++t) { \
      f32x4 e0, e1, e2, e3; \
      _Pragma("unroll") for (int r = 0; r < 4; ++r) { \
        e0[r] = __builtin_amdgcn_exp2f(s[t][0][r]); \
        e1[r] = __builtin_amdgcn_exp2f(s[t][1][r]); \
        e2[r] = __builtin_amdgcn_exp2f(s[t][2][r]); \
        e3[r] = __builtin_amdgcn_exp2f(s[t][3][r]); \
      } \
      bf16x4 c0 = __builtin_convertvector(e0, bf16x4); \
      bf16x4 c1 = __builtin_convertvector(e1, bf16x4); \
      bf16x4 c2 = __builtin_convertvector(e2, bf16x4); \
      bf16x4 c3 = __builtin_convertvector(e3, bf16x4); \
      pf[t][0] = __builtin_shufflevector(c0, c1, 0, 1, 2, 3, 4, 5, 6, 7); \
      pf[t][1] = __builtin_shufflevector(c2, c3, 0, 1, 2, 3, 4, 5, 6, 7); \
    } \
    _Pragma("unroll") for (int n = 0; n < 4; ++n) { \
      const int row = (n * 16 + col) * 64; \
      const int rx = col & 7; \
      bf16x8 v0, v1; \
      { bf16x4 lo = *(const bf16x4*)&Vs[cur][row + ((0 + (quad >> 1)) ^ rx) * 8 + voff]; \
        bf16x4 hi = *(const bf16x4*)&Vs[cur][row + ((2 + (quad >> 1)) ^ rx) * 8 + voff]; \
        v0 = __builtin_shufflevector(lo, hi, 0, 1, 2, 3, 4, 5, 6, 7); } \
      { bf16x4 lo = *(const bf16x4*)&Vs[cur][row + ((4 + (quad >> 1)) ^ rx) * 8 + voff]; \
        bf16x4 hi = *(const bf16x4*)&Vs[cur][row + ((6 + (quad >> 1)) ^ rx) * 8 + voff]; \
        v1 = __builtin_shufflevector(lo, hi, 0, 1, 2, 3, 4, 5, 6, 7); } \
      _Pragma("unroll") for (int t = 0; t < 4; ++t) { \
        oacc[t][n] = MFMA16(pf[t][0], v0, oacc[t][n]); \
        oacc[t][n] = MFMA16(pf[t][1], v1, oacc[t][n]); \
      } \
    } \
    _Pragma("unroll") for (int t = 0; t < 4; ++t) { \
      lones[t] = MFMA16(pf[t][0], onev, lones[t]); \
      lones[t] = MFMA16(pf[t][1], onev, lones[t]); \
    } \
    VM; \
    __builtin_amdgcn_s_barrier(); \
  } while (0)

  // prologue: stage tiles 0,1 (8 loads outstanding); wait oldest 4 = tile 0
  FSTAGE(0, 0);
  FSTAGE(1, 1);
  VMW(4);
  __builtin_amdgcn_s_barrier();

#pragma unroll 1
  for (int ii = 0; ii < 30; ii += 3) {            // tiles 0..29
    FITER(0, ii + 0, FSTAGE(ii + 2, 2), VMW(4));
    FITER(1, ii + 1, FSTAGE(ii + 3, 0), VMW(4));
    FITER(2, ii + 2, FSTAGE(ii + 4, 1), VMW(4));
  }
  FITER(0, 30, (void)0, VMW(0));                  // tile 30: tile 31 must land
  FITER(1, 31, (void)0, (void)0);                 // tile 31

#undef FITER
#undef FSTAGE

  // epilogue: no cross-lane transpose needed; lones rows == oacc rows
#pragma unroll
  for (int t = 0; t < 4; ++t) {
    f32x4 rl;
#pragma unroll
    for (int r = 0; r < 4; ++r) rl[r] = __builtin_amdgcn_rcpf(lones[t][r]);
#pragma unroll
    for (int n = 0; n < 4; ++n)
#pragma unroll
      for (int r = 0; r < 4; ++r) {
        size_t q = (size_t)b * Tt + qbase0 + t * 16 + quad * 4 + r;
        ao[q * Dd + h * Hd + n * 16 + col] = (bf16)(oacc[t][n][r] * rl[r]);
      }
  }
}

// --------------------------------------------------------------------- launcher
extern "C" void kernel_launch(void* const* d_in, const int* in_sizes, int n_in,
                              void* d_out, int out_size, void* d_ws, size_t ws_size,
                              hipStream_t stream) {
  const float* x = (const float*)d_in[0];
  const unsigned char* mask = (const unsigned char*)d_in[1];
  const float* Wq = (const float*)d_in[2];
  const float* bq = (const float*)d_in[3];
  const float* Wk = (const float*)d_in[4];
  const float* bk = (const float*)d_in[5];
  const float* Wv = (const float*)d_in[6];
  const float* bv = (const float*)d_in[7];
  const float* Wo = (const float*)d_in[8];
  const float* bo = (const float*)d_in[9];
  float* out = (float*)d_out;

  char* ws = (char*)d_ws;
  size_t off = 0;
  auto alloc = [&](size_t bytes) {
    char* p = ws + off;
    off += (bytes + 255) & ~(size_t)255;
    return p;
  };
  bf16* xb  = (bf16*)alloc((size_t)Mrows * Dd * 2);        // 16.8MB (reused as AO)
  bf16* Wt  = (bf16*)alloc((size_t)3 * Dd * Dd * 2);       // 6.3MB  packed [3072][1024]
  bf16* Wot = (bf16*)alloc((size_t)Dd * Dd * 2);           // 2.1MB
  bf16* QK  = (bf16*)alloc((size_t)Mrows * 2048 * 2);      // 33.6MB [8192][2048]
  bf16* Vt  = (bf16*)alloc((size_t)Bb * Hh * Hd * Tt * 2); // 16.8MB
  float* bqkv = (float*)alloc((size_t)3 * Dd * 4);

  prep_kernel<<<dim3(4096 + 1024), 256, 0, stream>>>(
      x, xb, Wq, Wk, Wv, Wo, bq, bk, bv, Wt, Wot, bqkv);

  gemm_qkv_kernel<<<dim3(Mrows / QBM, 3 * Dd / QBN), 256, 0, stream>>>(
      xb, Wt, bqkv, QK, Vt);

  bf16* AO = xb;  // xb dead after QKV GEMM
  flash_attn_kernel<<<dim3(512), 256, 0, stream>>>(QK, Vt, mask, AO);
  gemm_out_kernel<<<dim3(Mrows / QBM, Dd / QBN), 256, 0, stream>>>(
      AO, Wot, bo, out);
}